// Round 11
// baseline (227.972 us; speedup 1.0000x reference)
//
#include <hip/hip_runtime.h>
#include <stdint.h>

#define EMB 1024
#define HEADS 16
#define HDIM 64
#define SEQN 2048
#define BATCH 2
#define FFD 4096
#define ROWS (BATCH * SEQN)

typedef unsigned short u16t;
typedef __attribute__((ext_vector_type(4))) unsigned short u16x4;
typedef __attribute__((ext_vector_type(8))) unsigned short u16x8;
typedef __attribute__((ext_vector_type(8))) __bf16 bf16x8;
typedef __attribute__((ext_vector_type(4))) float f32x4;

__device__ __forceinline__ float b2f(u16t u) {
  union { float f; unsigned int i; } v; v.i = ((unsigned int)u) << 16; return v.f;
}
__device__ __forceinline__ u16t f2b(float f) {
  union { float f; unsigned int i; } v; v.f = f;
  unsigned int r = v.i + 0x7FFFu + ((v.i >> 16) & 1u);
  return (u16t)(r >> 16);
}

// gelu_tanh via sigmoid identity: 0.5v(1+tanh(t)) = v/(1+e^{-2t}).
// Confirmed: warm pipeline gain ~21 us vs libm tanhf (R1 vs R6).
__device__ __forceinline__ float gelu_f(float v) {
  float t2 = 1.5957691216057308f * (v + 0.044715f * v * v * v);  // 2*sqrt(2/pi)*(...)
  return v / (1.f + __expf(-t2));
}

__device__ __forceinline__ void gload16(const u16t* g, u16t* l) {
  __builtin_amdgcn_global_load_lds((const __attribute__((address_space(1))) void*)g,
                                   (__attribute__((address_space(3))) void*)l, 16, 0, 0);
}

// ---------------- LayerNorm: one block per row (1024 cols) ----------------
template <bool INF32>
__global__ __launch_bounds__(256) void ln_k(const void* __restrict__ x_, const float* __restrict__ g,
                                            const float* __restrict__ s, u16t* __restrict__ out) {
  const int row = blockIdx.x;
  const int t = threadIdx.x;
  float f[4];
  if (INF32) {
    const float4* xr = (const float4*)((const float*)x_ + (size_t)row * EMB);
    float4 xv = xr[t];
    f[0] = xv.x; f[1] = xv.y; f[2] = xv.z; f[3] = xv.w;
  } else {
    const u16t* xr = (const u16t*)x_ + (size_t)row * EMB;
    u16x4 xv = *(const u16x4*)(xr + t * 4);
#pragma unroll
    for (int i = 0; i < 4; i++) f[i] = b2f(xv[i]);
  }
  float sum = 0.f, sq = 0.f;
#pragma unroll
  for (int i = 0; i < 4; i++) { sum += f[i]; sq += f[i] * f[i]; }
#pragma unroll
  for (int off = 1; off < 64; off <<= 1) { sum += __shfl_xor(sum, off); sq += __shfl_xor(sq, off); }
  __shared__ float red[8];
  const int lane = t & 63, wave = t >> 6;
  if (lane == 0) { red[wave] = sum; red[4 + wave] = sq; }
  __syncthreads();
  sum = red[0] + red[1] + red[2] + red[3];
  sq = red[4] + red[5] + red[6] + red[7];
  const float mean = sum * (1.f / EMB);
  const float var = sq * (1.f / EMB) - mean * mean;
  const float rstd = rsqrtf(var + 1e-5f);
  float4 gv = ((const float4*)g)[t];
  float4 sv = ((const float4*)s)[t];
  float gg[4] = {gv.x, gv.y, gv.z, gv.w};
  float ss[4] = {sv.x, sv.y, sv.z, sv.w};
  u16x4 ov;
#pragma unroll
  for (int i = 0; i < 4; i++) ov[i] = f2b((f[i] - mean) * rstd * gg[i] + ss[i]);
  *(u16x4*)(out + (size_t)row * EMB + t * 4) = ov;
}

// ------ Merged: ALL 6 weight transposes + LN1 in ONE dispatch ------------
__global__ __launch_bounds__(256) void trln_k(const float* __restrict__ Wq, const float* __restrict__ Wk,
                                              const float* __restrict__ Wv, const float* __restrict__ Wo,
                                              const float* __restrict__ W1, const float* __restrict__ W2,
                                              u16t* __restrict__ WqkvT, u16t* __restrict__ WoT,
                                              u16t* __restrict__ W1T, u16t* __restrict__ W2T,
                                              const float* __restrict__ x, const float* __restrict__ g1,
                                              const float* __restrict__ s1, u16t* __restrict__ hln) {
  int t = blockIdx.x;
  if (t >= 12288) {
    // ---- LN1 part: one block per row ----
    const int row = t - 12288;
    const int tt = threadIdx.x;
    const float4* xr = (const float4*)(x + (size_t)row * EMB);
    float4 xv = xr[tt];
    float f[4] = {xv.x, xv.y, xv.z, xv.w};
    float sum = 0.f, sq = 0.f;
#pragma unroll
    for (int i = 0; i < 4; i++) { sum += f[i]; sq += f[i] * f[i]; }
#pragma unroll
    for (int off = 1; off < 64; off <<= 1) { sum += __shfl_xor(sum, off); sq += __shfl_xor(sq, off); }
    __shared__ float red[8];
    const int lane = tt & 63, wave = tt >> 6;
    if (lane == 0) { red[wave] = sum; red[4 + wave] = sq; }
    __syncthreads();
    sum = red[0] + red[1] + red[2] + red[3];
    sq = red[4] + red[5] + red[6] + red[7];
    const float mean = sum * (1.f / EMB);
    const float var = sq * (1.f / EMB) - mean * mean;
    const float rstd = rsqrtf(var + 1e-5f);
    float4 gv = ((const float4*)g1)[tt];
    float4 sv = ((const float4*)s1)[tt];
    float gg[4] = {gv.x, gv.y, gv.z, gv.w};
    float ss[4] = {sv.x, sv.y, sv.z, sv.w};
    u16x4 ov;
#pragma unroll
    for (int i = 0; i < 4; i++) ov[i] = f2b((f[i] - mean) * rstd * gg[i] + ss[i]);
    *(u16x4*)(hln + (size_t)row * EMB + tt * 4) = ov;
    return;
  }
  // ---- transpose part ----
  const float* in; u16t* out; int R, C;
  if (t < 4096) {
    R = EMB; C = EMB;
    const int seg = t >> 10; t &= 1023;
    if (seg == 0)      { in = Wq; out = WqkvT; }
    else if (seg == 1) { in = Wk; out = WqkvT + (size_t)EMB * EMB; }
    else if (seg == 2) { in = Wv; out = WqkvT + (size_t)2 * EMB * EMB; }
    else               { in = Wo; out = WoT; }
  } else if (t < 8192) {
    in = W1; out = W1T; R = EMB; C = FFD; t -= 4096;
  } else {
    in = W2; out = W2T; R = FFD; C = EMB; t -= 8192;
  }
  const int bx = t % (C >> 5), by = t / (C >> 5);

  __shared__ float tile[32][33];
  const int tx = threadIdx.x & 31, ty = threadIdx.x >> 5;
  const int c = bx * 32 + tx;
#pragma unroll
  for (int i = 0; i < 4; i++) {
    int r = by * 32 + ty + i * 8;
    tile[ty + i * 8][tx] = in[(size_t)r * C + c];
  }
  __syncthreads();
  const int r2 = by * 32 + tx;
#pragma unroll
  for (int i = 0; i < 4; i++) {
    int c2 = bx * 32 + ty + i * 8;
    out[(size_t)c2 * R + r2] = f2b(tile[tx][ty + i * 8]);
  }
}

// ---------------- V transpose: qkv V part -> vt[b*H+h][64][SEQN] ---------
__global__ __launch_bounds__(256) void vtr_k(const u16t* __restrict__ qkv, u16t* __restrict__ vt) {
  __shared__ u16t tile[32][33];
  const int tx = threadIdx.x & 31, ty = threadIdx.x >> 5;  // 32 x 8
  const int k0 = blockIdx.x * 32;
  const int d0 = blockIdx.y * 32;
  const int bh = blockIdx.z;
  const int b = bh / HEADS, h = bh % HEADS;
  const u16t* src = qkv + (size_t)b * SEQN * (3 * EMB) + 2 * EMB + h * HDIM;
#pragma unroll
  for (int i = 0; i < 4; i++)
    tile[ty + i * 8][tx] = src[(size_t)(k0 + ty + i * 8) * (3 * EMB) + d0 + tx];
  __syncthreads();
  u16t* dst = vt + ((size_t)bh * HDIM + d0) * SEQN + k0;
#pragma unroll
  for (int i = 0; i < 4; i++)
    dst[(size_t)(ty + i * 8) * SEQN + tx] = tile[tx][ty + i * 8];
}

// ------- GEMM 256x256 tile: 4-phase, T2 swizzle, counted vmcnt -----------
// Measured ~1250 TF warm (FF1 27.5us) -- keep for QKV/FF1 (wide-N shapes).
template <bool GELU, bool BIAS, bool OUTF32>
__global__ __launch_bounds__(512, 2) void gemm256_k(const u16t* __restrict__ A, const u16t* __restrict__ Bt,
                                                    const float* __restrict__ bias, void* __restrict__ C_,
                                                    int M, int N, int K) {
  __shared__ u16t As[2][256 * 64];
  __shared__ u16t Bs[2][256 * 64];
  const int tid = threadIdx.x;
  const int lane = tid & 63, wave = tid >> 6;
  const int wr = wave >> 2, wc = wave & 3;  // 2 x 4 waves
  const int nwg = gridDim.x, per = nwg >> 3;
  const int swz = (blockIdx.x & 7) * per + (blockIdx.x >> 3);
  const int nx = N >> 8;
  const int m0 = (swz / nx) * 256, n0 = (swz % nx) * 256;
  f32x4 acc[8][4] = {};
  const int nk = K >> 6;

  // stage one 128-row half (2 loads/thread) of the A or B tile
  auto stageA = [&](int t, int buf, int h) {
    const int k0 = t << 6;
#pragma unroll
    for (int i = 0; i < 2; i++) {
      unsigned P = (h * 2 + i) * 8192 + tid * 16;
      unsigned row = P >> 7, slot = ((P >> 4) & 7) ^ (row & 7);
      gload16(A + (size_t)(m0 + row) * K + k0 + slot * 8, &As[buf][P >> 1]);
    }
  };
  auto stageB = [&](int t, int buf, int h) {
    const int k0 = t << 6;
#pragma unroll
    for (int i = 0; i < 2; i++) {
      unsigned P = (h * 2 + i) * 8192 + tid * 16;
      unsigned row = P >> 7, slot = ((P >> 4) & 7) ^ (row & 7);
      gload16(Bt + (size_t)(n0 + row) * K + k0 + slot * 8, &Bs[buf][P >> 1]);
    }
  };

  // prologue: tile0 A+B, tile1 B (B of buf[1] is only read at tile1 phase 0)
  stageA(0, 0, 0); stageA(0, 0, 1);
  stageB(0, 0, 0); stageB(0, 0, 1);
  if (nk > 1) {
    stageB(1, 1, 0); stageB(1, 1, 1);
    asm volatile("s_waitcnt vmcnt(4)" ::: "memory");  // A(0),B(0) done; B(1) in flight
  } else {
    asm volatile("s_waitcnt vmcnt(0)" ::: "memory");
  }
  __builtin_amdgcn_s_barrier();

  for (int t = 0; t < nk; t++) {
    const int cur = t & 1;
    const u16t* Asc = As[cur];
    const u16t* Bsc = Bs[cur];
    auto rdA = [&](int mi, int kc) -> bf16x8 {
      unsigned row = wr * 128 + mi * 16 + (lane & 15);
      unsigned slot = ((unsigned)(kc * 4 + (lane >> 4))) ^ (row & 7);
      return *(const bf16x8*)&Asc[row * 64 + slot * 8];
    };
    // ---- phase 0 ----
    bf16x8 bfr[4][2];
#pragma unroll
    for (int ni = 0; ni < 4; ni++)
#pragma unroll
      for (int kc = 0; kc < 2; kc++) {
        unsigned row = wc * 64 + ni * 16 + (lane & 15);
        unsigned slot = ((unsigned)(kc * 4 + (lane >> 4))) ^ (row & 7);
        bfr[ni][kc] = *(const bf16x8*)&Bsc[row * 64 + slot * 8];
      }
    bf16x8 aL0 = rdA(0, 0), aL1 = rdA(0, 1), aH0 = rdA(1, 0), aH1 = rdA(1, 1);
    if (t + 1 < nk) stageA(t + 1, cur ^ 1, 0);
    __builtin_amdgcn_s_barrier();
    __builtin_amdgcn_s_setprio(1);
#pragma unroll
    for (int ni = 0; ni < 4; ni++) {
      acc[0][ni] = __builtin_amdgcn_mfma_f32_16x16x32_bf16(aL0, bfr[ni][0], acc[0][ni], 0, 0, 0);
      acc[0][ni] = __builtin_amdgcn_mfma_f32_16x16x32_bf16(aL1, bfr[ni][1], acc[0][ni], 0, 0, 0);
      acc[1][ni] = __builtin_amdgcn_mfma_f32_16x16x32_bf16(aH0, bfr[ni][0], acc[1][ni], 0, 0, 0);
      acc[1][ni] = __builtin_amdgcn_mfma_f32_16x16x32_bf16(aH1, bfr[ni][1], acc[1][ni], 0, 0, 0);
    }
    __builtin_amdgcn_s_setprio(0);
    __builtin_amdgcn_s_barrier();
    // ---- phase 1 ----
    aL0 = rdA(2, 0); aL1 = rdA(2, 1); aH0 = rdA(3, 0); aH1 = rdA(3, 1);
    if (t + 1 < nk) stageA(t + 1, cur ^ 1, 1);
    __builtin_amdgcn_s_barrier();
    __builtin_amdgcn_s_setprio(1);
#pragma unroll
    for (int ni = 0; ni < 4; ni++) {
      acc[2][ni] = __builtin_amdgcn_mfma_f32_16x16x32_bf16(aL0, bfr[ni][0], acc[2][ni], 0, 0, 0);
      acc[2][ni] = __builtin_amdgcn_mfma_f32_16x16x32_bf16(aL1, bfr[ni][1], acc[2][ni], 0, 0, 0);
      acc[3][ni] = __builtin_amdgcn_mfma_f32_16x16x32_bf16(aH0, bfr[ni][0], acc[3][ni], 0, 0, 0);
      acc[3][ni] = __builtin_amdgcn_mfma_f32_16x16x32_bf16(aH1, bfr[ni][1], acc[3][ni], 0, 0, 0);
    }
    __builtin_amdgcn_s_setprio(0);
    __builtin_amdgcn_s_barrier();
    // ---- phase 2 ----
    aL0 = rdA(4, 0); aL1 = rdA(4, 1); aH0 = rdA(5, 0); aH1 = rdA(5, 1);
    if (t + 2 < nk) stageB(t + 2, cur, 0);  // Bs[cur] B-frags already in regs
    __builtin_amdgcn_s_barrier();
    __builtin_amdgcn_s_setprio(1);
#pragma unroll
    for (int ni = 0; ni < 4; ni++) {
      acc[4][ni] = __builtin_amdgcn_mfma_f32_16x16x32_bf16(aL0, bfr[ni][0], acc[4][ni], 0, 0, 0);
      acc[4][ni] = __builtin_amdgcn_mfma_f32_16x16x32_bf16(aL1, bfr[ni][1], acc[4][ni], 0, 0, 0);
      acc[5][ni] = __builtin_amdgcn_mfma_f32_16x16x32_bf16(aH0, bfr[ni][0], acc[5][ni], 0, 0, 0);
      acc[5][ni] = __builtin_amdgcn_mfma_f32_16x16x32_bf16(aH1, bfr[ni][1], acc[5][ni], 0, 0, 0);
    }
    __builtin_amdgcn_s_setprio(0);
    __builtin_amdgcn_s_barrier();
    // ---- phase 3 ----
    aL0 = rdA(6, 0); aL1 = rdA(6, 1); aH0 = rdA(7, 0); aH1 = rdA(7, 1);
    if (t + 2 < nk) stageB(t + 2, cur, 1);
    if (t + 2 < nk)      asm volatile("s_waitcnt vmcnt(4)" ::: "memory");
    else if (t + 1 < nk) asm volatile("s_waitcnt vmcnt(0)" ::: "memory");
    __builtin_amdgcn_s_barrier();
    __builtin_amdgcn_s_setprio(1);
#pragma unroll
    for (int ni = 0; ni < 4; ni++) {
      acc[6][ni] = __builtin_amdgcn_mfma_f32_16x16x32_bf16(aL0, bfr[ni][0], acc[6][ni], 0, 0, 0);
      acc[6][ni] = __builtin_amdgcn_mfma_f32_16x16x32_bf16(aL1, bfr[ni][1], acc[6][ni], 0, 0, 0);
      acc[7][ni] = __builtin_amdgcn_mfma_f32_16x16x32_bf16(aH0, bfr[ni][0], acc[7][ni], 0, 0, 0);
      acc[7][ni] = __builtin_amdgcn_mfma_f32_16x16x32_bf16(aH1, bfr[ni][1], acc[7][ni], 0, 0, 0);
    }
    __builtin_amdgcn_s_setprio(0);
    __builtin_amdgcn_s_barrier();
  }

#pragma unroll
  for (int mi = 0; mi < 8; mi++) {
#pragma unroll
    for (int ni = 0; ni < 4; ni++) {
      int col = n0 + wc * 64 + ni * 16 + (lane & 15);
      int rb = m0 + wr * 128 + mi * 16 + ((lane >> 4) << 2);
      float bv = 0.f;
      if (BIAS) bv = bias[col];
#pragma unroll
      for (int r = 0; r < 4; r++) {
        float v = acc[mi][ni][r] + bv;
        if (GELU) v = gelu_f(v);
        size_t idx = (size_t)(rb + r) * N + col;
        if (OUTF32) ((float*)C_)[idx] = v;
        else ((u16t*)C_)[idx] = f2b(v);
      }
    }
  }
}

// -------- GEMM 128x64 (N=1024 shapes): 3-stage ring, counted vmcnt, T2 ---
// Geometric optimum for N=1024 at 2 blk/CU (FLOP/ds_read = 1024MN/(M+N);
// 64x64/wave needs 128x128 blocks -> 1 blk/CU -> R7 regression). Keep.
template <int BN, bool GELU, bool RESID, bool BIAS, bool RESF32, bool OUTF32>
__global__ __launch_bounds__(256) void gemm_k(const u16t* __restrict__ A, const u16t* __restrict__ Bt,
                                              const float* __restrict__ bias, const void* __restrict__ res_,
                                              void* __restrict__ C_, int M, int N, int K) {
  constexpr int NF = BN / 32;
  static_assert(BN == 64, "vmcnt count assumes 6 loads/stage");
  __shared__ u16t As[3][128 * 64];
  __shared__ u16t Bs[3][BN * 64];
  const int tid = threadIdx.x;
  const int lane = tid & 63;
  const int wave = tid >> 6;
  const int nx = N / BN, pnx = nx >> 3;
  const int bid = blockIdx.x;
  const int xcd = bid & 7, idx = bid >> 3;
  const int n0 = (xcd * pnx + (idx % pnx)) * BN;
  const int m0 = (idx / pnx) * 128;
  const int wm = (wave >> 1) * 64, wn = (wave & 1) * (BN / 2);
  f32x4 acc[4][NF] = {};
  const int nk = K >> 6;

  auto stage = [&](int t, int buf) {
    const int k0 = t << 6;
#pragma unroll
    for (int i = 0; i < 4; i++) {
      unsigned P = i * 4096 + tid * 16;
      unsigned row = P >> 7, slot = ((P >> 4) & 7) ^ (row & 7);
      gload16(A + (size_t)(m0 + row) * K + k0 + slot * 8, &As[buf][P >> 1]);
    }
#pragma unroll
    for (int i = 0; i < BN / 32; i++) {
      unsigned P = i * 4096 + tid * 16;
      unsigned row = P >> 7, slot = ((P >> 4) & 7) ^ (row & 7);
      gload16(Bt + (size_t)(n0 + row) * K + k0 + slot * 8, &Bs[buf][P >> 1]);
    }
  };

  stage(0, 0);
  if (nk > 1) stage(1, 1);

  for (int t = 0; t < nk; t++) {
    if (t + 1 < nk) asm volatile("s_waitcnt vmcnt(6)" ::: "memory");
    else            asm volatile("s_waitcnt vmcnt(0)" ::: "memory");
    __builtin_amdgcn_s_barrier();
    const int cur = t % 3;
#pragma unroll
    for (int kc = 0; kc < 2; kc++) {
      bf16x8 af[4], bf[NF];
#pragma unroll
      for (int mi = 0; mi < 4; mi++) {
        unsigned row = wm + mi * 16 + (lane & 15);
        unsigned slot = ((unsigned)(kc * 4 + (lane >> 4))) ^ (row & 7);
        af[mi] = *(const bf16x8*)&As[cur][row * 64 + slot * 8];
      }
#pragma unroll
      for (int ni = 0; ni < NF; ni++) {
        unsigned row = wn + ni * 16 + (lane & 15);
        unsigned slot = ((unsigned)(kc * 4 + (lane >> 4))) ^ (row & 7);
        bf[ni] = *(const bf16x8*)&Bs[cur][row * 64 + slot * 8];
      }
      __builtin_amdgcn_s_setprio(1);
#pragma unroll
      for (int mi = 0; mi < 4; mi++)
#pragma unroll
        for (int ni = 0; ni < NF; ni++)
          acc[mi][ni] = __builtin_amdgcn_mfma_f32_16x16x32_bf16(af[mi], bf[ni], acc[mi][ni], 0, 0, 0);
      __builtin_amdgcn_s_setprio(0);
    }
    if (t + 2 < nk) stage(t + 2, (t + 2) % 3);
  }

#pragma unroll
  for (int mi = 0; mi < 4; mi++) {
#pragma unroll
    for (int ni = 0; ni < NF; ni++) {
      int col = n0 + wn + ni * 16 + (lane & 15);
      int rb = m0 + wm + mi * 16 + ((lane >> 4) << 2);
      float bv = 0.f;
      if (BIAS) bv = bias[col];
#pragma unroll
      for (int r = 0; r < 4; r++) {
        float v = acc[mi][ni][r] + bv;
        if (GELU) v = gelu_f(v);
        size_t idx = (size_t)(rb + r) * N + col;
        if (RESID) v += RESF32 ? ((const float*)res_)[idx] : b2f(((const u16t*)res_)[idx]);
        if (OUTF32) ((float*)C_)[idx] = v;
        else ((u16t*)C_)[idx] = f2b(v);
      }
    }
  }
}

// -- Flash attention (causal), KVBLK=64, abs softmax ----------------------
// R8 structure (dbuf K/V, one barrier/tile, truncating P, exp2-direct).
// R11: K/V staging via global_load_lds DMA (same pre-swizzled source
// addressing -> byte-identical LDS content). Removes 8 ds_write_b128 per
// wave per tile from the LDS issue pipe (attn is LDS-throughput-bound:
// ~1900cy LDS vs ~660cy MFMA per block-tile) and frees 8 VGPRs.
__global__ __launch_bounds__(256) void attn_k(const u16t* __restrict__ qkv,
                                              const u16t* __restrict__ vt,
                                              u16t* __restrict__ ctx) {
  const int b = blockIdx.z, h = blockIdx.y;
  const int tid = threadIdx.x, lane = tid & 63, wave = tid >> 6;
  const int bx = (b == 1) ? (gridDim.x - 1 - blockIdx.x) : blockIdx.x;  // causal balance
  const int q0 = bx * 128 + wave * 32;
  const int ld = 3 * EMB;
  const u16t* Qp = qkv + (size_t)b * SEQN * ld + h * HDIM;
  const u16t* Kp = Qp + EMB;
  const u16t* VTp = vt + (size_t)(b * HEADS + h) * HDIM * SEQN;  // [64][SEQN]

  __shared__ u16t Ks[2][64 * 64];
  __shared__ u16t Vs[2][64 * 64];
  __shared__ u16t Ps[4][32][72];

  bf16x8 qf[2][2];
#pragma unroll
  for (int mi = 0; mi < 2; mi++)
#pragma unroll
    for (int kc = 0; kc < 2; kc++) {
      u16x8 qraw = *(const u16x8*)(Qp + (size_t)(q0 + mi * 16 + (lane & 15)) * ld + kc * 32 + (lane >> 4) * 8);
      u16x8 qs;
#pragma unroll
      for (int j = 0; j < 8; j++) qs[j] = f2b(b2f(qraw[j]) * 0.18033688011112042f);  // (1/8)*log2(e)
      qf[mi][kc] = __builtin_bit_cast(bf16x8, qs);
    }

  u16x8 onesu;
#pragma unroll
  for (int j = 0; j < 8; j++) onesu[j] = 0x3F80;  // bf16 1.0
  const bf16x8 ones = __builtin_bit_cast(bf16x8, onesu);

  f32x4 o[2][4] = {};
  f32x4 ls[2] = {};

  // DMA staging: per-lane global src (pre-swizzled), linear LDS dest
  // (base + lane*16 within wave -- the required global_load_lds pattern).
  auto stageKV = [&](int kt, int buf) {
    const int kb = kt * 64;
#pragma unroll
    for (int i = 0; i < 2; i++) {
      unsigned P = i * 4096 + tid * 16;
      unsigned row = P >> 7;
      unsigned slot = ((P >> 4) & 7) ^ (row & 7);
      gload16(Kp + (size_t)(kb + row) * ld + slot * 8, &Ks[buf][P >> 1]);
      gload16(VTp + (size_t)row * SEQN + kb + slot * 8, &Vs[buf][P >> 1]);
    }
  };

  const int ntiles = 2 * bx + 2;
  // prologue: tile 0 into LDS buf 0
  stageKV(0, 0);
  asm volatile("s_waitcnt vmcnt(0)" ::: "memory");
  __builtin_amdgcn_s_barrier();

  for (int kt = 0; kt < ntiles; kt++) {
    const int kb = kt * 64;
    const int cur = kt & 1;
    // DMA tile kt+1 into the other buffer; its readers (iter kt-1) all
    // cleared the previous barrier. Latency covered by compute below.
    if (kt + 1 < ntiles) stageKV(kt + 1, cur ^ 1);

    if (kb <= q0 + 31) {
      f32x4 st[2][4] = {};
      __builtin_amdgcn_s_setprio(1);
#pragma unroll
      for (int ni = 0; ni < 4; ni++) {
#pragma unroll
        for (int kc = 0; kc < 2; kc++) {
          unsigned row = ni * 16 + (lane & 15);
          unsigned slot = ((unsigned)(kc * 4 + (lane >> 4))) ^ (row & 7);
          bf16x8 bfr = *(const bf16x8*)&Ks[cur][row * 64 + slot * 8];
          st[0][ni] = __builtin_amdgcn_mfma_f32_16x16x32_bf16(qf[0][kc], bfr, st[0][ni], 0, 0, 0);
          st[1][ni] = __builtin_amdgcn_mfma_f32_16x16x32_bf16(qf[1][kc], bfr, st[1][ni], 0, 0, 0);
        }
      }
      __builtin_amdgcn_s_setprio(0);

      if (kb + 63 > q0) {
#pragma unroll
        for (int mi = 0; mi < 2; mi++)
#pragma unroll
          for (int ni = 0; ni < 4; ni++) {
            int kk = kb + ni * 16 + (lane & 15);
#pragma unroll
            for (int r = 0; r < 4; r++) {
              int qq = q0 + mi * 16 + ((lane >> 4) << 2) + r;
              if (kk > qq) st[mi][ni][r] = -1e30f;
            }
          }
      }

#pragma unroll
      for (int mi = 0; mi < 2; mi++)
#pragma unroll
        for (int ni = 0; ni < 4; ni++)
#pragma unroll
          for (int r = 0; r < 4; r++) {
            union { float f; unsigned int u; } pv;
            // exp2 direct: S' already includes log2(e)/8 via Q pre-scale
            asm("v_exp_f32 %0, %1" : "=v"(pv.f) : "v"(st[mi][ni][r]));
            Ps[wave][mi * 16 + ((lane >> 4) << 2) + r][ni * 16 + (lane & 15)] =
                (u16t)(pv.u >> 16);  // truncating bf16
          }

      bf16x8 pa[2][2];
#pragma unroll
      for (int mi = 0; mi < 2; mi++)
#pragma unroll
        for (int kc = 0; kc < 2; kc++)
          pa[mi][kc] = *(const bf16x8*)&Ps[wave][mi * 16 + (lane & 15)][kc * 32 + (lane >> 4) * 8];

      __builtin_amdgcn_s_setprio(1);
#pragma unroll
      for (int di = 0; di < 4; di++) {
#pragma unroll
        for (int kc = 0; kc < 2; kc++) {
          unsigned row = di * 16 + (lane & 15);
          unsigned slot = ((unsigned)(kc * 4 + (lane >> 4))) ^ (row & 7);
          bf16x8 vf = *(const bf16x8*)&Vs[cur][row * 64 + slot * 8];
          o[0][di] = __builtin_amdgcn_mfma_f32_16x16x32_bf16(pa[0][kc], vf, o[0][di], 0, 0, 0);
          o[1][di] = __builtin_amdgcn_mfma_f32_16x16x32_bf16(pa[1][kc], vf, o[1][di], 0, 0, 0);
        }
      }
#pragma unroll
      for (int kc = 0; kc < 2; kc++) {
        ls[0] = __builtin_amdgcn_mfma_f32_16x16x32_bf16(pa[0][kc], ones, ls[0], 0, 0, 0);
        ls[1] = __builtin_amdgcn_mfma_f32_16x16x32_bf16(pa[1][kc], ones, ls[1], 0, 0, 0);
      }
      __builtin_amdgcn_s_setprio(0);
    }

    // per-wave: own DMAs (tile kt+1) landed; barrier: all waves' DMAs
    // landed AND all readers of buf cur are done -> safe to proceed.
    asm volatile("s_waitcnt vmcnt(0)" ::: "memory");
    __builtin_amdgcn_s_barrier();
  }

  u16t* Cp = ctx + (size_t)b * SEQN * EMB + h * HDIM;
#pragma unroll
  for (int mi = 0; mi < 2; mi++)
#pragma unroll
    for (int r = 0; r < 4; r++) {
      float inv = 1.f / ls[mi][r];
      int qq = q0 + mi * 16 + ((lane >> 4) << 2) + r;
#pragma unroll
      for (int di = 0; di < 4; di++)
        Cp[(size_t)qq * EMB + di * 16 + (lane & 15)] = f2b(o[mi][di][r] * inv);
    }
}

// -------------------------------------------------------------------------
extern "C" void kernel_launch(void* const* d_in, const int* in_sizes, int n_in,
                              void* d_out, int out_size, void* d_ws, size_t ws_size,
                              hipStream_t stream) {
  const float* x  = (const float*)d_in[0];
  const float* Wq = (const float*)d_in[1];
  const float* Wk = (const float*)d_in[2];
  const float* Wv = (const float*)d_in[3];
  const float* Wo = (const float*)d_in[4];
  const float* bo = (const float*)d_in[5];
  const float* W1 = (const float*)d_in[6];
  const float* b1 = (const float*)d_in[7];
  const float* W2 = (const float*)d_in[8];
  const float* b2 = (const float*)d_in[9];
  const float* g1 = (const float*)d_in[10];
  const float* s1 = (const float*)d_in[11];
  const float* g2 = (const float*)d_in[12];
  const float* s2 = (const float*)d_in[13];
  float* out = (float*)d_out;  // reference output dtype is float32

  // workspace layout (64 MiB total).
  // ALIAS MAP (liveness!):
  //   ff1 = qkvb..qkvb+32MB => covers qkvb(24MB) AND ctxb(8MB); live to FF2 end.
  //   vtb = hln (dead between QKV-GEMM and LN2); hln dead after FF1 reads it.
  char* p = (char*)d_ws;
  u16t* WqkvT = (u16t*)p; p += (size_t)3 * EMB * EMB * 2;   // [3072][1024]
  u16t* WoT   = (u16t*)p; p += (size_t)EMB * EMB * 2;       // [1024][1024]
  u16t* W1T   = (u16t*)p; p += (size_t)FFD * EMB * 2;       // [4096][1024]
  u16t* W2T   = (u16t*)p; p += (size_t)EMB * FFD * 2;       // [1024][4096]
  u16t* hln   = (u16t*)p; p += (size_t)ROWS * EMB * 2;      // [4096][1024]
  u16t* qkvb  = (u16t*)p; p += (size_t)ROWS * 3 * EMB * 2;  // [4096][3072]
  u16t* ctxb  = (u16t*)p; p += (size_t)ROWS * EMB * 2;      // [4096][1024]
  u16t* ff1   = qkvb;  // [4096][4096] aliases qkv(24MB)+ctx(8MB)
  u16t* vtb   = hln;   // [32][64][2048] aliases hln

  dim3 blk(256);
  // merged transposes + LN1 (blocks >= 12288 run LN rows)
  trln_k<<<dim3(12288 + ROWS), blk, 0, stream>>>(Wq, Wk, Wv, Wo, W1, W2,
                                                 WqkvT, WoT, W1T, W2T, x, g1, s1, hln);
  gemm256_k<false, false, false><<<dim3((3 * EMB / 256) * (ROWS / 256)), dim3(512), 0, stream>>>(
      hln, WqkvT, nullptr, qkvb, ROWS, 3 * EMB, EMB);
  vtr_k<<<dim3(SEQN / 32, HDIM / 32, BATCH * HEADS), blk, 0, stream>>>(qkvb, vtb);
  attn_k<<<dim3(SEQN / 128, HEADS, BATCH), blk, 0, stream>>>(qkvb, vtb, ctxb);
  gemm_k<64, false, true, true, true, true><<<dim3((EMB / 64) * (ROWS / 128)), blk, 0, stream>>>(
      ctxb, WoT, bo, x, out, ROWS, EMB, EMB);
  ln_k<true><<<ROWS, blk, 0, stream>>>(out, g2, s2, hln);
  gemm256_k<true, true, false><<<dim3((FFD / 256) * (ROWS / 256)), dim3(512), 0, stream>>>(
      hln, W1T, b1, ff1, ROWS, FFD, EMB);
  gemm_k<64, false, true, true, true, true><<<dim3((EMB / 64) * (ROWS / 128)), blk, 0, stream>>>(
      ff1, W2T, b2, out, out, ROWS, EMB, FFD);
}

// Round 12
// 220.810 us; speedup vs baseline: 1.0324x; 1.0324x over previous
//
#include <hip/hip_runtime.h>
#include <stdint.h>

#define EMB 1024
#define HEADS 16
#define HDIM 64
#define SEQN 2048
#define BATCH 2
#define FFD 4096
#define ROWS (BATCH * SEQN)

typedef unsigned short u16t;
typedef __attribute__((ext_vector_type(4))) unsigned short u16x4;
typedef __attribute__((ext_vector_type(8))) unsigned short u16x8;
typedef __attribute__((ext_vector_type(8))) __bf16 bf16x8;
typedef __attribute__((ext_vector_type(4))) float f32x4;

__device__ __forceinline__ float b2f(u16t u) {
  union { float f; unsigned int i; } v; v.i = ((unsigned int)u) << 16; return v.f;
}
__device__ __forceinline__ u16t f2b(float f) {
  union { float f; unsigned int i; } v; v.f = f;
  unsigned int r = v.i + 0x7FFFu + ((v.i >> 16) & 1u);
  return (u16t)(r >> 16);
}

// gelu_tanh via sigmoid identity: 0.5v(1+tanh(t)) = v/(1+e^{-2t}).
// Confirmed: warm pipeline gain ~21 us vs libm tanhf (R1 vs R6).
__device__ __forceinline__ float gelu_f(float v) {
  float t2 = 1.5957691216057308f * (v + 0.044715f * v * v * v);  // 2*sqrt(2/pi)*(...)
  return v / (1.f + __expf(-t2));
}

__device__ __forceinline__ void gload16(const u16t* g, u16t* l) {
  __builtin_amdgcn_global_load_lds((const __attribute__((address_space(1))) void*)g,
                                   (__attribute__((address_space(3))) void*)l, 16, 0, 0);
}

// ---------------- LayerNorm: one block per row (1024 cols) ----------------
template <bool INF32>
__global__ __launch_bounds__(256) void ln_k(const void* __restrict__ x_, const float* __restrict__ g,
                                            const float* __restrict__ s, u16t* __restrict__ out) {
  const int row = blockIdx.x;
  const int t = threadIdx.x;
  float f[4];
  if (INF32) {
    const float4* xr = (const float4*)((const float*)x_ + (size_t)row * EMB);
    float4 xv = xr[t];
    f[0] = xv.x; f[1] = xv.y; f[2] = xv.z; f[3] = xv.w;
  } else {
    const u16t* xr = (const u16t*)x_ + (size_t)row * EMB;
    u16x4 xv = *(const u16x4*)(xr + t * 4);
#pragma unroll
    for (int i = 0; i < 4; i++) f[i] = b2f(xv[i]);
  }
  float sum = 0.f, sq = 0.f;
#pragma unroll
  for (int i = 0; i < 4; i++) { sum += f[i]; sq += f[i] * f[i]; }
#pragma unroll
  for (int off = 1; off < 64; off <<= 1) { sum += __shfl_xor(sum, off); sq += __shfl_xor(sq, off); }
  __shared__ float red[8];
  const int lane = t & 63, wave = t >> 6;
  if (lane == 0) { red[wave] = sum; red[4 + wave] = sq; }
  __syncthreads();
  sum = red[0] + red[1] + red[2] + red[3];
  sq = red[4] + red[5] + red[6] + red[7];
  const float mean = sum * (1.f / EMB);
  const float var = sq * (1.f / EMB) - mean * mean;
  const float rstd = rsqrtf(var + 1e-5f);
  float4 gv = ((const float4*)g)[t];
  float4 sv = ((const float4*)s)[t];
  float gg[4] = {gv.x, gv.y, gv.z, gv.w};
  float ss[4] = {sv.x, sv.y, sv.z, sv.w};
  u16x4 ov;
#pragma unroll
  for (int i = 0; i < 4; i++) ov[i] = f2b((f[i] - mean) * rstd * gg[i] + ss[i]);
  *(u16x4*)(out + (size_t)row * EMB + t * 4) = ov;
}

// ------ Merged: ALL 6 weight transposes + LN1 in ONE dispatch ------------
__global__ __launch_bounds__(256) void trln_k(const float* __restrict__ Wq, const float* __restrict__ Wk,
                                              const float* __restrict__ Wv, const float* __restrict__ Wo,
                                              const float* __restrict__ W1, const float* __restrict__ W2,
                                              u16t* __restrict__ WqkvT, u16t* __restrict__ WoT,
                                              u16t* __restrict__ W1T, u16t* __restrict__ W2T,
                                              const float* __restrict__ x, const float* __restrict__ g1,
                                              const float* __restrict__ s1, u16t* __restrict__ hln) {
  int t = blockIdx.x;
  if (t >= 12288) {
    // ---- LN1 part: one block per row ----
    const int row = t - 12288;
    const int tt = threadIdx.x;
    const float4* xr = (const float4*)(x + (size_t)row * EMB);
    float4 xv = xr[tt];
    float f[4] = {xv.x, xv.y, xv.z, xv.w};
    float sum = 0.f, sq = 0.f;
#pragma unroll
    for (int i = 0; i < 4; i++) { sum += f[i]; sq += f[i] * f[i]; }
#pragma unroll
    for (int off = 1; off < 64; off <<= 1) { sum += __shfl_xor(sum, off); sq += __shfl_xor(sq, off); }
    __shared__ float red[8];
    const int lane = tt & 63, wave = tt >> 6;
    if (lane == 0) { red[wave] = sum; red[4 + wave] = sq; }
    __syncthreads();
    sum = red[0] + red[1] + red[2] + red[3];
    sq = red[4] + red[5] + red[6] + red[7];
    const float mean = sum * (1.f / EMB);
    const float var = sq * (1.f / EMB) - mean * mean;
    const float rstd = rsqrtf(var + 1e-5f);
    float4 gv = ((const float4*)g1)[tt];
    float4 sv = ((const float4*)s1)[tt];
    float gg[4] = {gv.x, gv.y, gv.z, gv.w};
    float ss[4] = {sv.x, sv.y, sv.z, sv.w};
    u16x4 ov;
#pragma unroll
    for (int i = 0; i < 4; i++) ov[i] = f2b((f[i] - mean) * rstd * gg[i] + ss[i]);
    *(u16x4*)(hln + (size_t)row * EMB + tt * 4) = ov;
    return;
  }
  // ---- transpose part ----
  const float* in; u16t* out; int R, C;
  if (t < 4096) {
    R = EMB; C = EMB;
    const int seg = t >> 10; t &= 1023;
    if (seg == 0)      { in = Wq; out = WqkvT; }
    else if (seg == 1) { in = Wk; out = WqkvT + (size_t)EMB * EMB; }
    else if (seg == 2) { in = Wv; out = WqkvT + (size_t)2 * EMB * EMB; }
    else               { in = Wo; out = WoT; }
  } else if (t < 8192) {
    in = W1; out = W1T; R = EMB; C = FFD; t -= 4096;
  } else {
    in = W2; out = W2T; R = FFD; C = EMB; t -= 8192;
  }
  const int bx = t % (C >> 5), by = t / (C >> 5);

  __shared__ float tile[32][33];
  const int tx = threadIdx.x & 31, ty = threadIdx.x >> 5;
  const int c = bx * 32 + tx;
#pragma unroll
  for (int i = 0; i < 4; i++) {
    int r = by * 32 + ty + i * 8;
    tile[ty + i * 8][tx] = in[(size_t)r * C + c];
  }
  __syncthreads();
  const int r2 = by * 32 + tx;
#pragma unroll
  for (int i = 0; i < 4; i++) {
    int c2 = bx * 32 + ty + i * 8;
    out[(size_t)c2 * R + r2] = f2b(tile[tx][ty + i * 8]);
  }
}

// ---------------- V transpose: qkv V part -> vt[b*H+h][64][SEQN] ---------
__global__ __launch_bounds__(256) void vtr_k(const u16t* __restrict__ qkv, u16t* __restrict__ vt) {
  __shared__ u16t tile[32][33];
  const int tx = threadIdx.x & 31, ty = threadIdx.x >> 5;  // 32 x 8
  const int k0 = blockIdx.x * 32;
  const int d0 = blockIdx.y * 32;
  const int bh = blockIdx.z;
  const int b = bh / HEADS, h = bh % HEADS;
  const u16t* src = qkv + (size_t)b * SEQN * (3 * EMB) + 2 * EMB + h * HDIM;
#pragma unroll
  for (int i = 0; i < 4; i++)
    tile[ty + i * 8][tx] = src[(size_t)(k0 + ty + i * 8) * (3 * EMB) + d0 + tx];
  __syncthreads();
  u16t* dst = vt + ((size_t)bh * HDIM + d0) * SEQN + k0;
#pragma unroll
  for (int i = 0; i < 4; i++)
    dst[(size_t)(ty + i * 8) * SEQN + tx] = tile[tx][ty + i * 8];
}

// ------- GEMM 256x256 tile: 4-phase, T2 swizzle, counted vmcnt -----------
// Measured ~1250 TF warm (FF1 27.5us) -- keep for QKV/FF1 (wide-N shapes).
template <bool GELU, bool BIAS, bool OUTF32>
__global__ __launch_bounds__(512, 2) void gemm256_k(const u16t* __restrict__ A, const u16t* __restrict__ Bt,
                                                    const float* __restrict__ bias, void* __restrict__ C_,
                                                    int M, int N, int K) {
  __shared__ u16t As[2][256 * 64];
  __shared__ u16t Bs[2][256 * 64];
  const int tid = threadIdx.x;
  const int lane = tid & 63, wave = tid >> 6;
  const int wr = wave >> 2, wc = wave & 3;  // 2 x 4 waves
  const int nwg = gridDim.x, per = nwg >> 3;
  const int swz = (blockIdx.x & 7) * per + (blockIdx.x >> 3);
  const int nx = N >> 8;
  const int m0 = (swz / nx) * 256, n0 = (swz % nx) * 256;
  f32x4 acc[8][4] = {};
  const int nk = K >> 6;

  // stage one 128-row half (2 loads/thread) of the A or B tile
  auto stageA = [&](int t, int buf, int h) {
    const int k0 = t << 6;
#pragma unroll
    for (int i = 0; i < 2; i++) {
      unsigned P = (h * 2 + i) * 8192 + tid * 16;
      unsigned row = P >> 7, slot = ((P >> 4) & 7) ^ (row & 7);
      gload16(A + (size_t)(m0 + row) * K + k0 + slot * 8, &As[buf][P >> 1]);
    }
  };
  auto stageB = [&](int t, int buf, int h) {
    const int k0 = t << 6;
#pragma unroll
    for (int i = 0; i < 2; i++) {
      unsigned P = (h * 2 + i) * 8192 + tid * 16;
      unsigned row = P >> 7, slot = ((P >> 4) & 7) ^ (row & 7);
      gload16(Bt + (size_t)(n0 + row) * K + k0 + slot * 8, &Bs[buf][P >> 1]);
    }
  };

  // prologue: tile0 A+B, tile1 B (B of buf[1] is only read at tile1 phase 0)
  stageA(0, 0, 0); stageA(0, 0, 1);
  stageB(0, 0, 0); stageB(0, 0, 1);
  if (nk > 1) {
    stageB(1, 1, 0); stageB(1, 1, 1);
    asm volatile("s_waitcnt vmcnt(4)" ::: "memory");  // A(0),B(0) done; B(1) in flight
  } else {
    asm volatile("s_waitcnt vmcnt(0)" ::: "memory");
  }
  __builtin_amdgcn_s_barrier();

  for (int t = 0; t < nk; t++) {
    const int cur = t & 1;
    const u16t* Asc = As[cur];
    const u16t* Bsc = Bs[cur];
    auto rdA = [&](int mi, int kc) -> bf16x8 {
      unsigned row = wr * 128 + mi * 16 + (lane & 15);
      unsigned slot = ((unsigned)(kc * 4 + (lane >> 4))) ^ (row & 7);
      return *(const bf16x8*)&Asc[row * 64 + slot * 8];
    };
    // ---- phase 0 ----
    bf16x8 bfr[4][2];
#pragma unroll
    for (int ni = 0; ni < 4; ni++)
#pragma unroll
      for (int kc = 0; kc < 2; kc++) {
        unsigned row = wc * 64 + ni * 16 + (lane & 15);
        unsigned slot = ((unsigned)(kc * 4 + (lane >> 4))) ^ (row & 7);
        bfr[ni][kc] = *(const bf16x8*)&Bsc[row * 64 + slot * 8];
      }
    bf16x8 aL0 = rdA(0, 0), aL1 = rdA(0, 1), aH0 = rdA(1, 0), aH1 = rdA(1, 1);
    if (t + 1 < nk) stageA(t + 1, cur ^ 1, 0);
    __builtin_amdgcn_s_barrier();
    __builtin_amdgcn_s_setprio(1);
#pragma unroll
    for (int ni = 0; ni < 4; ni++) {
      acc[0][ni] = __builtin_amdgcn_mfma_f32_16x16x32_bf16(aL0, bfr[ni][0], acc[0][ni], 0, 0, 0);
      acc[0][ni] = __builtin_amdgcn_mfma_f32_16x16x32_bf16(aL1, bfr[ni][1], acc[0][ni], 0, 0, 0);
      acc[1][ni] = __builtin_amdgcn_mfma_f32_16x16x32_bf16(aH0, bfr[ni][0], acc[1][ni], 0, 0, 0);
      acc[1][ni] = __builtin_amdgcn_mfma_f32_16x16x32_bf16(aH1, bfr[ni][1], acc[1][ni], 0, 0, 0);
    }
    __builtin_amdgcn_s_setprio(0);
    __builtin_amdgcn_s_barrier();
    // ---- phase 1 ----
    aL0 = rdA(2, 0); aL1 = rdA(2, 1); aH0 = rdA(3, 0); aH1 = rdA(3, 1);
    if (t + 1 < nk) stageA(t + 1, cur ^ 1, 1);
    __builtin_amdgcn_s_barrier();
    __builtin_amdgcn_s_setprio(1);
#pragma unroll
    for (int ni = 0; ni < 4; ni++) {
      acc[2][ni] = __builtin_amdgcn_mfma_f32_16x16x32_bf16(aL0, bfr[ni][0], acc[2][ni], 0, 0, 0);
      acc[2][ni] = __builtin_amdgcn_mfma_f32_16x16x32_bf16(aL1, bfr[ni][1], acc[2][ni], 0, 0, 0);
      acc[3][ni] = __builtin_amdgcn_mfma_f32_16x16x32_bf16(aH0, bfr[ni][0], acc[3][ni], 0, 0, 0);
      acc[3][ni] = __builtin_amdgcn_mfma_f32_16x16x32_bf16(aH1, bfr[ni][1], acc[3][ni], 0, 0, 0);
    }
    __builtin_amdgcn_s_setprio(0);
    __builtin_amdgcn_s_barrier();
    // ---- phase 2 ----
    aL0 = rdA(4, 0); aL1 = rdA(4, 1); aH0 = rdA(5, 0); aH1 = rdA(5, 1);
    if (t + 2 < nk) stageB(t + 2, cur, 0);  // Bs[cur] B-frags already in regs
    __builtin_amdgcn_s_barrier();
    __builtin_amdgcn_s_setprio(1);
#pragma unroll
    for (int ni = 0; ni < 4; ni++) {
      acc[4][ni] = __builtin_amdgcn_mfma_f32_16x16x32_bf16(aL0, bfr[ni][0], acc[4][ni], 0, 0, 0);
      acc[4][ni] = __builtin_amdgcn_mfma_f32_16x16x32_bf16(aL1, bfr[ni][1], acc[4][ni], 0, 0, 0);
      acc[5][ni] = __builtin_amdgcn_mfma_f32_16x16x32_bf16(aH0, bfr[ni][0], acc[5][ni], 0, 0, 0);
      acc[5][ni] = __builtin_amdgcn_mfma_f32_16x16x32_bf16(aH1, bfr[ni][1], acc[5][ni], 0, 0, 0);
    }
    __builtin_amdgcn_s_setprio(0);
    __builtin_amdgcn_s_barrier();
    // ---- phase 3 ----
    aL0 = rdA(6, 0); aL1 = rdA(6, 1); aH0 = rdA(7, 0); aH1 = rdA(7, 1);
    if (t + 2 < nk) stageB(t + 2, cur, 1);
    if (t + 2 < nk)      asm volatile("s_waitcnt vmcnt(4)" ::: "memory");
    else if (t + 1 < nk) asm volatile("s_waitcnt vmcnt(0)" ::: "memory");
    __builtin_amdgcn_s_barrier();
    __builtin_amdgcn_s_setprio(1);
#pragma unroll
    for (int ni = 0; ni < 4; ni++) {
      acc[6][ni] = __builtin_amdgcn_mfma_f32_16x16x32_bf16(aL0, bfr[ni][0], acc[6][ni], 0, 0, 0);
      acc[6][ni] = __builtin_amdgcn_mfma_f32_16x16x32_bf16(aL1, bfr[ni][1], acc[6][ni], 0, 0, 0);
      acc[7][ni] = __builtin_amdgcn_mfma_f32_16x16x32_bf16(aH0, bfr[ni][0], acc[7][ni], 0, 0, 0);
      acc[7][ni] = __builtin_amdgcn_mfma_f32_16x16x32_bf16(aH1, bfr[ni][1], acc[7][ni], 0, 0, 0);
    }
    __builtin_amdgcn_s_setprio(0);
    __builtin_amdgcn_s_barrier();
  }

#pragma unroll
  for (int mi = 0; mi < 8; mi++) {
#pragma unroll
    for (int ni = 0; ni < 4; ni++) {
      int col = n0 + wc * 64 + ni * 16 + (lane & 15);
      int rb = m0 + wr * 128 + mi * 16 + ((lane >> 4) << 2);
      float bv = 0.f;
      if (BIAS) bv = bias[col];
#pragma unroll
      for (int r = 0; r < 4; r++) {
        float v = acc[mi][ni][r] + bv;
        if (GELU) v = gelu_f(v);
        size_t idx = (size_t)(rb + r) * N + col;
        if (OUTF32) ((float*)C_)[idx] = v;
        else ((u16t*)C_)[idx] = f2b(v);
      }
    }
  }
}

// -------- GEMM 128x64 (N=1024 shapes): 3-stage ring, counted vmcnt, T2 ---
// Geometric optimum for N=1024 at 2 blk/CU (FLOP/ds_read = 1024MN/(M+N);
// 64x64/wave needs 128x128 blocks -> 1 blk/CU -> R7 regression). Keep.
template <int BN, bool GELU, bool RESID, bool BIAS, bool RESF32, bool OUTF32>
__global__ __launch_bounds__(256) void gemm_k(const u16t* __restrict__ A, const u16t* __restrict__ Bt,
                                              const float* __restrict__ bias, const void* __restrict__ res_,
                                              void* __restrict__ C_, int M, int N, int K) {
  constexpr int NF = BN / 32;
  static_assert(BN == 64, "vmcnt count assumes 6 loads/stage");
  __shared__ u16t As[3][128 * 64];
  __shared__ u16t Bs[3][BN * 64];
  const int tid = threadIdx.x;
  const int lane = tid & 63;
  const int wave = tid >> 6;
  const int nx = N / BN, pnx = nx >> 3;
  const int bid = blockIdx.x;
  const int xcd = bid & 7, idx = bid >> 3;
  const int n0 = (xcd * pnx + (idx % pnx)) * BN;
  const int m0 = (idx / pnx) * 128;
  const int wm = (wave >> 1) * 64, wn = (wave & 1) * (BN / 2);
  f32x4 acc[4][NF] = {};
  const int nk = K >> 6;

  auto stage = [&](int t, int buf) {
    const int k0 = t << 6;
#pragma unroll
    for (int i = 0; i < 4; i++) {
      unsigned P = i * 4096 + tid * 16;
      unsigned row = P >> 7, slot = ((P >> 4) & 7) ^ (row & 7);
      gload16(A + (size_t)(m0 + row) * K + k0 + slot * 8, &As[buf][P >> 1]);
    }
#pragma unroll
    for (int i = 0; i < BN / 32; i++) {
      unsigned P = i * 4096 + tid * 16;
      unsigned row = P >> 7, slot = ((P >> 4) & 7) ^ (row & 7);
      gload16(Bt + (size_t)(n0 + row) * K + k0 + slot * 8, &Bs[buf][P >> 1]);
    }
  };

  stage(0, 0);
  if (nk > 1) stage(1, 1);

  for (int t = 0; t < nk; t++) {
    if (t + 1 < nk) asm volatile("s_waitcnt vmcnt(6)" ::: "memory");
    else            asm volatile("s_waitcnt vmcnt(0)" ::: "memory");
    __builtin_amdgcn_s_barrier();
    const int cur = t % 3;
#pragma unroll
    for (int kc = 0; kc < 2; kc++) {
      bf16x8 af[4], bf[NF];
#pragma unroll
      for (int mi = 0; mi < 4; mi++) {
        unsigned row = wm + mi * 16 + (lane & 15);
        unsigned slot = ((unsigned)(kc * 4 + (lane >> 4))) ^ (row & 7);
        af[mi] = *(const bf16x8*)&As[cur][row * 64 + slot * 8];
      }
#pragma unroll
      for (int ni = 0; ni < NF; ni++) {
        unsigned row = wn + ni * 16 + (lane & 15);
        unsigned slot = ((unsigned)(kc * 4 + (lane >> 4))) ^ (row & 7);
        bf[ni] = *(const bf16x8*)&Bs[cur][row * 64 + slot * 8];
      }
      __builtin_amdgcn_s_setprio(1);
#pragma unroll
      for (int mi = 0; mi < 4; mi++)
#pragma unroll
        for (int ni = 0; ni < NF; ni++)
          acc[mi][ni] = __builtin_amdgcn_mfma_f32_16x16x32_bf16(af[mi], bf[ni], acc[mi][ni], 0, 0, 0);
      __builtin_amdgcn_s_setprio(0);
    }
    if (t + 2 < nk) stage(t + 2, (t + 2) % 3);
  }

#pragma unroll
  for (int mi = 0; mi < 4; mi++) {
#pragma unroll
    for (int ni = 0; ni < NF; ni++) {
      int col = n0 + wn + ni * 16 + (lane & 15);
      int rb = m0 + wm + mi * 16 + ((lane >> 4) << 2);
      float bv = 0.f;
      if (BIAS) bv = bias[col];
#pragma unroll
      for (int r = 0; r < 4; r++) {
        float v = acc[mi][ni][r] + bv;
        if (GELU) v = gelu_f(v);
        size_t idx = (size_t)(rb + r) * N + col;
        if (RESID) v += RESF32 ? ((const float*)res_)[idx] : b2f(((const u16t*)res_)[idx]);
        if (OUTF32) ((float*)C_)[idx] = v;
        else ((u16t*)C_)[idx] = f2b(v);
      }
    }
  }
}

// -- Flash attention (causal), KVBLK=64, abs softmax ----------------------
// R10 structure RESTORED (best known): dbuf K/V with reg-staging
// (issue global->reg at loop top, ds_write after barrier -- decouples
// global-load latency from LDS publish; R11's DMA fused them and
// regressed 7us). Truncating P->bf16, exp2-direct via Q pre-scale.
__global__ __launch_bounds__(256) void attn_k(const u16t* __restrict__ qkv,
                                              const u16t* __restrict__ vt,
                                              u16t* __restrict__ ctx) {
  const int b = blockIdx.z, h = blockIdx.y;
  const int tid = threadIdx.x, lane = tid & 63, wave = tid >> 6;
  const int bx = (b == 1) ? (gridDim.x - 1 - blockIdx.x) : blockIdx.x;  // causal balance
  const int q0 = bx * 128 + wave * 32;
  const int ld = 3 * EMB;
  const u16t* Qp = qkv + (size_t)b * SEQN * ld + h * HDIM;
  const u16t* Kp = Qp + EMB;
  const u16t* VTp = vt + (size_t)(b * HEADS + h) * HDIM * SEQN;  // [64][SEQN]

  __shared__ u16t Ks[2][64 * 64];
  __shared__ u16t Vs[2][64 * 64];
  __shared__ u16t Ps[4][32][72];

  bf16x8 qf[2][2];
#pragma unroll
  for (int mi = 0; mi < 2; mi++)
#pragma unroll
    for (int kc = 0; kc < 2; kc++) {
      u16x8 qraw = *(const u16x8*)(Qp + (size_t)(q0 + mi * 16 + (lane & 15)) * ld + kc * 32 + (lane >> 4) * 8);
      u16x8 qs;
#pragma unroll
      for (int j = 0; j < 8; j++) qs[j] = f2b(b2f(qraw[j]) * 0.18033688011112042f);  // (1/8)*log2(e)
      qf[mi][kc] = __builtin_bit_cast(bf16x8, qs);
    }

  u16x8 onesu;
#pragma unroll
  for (int j = 0; j < 8; j++) onesu[j] = 0x3F80;  // bf16 1.0
  const bf16x8 ones = __builtin_bit_cast(bf16x8, onesu);

  f32x4 o[2][4] = {};
  f32x4 ls[2] = {};

  u16x8 kreg[2], vreg[2];
  auto issue = [&](int kt) {  // global (pre-swizzled source) -> regs
    const int kb = kt * 64;
#pragma unroll
    for (int i = 0; i < 2; i++) {
      unsigned P = i * 4096 + tid * 16;
      unsigned row = P >> 7;
      unsigned slot = ((P >> 4) & 7) ^ (row & 7);
      kreg[i] = *(const u16x8*)(Kp + (size_t)(kb + row) * ld + slot * 8);
      vreg[i] = *(const u16x8*)(VTp + (size_t)row * SEQN + kb + slot * 8);
    }
  };
  auto write = [&](int buf) {  // regs -> linear LDS offsets
#pragma unroll
    for (int i = 0; i < 2; i++) {
      unsigned P = i * 4096 + tid * 16;
      *(u16x8*)&Ks[buf][P >> 1] = kreg[i];
      *(u16x8*)&Vs[buf][P >> 1] = vreg[i];
    }
  };

  const int ntiles = 2 * bx + 2;
  // prologue: tile 0 into LDS buf 0
  issue(0);
  asm volatile("s_waitcnt vmcnt(0)" ::: "memory");
  write(0);
  __syncthreads();

  for (int kt = 0; kt < ntiles; kt++) {
    const int kb = kt * 64;
    const int cur = kt & 1;
    if (kt + 1 < ntiles) issue(kt + 1);  // latency covered by compute below

    if (kb <= q0 + 31) {
      f32x4 st[2][4] = {};
      __builtin_amdgcn_s_setprio(1);
#pragma unroll
      for (int ni = 0; ni < 4; ni++) {
#pragma unroll
        for (int kc = 0; kc < 2; kc++) {
          unsigned row = ni * 16 + (lane & 15);
          unsigned slot = ((unsigned)(kc * 4 + (lane >> 4))) ^ (row & 7);
          bf16x8 bfr = *(const bf16x8*)&Ks[cur][row * 64 + slot * 8];
          st[0][ni] = __builtin_amdgcn_mfma_f32_16x16x32_bf16(qf[0][kc], bfr, st[0][ni], 0, 0, 0);
          st[1][ni] = __builtin_amdgcn_mfma_f32_16x16x32_bf16(qf[1][kc], bfr, st[1][ni], 0, 0, 0);
        }
      }
      __builtin_amdgcn_s_setprio(0);

      if (kb + 63 > q0) {
#pragma unroll
        for (int mi = 0; mi < 2; mi++)
#pragma unroll
          for (int ni = 0; ni < 4; ni++) {
            int kk = kb + ni * 16 + (lane & 15);
#pragma unroll
            for (int r = 0; r < 4; r++) {
              int qq = q0 + mi * 16 + ((lane >> 4) << 2) + r;
              if (kk > qq) st[mi][ni][r] = -1e30f;
            }
          }
      }

#pragma unroll
      for (int mi = 0; mi < 2; mi++)
#pragma unroll
        for (int ni = 0; ni < 4; ni++)
#pragma unroll
          for (int r = 0; r < 4; r++) {
            union { float f; unsigned int u; } pv;
            // exp2 direct: S' already includes log2(e)/8 via Q pre-scale
            asm("v_exp_f32 %0, %1" : "=v"(pv.f) : "v"(st[mi][ni][r]));
            Ps[wave][mi * 16 + ((lane >> 4) << 2) + r][ni * 16 + (lane & 15)] =
                (u16t)(pv.u >> 16);  // truncating bf16
          }

      bf16x8 pa[2][2];
#pragma unroll
      for (int mi = 0; mi < 2; mi++)
#pragma unroll
        for (int kc = 0; kc < 2; kc++)
          pa[mi][kc] = *(const bf16x8*)&Ps[wave][mi * 16 + (lane & 15)][kc * 32 + (lane >> 4) * 8];

      __builtin_amdgcn_s_setprio(1);
#pragma unroll
      for (int di = 0; di < 4; di++) {
#pragma unroll
        for (int kc = 0; kc < 2; kc++) {
          unsigned row = di * 16 + (lane & 15);
          unsigned slot = ((unsigned)(kc * 4 + (lane >> 4))) ^ (row & 7);
          bf16x8 vf = *(const bf16x8*)&Vs[cur][row * 64 + slot * 8];
          o[0][di] = __builtin_amdgcn_mfma_f32_16x16x32_bf16(pa[0][kc], vf, o[0][di], 0, 0, 0);
          o[1][di] = __builtin_amdgcn_mfma_f32_16x16x32_bf16(pa[1][kc], vf, o[1][di], 0, 0, 0);
        }
      }
#pragma unroll
      for (int kc = 0; kc < 2; kc++) {
        ls[0] = __builtin_amdgcn_mfma_f32_16x16x32_bf16(pa[0][kc], ones, ls[0], 0, 0, 0);
        ls[1] = __builtin_amdgcn_mfma_f32_16x16x32_bf16(pa[1][kc], ones, ls[1], 0, 0, 0);
      }
      __builtin_amdgcn_s_setprio(0);
    }

    // Single barrier per tile: write kt+1 into the OTHER buffer (no
    // overwrite hazard with this tile's readers), then publish.
    asm volatile("s_waitcnt vmcnt(0)" ::: "memory");  // issue(kt+1) landed; also compiler fence
    if (kt + 1 < ntiles) write(cur ^ 1);
    __syncthreads();  // lgkm drain + barrier: writes visible before next compute
  }

  u16t* Cp = ctx + (size_t)b * SEQN * EMB + h * HDIM;
#pragma unroll
  for (int mi = 0; mi < 2; mi++)
#pragma unroll
    for (int r = 0; r < 4; r++) {
      float inv = 1.f / ls[mi][r];
      int qq = q0 + mi * 16 + ((lane >> 4) << 2) + r;
#pragma unroll
      for (int di = 0; di < 4; di++)
        Cp[(size_t)qq * EMB + di * 16 + (lane & 15)] = f2b(o[mi][di][r] * inv);
    }
}

// -------------------------------------------------------------------------
extern "C" void kernel_launch(void* const* d_in, const int* in_sizes, int n_in,
                              void* d_out, int out_size, void* d_ws, size_t ws_size,
                              hipStream_t stream) {
  const float* x  = (const float*)d_in[0];
  const float* Wq = (const float*)d_in[1];
  const float* Wk = (const float*)d_in[2];
  const float* Wv = (const float*)d_in[3];
  const float* Wo = (const float*)d_in[4];
  const float* bo = (const float*)d_in[5];
  const float* W1 = (const float*)d_in[6];
  const float* b1 = (const float*)d_in[7];
  const float* W2 = (const float*)d_in[8];
  const float* b2 = (const float*)d_in[9];
  const float* g1 = (const float*)d_in[10];
  const float* s1 = (const float*)d_in[11];
  const float* g2 = (const float*)d_in[12];
  const float* s2 = (const float*)d_in[13];
  float* out = (float*)d_out;  // reference output dtype is float32

  // workspace layout (64 MiB total).
  // ALIAS MAP (liveness!):
  //   ff1 = qkvb..qkvb+32MB => covers qkvb(24MB) AND ctxb(8MB); live to FF2 end.
  //   vtb = hln (dead between QKV-GEMM and LN2); hln dead after FF1 reads it.
  char* p = (char*)d_ws;
  u16t* WqkvT = (u16t*)p; p += (size_t)3 * EMB * EMB * 2;   // [3072][1024]
  u16t* WoT   = (u16t*)p; p += (size_t)EMB * EMB * 2;       // [1024][1024]
  u16t* W1T   = (u16t*)p; p += (size_t)FFD * EMB * 2;       // [4096][1024]
  u16t* W2T   = (u16t*)p; p += (size_t)EMB * FFD * 2;       // [1024][4096]
  u16t* hln   = (u16t*)p; p += (size_t)ROWS * EMB * 2;      // [4096][1024]
  u16t* qkvb  = (u16t*)p; p += (size_t)ROWS * 3 * EMB * 2;  // [4096][3072]
  u16t* ctxb  = (u16t*)p; p += (size_t)ROWS * EMB * 2;      // [4096][1024]
  u16t* ff1   = qkvb;  // [4096][4096] aliases qkv(24MB)+ctx(8MB)
  u16t* vtb   = hln;   // [32][64][2048] aliases hln

  dim3 blk(256);
  // merged transposes + LN1 (blocks >= 12288 run LN rows)
  trln_k<<<dim3(12288 + ROWS), blk, 0, stream>>>(Wq, Wk, Wv, Wo, W1, W2,
                                                 WqkvT, WoT, W1T, W2T, x, g1, s1, hln);
  gemm256_k<false, false, false><<<dim3((3 * EMB / 256) * (ROWS / 256)), dim3(512), 0, stream>>>(
      hln, WqkvT, nullptr, qkvb, ROWS, 3 * EMB, EMB);
  vtr_k<<<dim3(SEQN / 32, HDIM / 32, BATCH * HEADS), blk, 0, stream>>>(qkvb, vtb);
  attn_k<<<dim3(SEQN / 128, HEADS, BATCH), blk, 0, stream>>>(qkvb, vtb, ctxb);
  gemm_k<64, false, true, true, true, true><<<dim3((EMB / 64) * (ROWS / 128)), blk, 0, stream>>>(
      ctxb, WoT, bo, x, out, ROWS, EMB, EMB);
  ln_k<true><<<ROWS, blk, 0, stream>>>(out, g2, s2, hln);
  gemm256_k<true, true, false><<<dim3((FFD / 256) * (ROWS / 256)), dim3(512), 0, stream>>>(
      hln, W1T, b1, ff1, ROWS, FFD, EMB);
  gemm_k<64, false, true, true, true, true><<<dim3((EMB / 64) * (ROWS / 128)), blk, 0, stream>>>(
      ff1, W2T, b2, out, out, ROWS, EMB, FFD);
}

// Round 13
// 216.482 us; speedup vs baseline: 1.0531x; 1.0200x over previous
//
#include <hip/hip_runtime.h>
#include <stdint.h>

#define EMB 1024
#define HEADS 16
#define HDIM 64
#define SEQN 2048
#define BATCH 2
#define FFD 4096
#define ROWS (BATCH * SEQN)

typedef unsigned short u16t;
typedef __attribute__((ext_vector_type(4))) unsigned short u16x4;
typedef __attribute__((ext_vector_type(8))) unsigned short u16x8;
typedef __attribute__((ext_vector_type(8))) __bf16 bf16x8;
typedef __attribute__((ext_vector_type(4))) float f32x4;

__device__ __forceinline__ float b2f(u16t u) {
  union { float f; unsigned int i; } v; v.i = ((unsigned int)u) << 16; return v.f;
}
__device__ __forceinline__ u16t f2b(float f) {
  union { float f; unsigned int i; } v; v.f = f;
  unsigned int r = v.i + 0x7FFFu + ((v.i >> 16) & 1u);
  return (u16t)(r >> 16);
}

// gelu_tanh via sigmoid identity: 0.5v(1+tanh(t)) = v/(1+e^{-2t}).
// Confirmed: warm pipeline gain ~21 us vs libm tanhf (R1 vs R6).
__device__ __forceinline__ float gelu_f(float v) {
  float t2 = 1.5957691216057308f * (v + 0.044715f * v * v * v);  // 2*sqrt(2/pi)*(...)
  return v / (1.f + __expf(-t2));
}

__device__ __forceinline__ void gload16(const u16t* g, u16t* l) {
  __builtin_amdgcn_global_load_lds((const __attribute__((address_space(1))) void*)g,
                                   (__attribute__((address_space(3))) void*)l, 16, 0, 0);
}

// ---------------- LayerNorm: one block per row (1024 cols) ----------------
template <bool INF32>
__global__ __launch_bounds__(256) void ln_k(const void* __restrict__ x_, const float* __restrict__ g,
                                            const float* __restrict__ s, u16t* __restrict__ out) {
  const int row = blockIdx.x;
  const int t = threadIdx.x;
  float f[4];
  if (INF32) {
    const float4* xr = (const float4*)((const float*)x_ + (size_t)row * EMB);
    float4 xv = xr[t];
    f[0] = xv.x; f[1] = xv.y; f[2] = xv.z; f[3] = xv.w;
  } else {
    const u16t* xr = (const u16t*)x_ + (size_t)row * EMB;
    u16x4 xv = *(const u16x4*)(xr + t * 4);
#pragma unroll
    for (int i = 0; i < 4; i++) f[i] = b2f(xv[i]);
  }
  float sum = 0.f, sq = 0.f;
#pragma unroll
  for (int i = 0; i < 4; i++) { sum += f[i]; sq += f[i] * f[i]; }
#pragma unroll
  for (int off = 1; off < 64; off <<= 1) { sum += __shfl_xor(sum, off); sq += __shfl_xor(sq, off); }
  __shared__ float red[8];
  const int lane = t & 63, wave = t >> 6;
  if (lane == 0) { red[wave] = sum; red[4 + wave] = sq; }
  __syncthreads();
  sum = red[0] + red[1] + red[2] + red[3];
  sq = red[4] + red[5] + red[6] + red[7];
  const float mean = sum * (1.f / EMB);
  const float var = sq * (1.f / EMB) - mean * mean;
  const float rstd = rsqrtf(var + 1e-5f);
  float4 gv = ((const float4*)g)[t];
  float4 sv = ((const float4*)s)[t];
  float gg[4] = {gv.x, gv.y, gv.z, gv.w};
  float ss[4] = {sv.x, sv.y, sv.z, sv.w};
  u16x4 ov;
#pragma unroll
  for (int i = 0; i < 4; i++) ov[i] = f2b((f[i] - mean) * rstd * gg[i] + ss[i]);
  *(u16x4*)(out + (size_t)row * EMB + t * 4) = ov;
}

// ------ Merged: ALL 6 weight transposes + LN1 in ONE dispatch ------------
__global__ __launch_bounds__(256) void trln_k(const float* __restrict__ Wq, const float* __restrict__ Wk,
                                              const float* __restrict__ Wv, const float* __restrict__ Wo,
                                              const float* __restrict__ W1, const float* __restrict__ W2,
                                              u16t* __restrict__ WqkvT, u16t* __restrict__ WoT,
                                              u16t* __restrict__ W1T, u16t* __restrict__ W2T,
                                              const float* __restrict__ x, const float* __restrict__ g1,
                                              const float* __restrict__ s1, u16t* __restrict__ hln) {
  int t = blockIdx.x;
  if (t >= 12288) {
    // ---- LN1 part: one block per row ----
    const int row = t - 12288;
    const int tt = threadIdx.x;
    const float4* xr = (const float4*)(x + (size_t)row * EMB);
    float4 xv = xr[tt];
    float f[4] = {xv.x, xv.y, xv.z, xv.w};
    float sum = 0.f, sq = 0.f;
#pragma unroll
    for (int i = 0; i < 4; i++) { sum += f[i]; sq += f[i] * f[i]; }
#pragma unroll
    for (int off = 1; off < 64; off <<= 1) { sum += __shfl_xor(sum, off); sq += __shfl_xor(sq, off); }
    __shared__ float red[8];
    const int lane = tt & 63, wave = tt >> 6;
    if (lane == 0) { red[wave] = sum; red[4 + wave] = sq; }
    __syncthreads();
    sum = red[0] + red[1] + red[2] + red[3];
    sq = red[4] + red[5] + red[6] + red[7];
    const float mean = sum * (1.f / EMB);
    const float var = sq * (1.f / EMB) - mean * mean;
    const float rstd = rsqrtf(var + 1e-5f);
    float4 gv = ((const float4*)g1)[tt];
    float4 sv = ((const float4*)s1)[tt];
    float gg[4] = {gv.x, gv.y, gv.z, gv.w};
    float ss[4] = {sv.x, sv.y, sv.z, sv.w};
    u16x4 ov;
#pragma unroll
    for (int i = 0; i < 4; i++) ov[i] = f2b((f[i] - mean) * rstd * gg[i] + ss[i]);
    *(u16x4*)(hln + (size_t)row * EMB + tt * 4) = ov;
    return;
  }
  // ---- transpose part ----
  const float* in; u16t* out; int R, C;
  if (t < 4096) {
    R = EMB; C = EMB;
    const int seg = t >> 10; t &= 1023;
    if (seg == 0)      { in = Wq; out = WqkvT; }
    else if (seg == 1) { in = Wk; out = WqkvT + (size_t)EMB * EMB; }
    else if (seg == 2) { in = Wv; out = WqkvT + (size_t)2 * EMB * EMB; }
    else               { in = Wo; out = WoT; }
  } else if (t < 8192) {
    in = W1; out = W1T; R = EMB; C = FFD; t -= 4096;
  } else {
    in = W2; out = W2T; R = FFD; C = EMB; t -= 8192;
  }
  const int bx = t % (C >> 5), by = t / (C >> 5);

  __shared__ float tile[32][33];
  const int tx = threadIdx.x & 31, ty = threadIdx.x >> 5;
  const int c = bx * 32 + tx;
#pragma unroll
  for (int i = 0; i < 4; i++) {
    int r = by * 32 + ty + i * 8;
    tile[ty + i * 8][tx] = in[(size_t)r * C + c];
  }
  __syncthreads();
  const int r2 = by * 32 + tx;
#pragma unroll
  for (int i = 0; i < 4; i++) {
    int c2 = bx * 32 + ty + i * 8;
    out[(size_t)c2 * R + r2] = f2b(tile[tx][ty + i * 8]);
  }
}

// ---------------- V transpose: qkv V part -> vt[b*H+h][64][SEQN] ---------
__global__ __launch_bounds__(256) void vtr_k(const u16t* __restrict__ qkv, u16t* __restrict__ vt) {
  __shared__ u16t tile[32][33];
  const int tx = threadIdx.x & 31, ty = threadIdx.x >> 5;  // 32 x 8
  const int k0 = blockIdx.x * 32;
  const int d0 = blockIdx.y * 32;
  const int bh = blockIdx.z;
  const int b = bh / HEADS, h = bh % HEADS;
  const u16t* src = qkv + (size_t)b * SEQN * (3 * EMB) + 2 * EMB + h * HDIM;
#pragma unroll
  for (int i = 0; i < 4; i++)
    tile[ty + i * 8][tx] = src[(size_t)(k0 + ty + i * 8) * (3 * EMB) + d0 + tx];
  __syncthreads();
  u16t* dst = vt + ((size_t)bh * HDIM + d0) * SEQN + k0;
#pragma unroll
  for (int i = 0; i < 4; i++)
    dst[(size_t)(ty + i * 8) * SEQN + tx] = tile[tx][ty + i * 8];
}

// ------- GEMM 256x256 tile: 4-phase, T2 swizzle, counted vmcnt -----------
// Measured ~1250 TF warm (FF1 27.5us) -- keep for QKV/FF1 (wide-N shapes).
template <bool GELU, bool BIAS, bool OUTF32>
__global__ __launch_bounds__(512, 2) void gemm256_k(const u16t* __restrict__ A, const u16t* __restrict__ Bt,
                                                    const float* __restrict__ bias, void* __restrict__ C_,
                                                    int M, int N, int K) {
  __shared__ u16t As[2][256 * 64];
  __shared__ u16t Bs[2][256 * 64];
  const int tid = threadIdx.x;
  const int lane = tid & 63, wave = tid >> 6;
  const int wr = wave >> 2, wc = wave & 3;  // 2 x 4 waves
  const int nwg = gridDim.x, per = nwg >> 3;
  const int swz = (blockIdx.x & 7) * per + (blockIdx.x >> 3);
  const int nx = N >> 8;
  const int m0 = (swz / nx) * 256, n0 = (swz % nx) * 256;
  f32x4 acc[8][4] = {};
  const int nk = K >> 6;

  // stage one 128-row half (2 loads/thread) of the A or B tile
  auto stageA = [&](int t, int buf, int h) {
    const int k0 = t << 6;
#pragma unroll
    for (int i = 0; i < 2; i++) {
      unsigned P = (h * 2 + i) * 8192 + tid * 16;
      unsigned row = P >> 7, slot = ((P >> 4) & 7) ^ (row & 7);
      gload16(A + (size_t)(m0 + row) * K + k0 + slot * 8, &As[buf][P >> 1]);
    }
  };
  auto stageB = [&](int t, int buf, int h) {
    const int k0 = t << 6;
#pragma unroll
    for (int i = 0; i < 2; i++) {
      unsigned P = (h * 2 + i) * 8192 + tid * 16;
      unsigned row = P >> 7, slot = ((P >> 4) & 7) ^ (row & 7);
      gload16(Bt + (size_t)(n0 + row) * K + k0 + slot * 8, &Bs[buf][P >> 1]);
    }
  };

  // prologue: tile0 A+B, tile1 B (B of buf[1] is only read at tile1 phase 0)
  stageA(0, 0, 0); stageA(0, 0, 1);
  stageB(0, 0, 0); stageB(0, 0, 1);
  if (nk > 1) {
    stageB(1, 1, 0); stageB(1, 1, 1);
    asm volatile("s_waitcnt vmcnt(4)" ::: "memory");  // A(0),B(0) done; B(1) in flight
  } else {
    asm volatile("s_waitcnt vmcnt(0)" ::: "memory");
  }
  __builtin_amdgcn_s_barrier();

  for (int t = 0; t < nk; t++) {
    const int cur = t & 1;
    const u16t* Asc = As[cur];
    const u16t* Bsc = Bs[cur];
    auto rdA = [&](int mi, int kc) -> bf16x8 {
      unsigned row = wr * 128 + mi * 16 + (lane & 15);
      unsigned slot = ((unsigned)(kc * 4 + (lane >> 4))) ^ (row & 7);
      return *(const bf16x8*)&Asc[row * 64 + slot * 8];
    };
    // ---- phase 0 ----
    bf16x8 bfr[4][2];
#pragma unroll
    for (int ni = 0; ni < 4; ni++)
#pragma unroll
      for (int kc = 0; kc < 2; kc++) {
        unsigned row = wc * 64 + ni * 16 + (lane & 15);
        unsigned slot = ((unsigned)(kc * 4 + (lane >> 4))) ^ (row & 7);
        bfr[ni][kc] = *(const bf16x8*)&Bsc[row * 64 + slot * 8];
      }
    bf16x8 aL0 = rdA(0, 0), aL1 = rdA(0, 1), aH0 = rdA(1, 0), aH1 = rdA(1, 1);
    if (t + 1 < nk) stageA(t + 1, cur ^ 1, 0);
    __builtin_amdgcn_s_barrier();
    __builtin_amdgcn_s_setprio(1);
#pragma unroll
    for (int ni = 0; ni < 4; ni++) {
      acc[0][ni] = __builtin_amdgcn_mfma_f32_16x16x32_bf16(aL0, bfr[ni][0], acc[0][ni], 0, 0, 0);
      acc[0][ni] = __builtin_amdgcn_mfma_f32_16x16x32_bf16(aL1, bfr[ni][1], acc[0][ni], 0, 0, 0);
      acc[1][ni] = __builtin_amdgcn_mfma_f32_16x16x32_bf16(aH0, bfr[ni][0], acc[1][ni], 0, 0, 0);
      acc[1][ni] = __builtin_amdgcn_mfma_f32_16x16x32_bf16(aH1, bfr[ni][1], acc[1][ni], 0, 0, 0);
    }
    __builtin_amdgcn_s_setprio(0);
    __builtin_amdgcn_s_barrier();
    // ---- phase 1 ----
    aL0 = rdA(2, 0); aL1 = rdA(2, 1); aH0 = rdA(3, 0); aH1 = rdA(3, 1);
    if (t + 1 < nk) stageA(t + 1, cur ^ 1, 1);
    __builtin_amdgcn_s_barrier();
    __builtin_amdgcn_s_setprio(1);
#pragma unroll
    for (int ni = 0; ni < 4; ni++) {
      acc[2][ni] = __builtin_amdgcn_mfma_f32_16x16x32_bf16(aL0, bfr[ni][0], acc[2][ni], 0, 0, 0);
      acc[2][ni] = __builtin_amdgcn_mfma_f32_16x16x32_bf16(aL1, bfr[ni][1], acc[2][ni], 0, 0, 0);
      acc[3][ni] = __builtin_amdgcn_mfma_f32_16x16x32_bf16(aH0, bfr[ni][0], acc[3][ni], 0, 0, 0);
      acc[3][ni] = __builtin_amdgcn_mfma_f32_16x16x32_bf16(aH1, bfr[ni][1], acc[3][ni], 0, 0, 0);
    }
    __builtin_amdgcn_s_setprio(0);
    __builtin_amdgcn_s_barrier();
    // ---- phase 2 ----
    aL0 = rdA(4, 0); aL1 = rdA(4, 1); aH0 = rdA(5, 0); aH1 = rdA(5, 1);
    if (t + 2 < nk) stageB(t + 2, cur, 0);  // Bs[cur] B-frags already in regs
    __builtin_amdgcn_s_barrier();
    __builtin_amdgcn_s_setprio(1);
#pragma unroll
    for (int ni = 0; ni < 4; ni++) {
      acc[4][ni] = __builtin_amdgcn_mfma_f32_16x16x32_bf16(aL0, bfr[ni][0], acc[4][ni], 0, 0, 0);
      acc[4][ni] = __builtin_amdgcn_mfma_f32_16x16x32_bf16(aL1, bfr[ni][1], acc[4][ni], 0, 0, 0);
      acc[5][ni] = __builtin_amdgcn_mfma_f32_16x16x32_bf16(aH0, bfr[ni][0], acc[5][ni], 0, 0, 0);
      acc[5][ni] = __builtin_amdgcn_mfma_f32_16x16x32_bf16(aH1, bfr[ni][1], acc[5][ni], 0, 0, 0);
    }
    __builtin_amdgcn_s_setprio(0);
    __builtin_amdgcn_s_barrier();
    // ---- phase 3 ----
    aL0 = rdA(6, 0); aL1 = rdA(6, 1); aH0 = rdA(7, 0); aH1 = rdA(7, 1);
    if (t + 2 < nk) stageB(t + 2, cur, 1);
    if (t + 2 < nk)      asm volatile("s_waitcnt vmcnt(4)" ::: "memory");
    else if (t + 1 < nk) asm volatile("s_waitcnt vmcnt(0)" ::: "memory");
    __builtin_amdgcn_s_barrier();
    __builtin_amdgcn_s_setprio(1);
#pragma unroll
    for (int ni = 0; ni < 4; ni++) {
      acc[6][ni] = __builtin_amdgcn_mfma_f32_16x16x32_bf16(aL0, bfr[ni][0], acc[6][ni], 0, 0, 0);
      acc[6][ni] = __builtin_amdgcn_mfma_f32_16x16x32_bf16(aL1, bfr[ni][1], acc[6][ni], 0, 0, 0);
      acc[7][ni] = __builtin_amdgcn_mfma_f32_16x16x32_bf16(aH0, bfr[ni][0], acc[7][ni], 0, 0, 0);
      acc[7][ni] = __builtin_amdgcn_mfma_f32_16x16x32_bf16(aH1, bfr[ni][1], acc[7][ni], 0, 0, 0);
    }
    __builtin_amdgcn_s_setprio(0);
    __builtin_amdgcn_s_barrier();
  }

#pragma unroll
  for (int mi = 0; mi < 8; mi++) {
#pragma unroll
    for (int ni = 0; ni < 4; ni++) {
      int col = n0 + wc * 64 + ni * 16 + (lane & 15);
      int rb = m0 + wr * 128 + mi * 16 + ((lane >> 4) << 2);
      float bv = 0.f;
      if (BIAS) bv = bias[col];
#pragma unroll
      for (int r = 0; r < 4; r++) {
        float v = acc[mi][ni][r] + bv;
        if (GELU) v = gelu_f(v);
        size_t idx = (size_t)(rb + r) * N + col;
        if (OUTF32) ((float*)C_)[idx] = v;
        else ((u16t*)C_)[idx] = f2b(v);
      }
    }
  }
}

// -------- GEMM 128x64 (N=1024 shapes): 3-stage ring, counted vmcnt, T2 ---
// Geometric optimum for N=1024 at 2 blk/CU (FLOP/ds_read = 1024MN/(M+N);
// 64x64/wave needs 128x128 blocks -> 1 blk/CU -> R7 regression). Keep.
template <int BN, bool GELU, bool RESID, bool BIAS, bool RESF32, bool OUTF32>
__global__ __launch_bounds__(256) void gemm_k(const u16t* __restrict__ A, const u16t* __restrict__ Bt,
                                              const float* __restrict__ bias, const void* __restrict__ res_,
                                              void* __restrict__ C_, int M, int N, int K) {
  constexpr int NF = BN / 32;
  static_assert(BN == 64, "vmcnt count assumes 6 loads/stage");
  __shared__ u16t As[3][128 * 64];
  __shared__ u16t Bs[3][BN * 64];
  const int tid = threadIdx.x;
  const int lane = tid & 63;
  const int wave = tid >> 6;
  const int nx = N / BN, pnx = nx >> 3;
  const int bid = blockIdx.x;
  const int xcd = bid & 7, idx = bid >> 3;
  const int n0 = (xcd * pnx + (idx % pnx)) * BN;
  const int m0 = (idx / pnx) * 128;
  const int wm = (wave >> 1) * 64, wn = (wave & 1) * (BN / 2);
  f32x4 acc[4][NF] = {};
  const int nk = K >> 6;

  auto stage = [&](int t, int buf) {
    const int k0 = t << 6;
#pragma unroll
    for (int i = 0; i < 4; i++) {
      unsigned P = i * 4096 + tid * 16;
      unsigned row = P >> 7, slot = ((P >> 4) & 7) ^ (row & 7);
      gload16(A + (size_t)(m0 + row) * K + k0 + slot * 8, &As[buf][P >> 1]);
    }
#pragma unroll
    for (int i = 0; i < BN / 32; i++) {
      unsigned P = i * 4096 + tid * 16;
      unsigned row = P >> 7, slot = ((P >> 4) & 7) ^ (row & 7);
      gload16(Bt + (size_t)(n0 + row) * K + k0 + slot * 8, &Bs[buf][P >> 1]);
    }
  };

  stage(0, 0);
  if (nk > 1) stage(1, 1);

  for (int t = 0; t < nk; t++) {
    if (t + 1 < nk) asm volatile("s_waitcnt vmcnt(6)" ::: "memory");
    else            asm volatile("s_waitcnt vmcnt(0)" ::: "memory");
    __builtin_amdgcn_s_barrier();
    const int cur = t % 3;
#pragma unroll
    for (int kc = 0; kc < 2; kc++) {
      bf16x8 af[4], bf[NF];
#pragma unroll
      for (int mi = 0; mi < 4; mi++) {
        unsigned row = wm + mi * 16 + (lane & 15);
        unsigned slot = ((unsigned)(kc * 4 + (lane >> 4))) ^ (row & 7);
        af[mi] = *(const bf16x8*)&As[cur][row * 64 + slot * 8];
      }
#pragma unroll
      for (int ni = 0; ni < NF; ni++) {
        unsigned row = wn + ni * 16 + (lane & 15);
        unsigned slot = ((unsigned)(kc * 4 + (lane >> 4))) ^ (row & 7);
        bf[ni] = *(const bf16x8*)&Bs[cur][row * 64 + slot * 8];
      }
      __builtin_amdgcn_s_setprio(1);
#pragma unroll
      for (int mi = 0; mi < 4; mi++)
#pragma unroll
        for (int ni = 0; ni < NF; ni++)
          acc[mi][ni] = __builtin_amdgcn_mfma_f32_16x16x32_bf16(af[mi], bf[ni], acc[mi][ni], 0, 0, 0);
      __builtin_amdgcn_s_setprio(0);
    }
    if (t + 2 < nk) stage(t + 2, (t + 2) % 3);
  }

#pragma unroll
  for (int mi = 0; mi < 4; mi++) {
#pragma unroll
    for (int ni = 0; ni < NF; ni++) {
      int col = n0 + wn + ni * 16 + (lane & 15);
      int rb = m0 + wm + mi * 16 + ((lane >> 4) << 2);
      float bv = 0.f;
      if (BIAS) bv = bias[col];
#pragma unroll
      for (int r = 0; r < 4; r++) {
        float v = acc[mi][ni][r] + bv;
        if (GELU) v = gelu_f(v);
        size_t idx = (size_t)(rb + r) * N + col;
        if (RESID) v += RESF32 ? ((const float*)res_)[idx] : b2f(((const u16t*)res_)[idx]);
        if (OUTF32) ((float*)C_)[idx] = v;
        else ((u16t*)C_)[idx] = f2b(v);
      }
    }
  }
}

// -- Flash attention (causal), KVBLK=64, abs softmax ----------------------
// R13: swapped QK^T. mfma(A=K,B=Q) -> D[kv][q]; A/B frag layouts are
// identical for 16x16x32 so operands need NO re-layout, just arg swap.
// Lane then holds 4 kv-CONSECUTIVE P values at fixed q -> P-store becomes
// 8 packed ds_write_b64 instead of 32 scalar ds_write_u16 (same [q][kv]
// LDS layout, same bytes). PA read / PV / ls unchanged. Mask indices swap
// roles. Same products, same k-order -> bit-identical output.
__global__ __launch_bounds__(256) void attn_k(const u16t* __restrict__ qkv,
                                              const u16t* __restrict__ vt,
                                              u16t* __restrict__ ctx) {
  const int b = blockIdx.z, h = blockIdx.y;
  const int tid = threadIdx.x, lane = tid & 63, wave = tid >> 6;
  const int bx = (b == 1) ? (gridDim.x - 1 - blockIdx.x) : blockIdx.x;  // causal balance
  const int q0 = bx * 128 + wave * 32;
  const int ld = 3 * EMB;
  const u16t* Qp = qkv + (size_t)b * SEQN * ld + h * HDIM;
  const u16t* Kp = Qp + EMB;
  const u16t* VTp = vt + (size_t)(b * HEADS + h) * HDIM * SEQN;  // [64][SEQN]

  __shared__ u16t Ks[2][64 * 64];
  __shared__ u16t Vs[2][64 * 64];
  __shared__ u16t Ps[4][32][72];

  bf16x8 qf[2][2];
#pragma unroll
  for (int mi = 0; mi < 2; mi++)
#pragma unroll
    for (int kc = 0; kc < 2; kc++) {
      u16x8 qraw = *(const u16x8*)(Qp + (size_t)(q0 + mi * 16 + (lane & 15)) * ld + kc * 32 + (lane >> 4) * 8);
      u16x8 qs;
#pragma unroll
      for (int j = 0; j < 8; j++) qs[j] = f2b(b2f(qraw[j]) * 0.18033688011112042f);  // (1/8)*log2(e)
      qf[mi][kc] = __builtin_bit_cast(bf16x8, qs);
    }

  u16x8 onesu;
#pragma unroll
  for (int j = 0; j < 8; j++) onesu[j] = 0x3F80;  // bf16 1.0
  const bf16x8 ones = __builtin_bit_cast(bf16x8, onesu);

  f32x4 o[2][4] = {};
  f32x4 ls[2] = {};

  u16x8 kreg[2], vreg[2];
  auto issue = [&](int kt) {  // global (pre-swizzled source) -> regs
    const int kb = kt * 64;
#pragma unroll
    for (int i = 0; i < 2; i++) {
      unsigned P = i * 4096 + tid * 16;
      unsigned row = P >> 7;
      unsigned slot = ((P >> 4) & 7) ^ (row & 7);
      kreg[i] = *(const u16x8*)(Kp + (size_t)(kb + row) * ld + slot * 8);
      vreg[i] = *(const u16x8*)(VTp + (size_t)row * SEQN + kb + slot * 8);
    }
  };
  auto write = [&](int buf) {  // regs -> linear LDS offsets
#pragma unroll
    for (int i = 0; i < 2; i++) {
      unsigned P = i * 4096 + tid * 16;
      *(u16x8*)&Ks[buf][P >> 1] = kreg[i];
      *(u16x8*)&Vs[buf][P >> 1] = vreg[i];
    }
  };

  const int ntiles = 2 * bx + 2;
  // prologue: tile 0 into LDS buf 0
  issue(0);
  asm volatile("s_waitcnt vmcnt(0)" ::: "memory");
  write(0);
  __syncthreads();

  for (int kt = 0; kt < ntiles; kt++) {
    const int kb = kt * 64;
    const int cur = kt & 1;
    if (kt + 1 < ntiles) issue(kt + 1);  // latency covered by compute below

    if (kb <= q0 + 31) {
      f32x4 st[2][4] = {};   // st[mi][ni]: D[kv][q] (swapped)
      __builtin_amdgcn_s_setprio(1);
#pragma unroll
      for (int ni = 0; ni < 4; ni++) {
#pragma unroll
        for (int kc = 0; kc < 2; kc++) {
          unsigned row = ni * 16 + (lane & 15);
          unsigned slot = ((unsigned)(kc * 4 + (lane >> 4))) ^ (row & 7);
          bf16x8 bfr = *(const bf16x8*)&Ks[cur][row * 64 + slot * 8];
          // swapped operand order: D = K . Q^T  (bit-same products/order)
          st[0][ni] = __builtin_amdgcn_mfma_f32_16x16x32_bf16(bfr, qf[0][kc], st[0][ni], 0, 0, 0);
          st[1][ni] = __builtin_amdgcn_mfma_f32_16x16x32_bf16(bfr, qf[1][kc], st[1][ni], 0, 0, 0);
        }
      }
      __builtin_amdgcn_s_setprio(0);

      if (kb + 63 > q0) {
#pragma unroll
        for (int mi = 0; mi < 2; mi++)
#pragma unroll
          for (int ni = 0; ni < 4; ni++) {
            int qq = q0 + mi * 16 + (lane & 15);  // q is now the column
#pragma unroll
            for (int r = 0; r < 4; r++) {
              int kk = kb + ni * 16 + ((lane >> 4) << 2) + r;  // kv is the row
              if (kk > qq) st[mi][ni][r] = -1e30f;
            }
          }
      }

      // P-store: 4 kv-consecutive values at fixed q -> one packed b64 per
      // (mi,ni). Same [q][kv] layout as before (read side unchanged).
#pragma unroll
      for (int mi = 0; mi < 2; mi++)
#pragma unroll
        for (int ni = 0; ni < 4; ni++) {
          u16x4 pk;
#pragma unroll
          for (int r = 0; r < 4; r++) {
            union { float f; unsigned int u; } pv;
            asm("v_exp_f32 %0, %1" : "=v"(pv.f) : "v"(st[mi][ni][r]));
            pk[r] = (u16t)(pv.u >> 16);  // truncating bf16
          }
          *(u16x4*)&Ps[wave][mi * 16 + (lane & 15)][ni * 16 + ((lane >> 4) << 2)] = pk;
        }

      bf16x8 pa[2][2];
#pragma unroll
      for (int mi = 0; mi < 2; mi++)
#pragma unroll
        for (int kc = 0; kc < 2; kc++)
          pa[mi][kc] = *(const bf16x8*)&Ps[wave][mi * 16 + (lane & 15)][kc * 32 + (lane >> 4) * 8];

      __builtin_amdgcn_s_setprio(1);
#pragma unroll
      for (int di = 0; di < 4; di++) {
#pragma unroll
        for (int kc = 0; kc < 2; kc++) {
          unsigned row = di * 16 + (lane & 15);
          unsigned slot = ((unsigned)(kc * 4 + (lane >> 4))) ^ (row & 7);
          bf16x8 vf = *(const bf16x8*)&Vs[cur][row * 64 + slot * 8];
          o[0][di] = __builtin_amdgcn_mfma_f32_16x16x32_bf16(pa[0][kc], vf, o[0][di], 0, 0, 0);
          o[1][di] = __builtin_amdgcn_mfma_f32_16x16x32_bf16(pa[1][kc], vf, o[1][di], 0, 0, 0);
        }
      }
#pragma unroll
      for (int kc = 0; kc < 2; kc++) {
        ls[0] = __builtin_amdgcn_mfma_f32_16x16x32_bf16(pa[0][kc], ones, ls[0], 0, 0, 0);
        ls[1] = __builtin_amdgcn_mfma_f32_16x16x32_bf16(pa[1][kc], ones, ls[1], 0, 0, 0);
      }
      __builtin_amdgcn_s_setprio(0);
    }

    // Single barrier per tile: write kt+1 into the OTHER buffer (no
    // overwrite hazard with this tile's readers), then publish.
    asm volatile("s_waitcnt vmcnt(0)" ::: "memory");  // issue(kt+1) landed; also compiler fence
    if (kt + 1 < ntiles) write(cur ^ 1);
    __syncthreads();  // lgkm drain + barrier: writes visible before next compute
  }

  u16t* Cp = ctx + (size_t)b * SEQN * EMB + h * HDIM;
#pragma unroll
  for (int mi = 0; mi < 2; mi++)
#pragma unroll
    for (int r = 0; r < 4; r++) {
      float inv = 1.f / ls[mi][r];
      int qq = q0 + mi * 16 + ((lane >> 4) << 2) + r;
#pragma unroll
      for (int di = 0; di < 4; di++)
        Cp[(size_t)qq * EMB + di * 16 + (lane & 15)] = f2b(o[mi][di][r] * inv);
    }
}

// -------------------------------------------------------------------------
extern "C" void kernel_launch(void* const* d_in, const int* in_sizes, int n_in,
                              void* d_out, int out_size, void* d_ws, size_t ws_size,
                              hipStream_t stream) {
  const float* x  = (const float*)d_in[0];
  const float* Wq = (const float*)d_in[1];
  const float* Wk = (const float*)d_in[2];
  const float* Wv = (const float*)d_in[3];
  const float* Wo = (const float*)d_in[4];
  const float* bo = (const float*)d_in[5];
  const float* W1 = (const float*)d_in[6];
  const float* b1 = (const float*)d_in[7];
  const float* W2 = (const float*)d_in[8];
  const float* b2 = (const float*)d_in[9];
  const float* g1 = (const float*)d_in[10];
  const float* s1 = (const float*)d_in[11];
  const float* g2 = (const float*)d_in[12];
  const float* s2 = (const float*)d_in[13];
  float* out = (float*)d_out;  // reference output dtype is float32

  // workspace layout (64 MiB total).
  // ALIAS MAP (liveness!):
  //   ff1 = qkvb..qkvb+32MB => covers qkvb(24MB) AND ctxb(8MB); live to FF2 end.
  //   vtb = hln (dead between QKV-GEMM and LN2); hln dead after FF1 reads it.
  char* p = (char*)d_ws;
  u16t* WqkvT = (u16t*)p; p += (size_t)3 * EMB * EMB * 2;   // [3072][1024]
  u16t* WoT   = (u16t*)p; p += (size_t)EMB * EMB * 2;       // [1024][1024]
  u16t* W1T   = (u16t*)p; p += (size_t)FFD * EMB * 2;       // [4096][1024]
  u16t* W2T   = (u16t*)p; p += (size_t)EMB * FFD * 2;       // [1024][4096]
  u16t* hln   = (u16t*)p; p += (size_t)ROWS * EMB * 2;      // [4096][1024]
  u16t* qkvb  = (u16t*)p; p += (size_t)ROWS * 3 * EMB * 2;  // [4096][3072]
  u16t* ctxb  = (u16t*)p; p += (size_t)ROWS * EMB * 2;      // [4096][1024]
  u16t* ff1   = qkvb;  // [4096][4096] aliases qkv(24MB)+ctx(8MB)
  u16t* vtb   = hln;   // [32][64][2048] aliases hln

  dim3 blk(256);
  // merged transposes + LN1 (blocks >= 12288 run LN rows)
  trln_k<<<dim3(12288 + ROWS), blk, 0, stream>>>(Wq, Wk, Wv, Wo, W1, W2,
                                                 WqkvT, WoT, W1T, W2T, x, g1, s1, hln);
  gemm256_k<false, false, false><<<dim3((3 * EMB / 256) * (ROWS / 256)), dim3(512), 0, stream>>>(
      hln, WqkvT, nullptr, qkvb, ROWS, 3 * EMB, EMB);
  vtr_k<<<dim3(SEQN / 32, HDIM / 32, BATCH * HEADS), blk, 0, stream>>>(qkvb, vtb);
  attn_k<<<dim3(SEQN / 128, HEADS, BATCH), blk, 0, stream>>>(qkvb, vtb, ctxb);
  gemm_k<64, false, true, true, true, true><<<dim3((EMB / 64) * (ROWS / 128)), blk, 0, stream>>>(
      ctxb, WoT, bo, x, out, ROWS, EMB, EMB);
  ln_k<true><<<ROWS, blk, 0, stream>>>(out, g2, s2, hln);
  gemm256_k<true, true, false><<<dim3((FFD / 256) * (ROWS / 256)), dim3(512), 0, stream>>>(
      hln, W1T, b1, ff1, ROWS, FFD, EMB);
  gemm_k<64, false, true, true, true, true><<<dim3((EMB / 64) * (ROWS / 128)), blk, 0, stream>>>(
      ff1, W2T, b2, out, out, ROWS, EMB, FFD);
}

// Round 14
// 215.318 us; speedup vs baseline: 1.0588x; 1.0054x over previous
//
#include <hip/hip_runtime.h>
#include <stdint.h>

#define EMB 1024
#define HEADS 16
#define HDIM 64
#define SEQN 2048
#define BATCH 2
#define FFD 4096
#define ROWS (BATCH * SEQN)

typedef unsigned short u16t;
typedef __attribute__((ext_vector_type(4))) unsigned short u16x4;
typedef __attribute__((ext_vector_type(8))) unsigned short u16x8;
typedef __attribute__((ext_vector_type(8))) __bf16 bf16x8;
typedef __attribute__((ext_vector_type(4))) float f32x4;

__device__ __forceinline__ float b2f(u16t u) {
  union { float f; unsigned int i; } v; v.i = ((unsigned int)u) << 16; return v.f;
}
__device__ __forceinline__ u16t f2b(float f) {
  union { float f; unsigned int i; } v; v.f = f;
  unsigned int r = v.i + 0x7FFFu + ((v.i >> 16) & 1u);
  return (u16t)(r >> 16);
}

// gelu_tanh via sigmoid identity: 0.5v(1+tanh(t)) = v/(1+e^{-2t}).
// Confirmed: warm pipeline gain ~21 us vs libm tanhf (R1 vs R6).
__device__ __forceinline__ float gelu_f(float v) {
  float t2 = 1.5957691216057308f * (v + 0.044715f * v * v * v);  // 2*sqrt(2/pi)*(...)
  return v / (1.f + __expf(-t2));
}

__device__ __forceinline__ void gload16(const u16t* g, u16t* l) {
  __builtin_amdgcn_global_load_lds((const __attribute__((address_space(1))) void*)g,
                                   (__attribute__((address_space(3))) void*)l, 16, 0, 0);
}

// ---------------- LayerNorm: one block per row (1024 cols) ----------------
template <bool INF32>
__global__ __launch_bounds__(256) void ln_k(const void* __restrict__ x_, const float* __restrict__ g,
                                            const float* __restrict__ s, u16t* __restrict__ out) {
  const int row = blockIdx.x;
  const int t = threadIdx.x;
  float f[4];
  if (INF32) {
    const float4* xr = (const float4*)((const float*)x_ + (size_t)row * EMB);
    float4 xv = xr[t];
    f[0] = xv.x; f[1] = xv.y; f[2] = xv.z; f[3] = xv.w;
  } else {
    const u16t* xr = (const u16t*)x_ + (size_t)row * EMB;
    u16x4 xv = *(const u16x4*)(xr + t * 4);
#pragma unroll
    for (int i = 0; i < 4; i++) f[i] = b2f(xv[i]);
  }
  float sum = 0.f, sq = 0.f;
#pragma unroll
  for (int i = 0; i < 4; i++) { sum += f[i]; sq += f[i] * f[i]; }
#pragma unroll
  for (int off = 1; off < 64; off <<= 1) { sum += __shfl_xor(sum, off); sq += __shfl_xor(sq, off); }
  __shared__ float red[8];
  const int lane = t & 63, wave = t >> 6;
  if (lane == 0) { red[wave] = sum; red[4 + wave] = sq; }
  __syncthreads();
  sum = red[0] + red[1] + red[2] + red[3];
  sq = red[4] + red[5] + red[6] + red[7];
  const float mean = sum * (1.f / EMB);
  const float var = sq * (1.f / EMB) - mean * mean;
  const float rstd = rsqrtf(var + 1e-5f);
  float4 gv = ((const float4*)g)[t];
  float4 sv = ((const float4*)s)[t];
  float gg[4] = {gv.x, gv.y, gv.z, gv.w};
  float ss[4] = {sv.x, sv.y, sv.z, sv.w};
  u16x4 ov;
#pragma unroll
  for (int i = 0; i < 4; i++) ov[i] = f2b((f[i] - mean) * rstd * gg[i] + ss[i]);
  *(u16x4*)(out + (size_t)row * EMB + t * 4) = ov;
}

// ------ Merged: ALL 6 weight transposes + LN1 in ONE dispatch ------------
__global__ __launch_bounds__(256) void trln_k(const float* __restrict__ Wq, const float* __restrict__ Wk,
                                              const float* __restrict__ Wv, const float* __restrict__ Wo,
                                              const float* __restrict__ W1, const float* __restrict__ W2,
                                              u16t* __restrict__ WqkvT, u16t* __restrict__ WoT,
                                              u16t* __restrict__ W1T, u16t* __restrict__ W2T,
                                              const float* __restrict__ x, const float* __restrict__ g1,
                                              const float* __restrict__ s1, u16t* __restrict__ hln) {
  int t = blockIdx.x;
  if (t >= 12288) {
    // ---- LN1 part: one block per row ----
    const int row = t - 12288;
    const int tt = threadIdx.x;
    const float4* xr = (const float4*)(x + (size_t)row * EMB);
    float4 xv = xr[tt];
    float f[4] = {xv.x, xv.y, xv.z, xv.w};
    float sum = 0.f, sq = 0.f;
#pragma unroll
    for (int i = 0; i < 4; i++) { sum += f[i]; sq += f[i] * f[i]; }
#pragma unroll
    for (int off = 1; off < 64; off <<= 1) { sum += __shfl_xor(sum, off); sq += __shfl_xor(sq, off); }
    __shared__ float red[8];
    const int lane = tt & 63, wave = tt >> 6;
    if (lane == 0) { red[wave] = sum; red[4 + wave] = sq; }
    __syncthreads();
    sum = red[0] + red[1] + red[2] + red[3];
    sq = red[4] + red[5] + red[6] + red[7];
    const float mean = sum * (1.f / EMB);
    const float var = sq * (1.f / EMB) - mean * mean;
    const float rstd = rsqrtf(var + 1e-5f);
    float4 gv = ((const float4*)g1)[tt];
    float4 sv = ((const float4*)s1)[tt];
    float gg[4] = {gv.x, gv.y, gv.z, gv.w};
    float ss[4] = {sv.x, sv.y, sv.z, sv.w};
    u16x4 ov;
#pragma unroll
    for (int i = 0; i < 4; i++) ov[i] = f2b((f[i] - mean) * rstd * gg[i] + ss[i]);
    *(u16x4*)(hln + (size_t)row * EMB + tt * 4) = ov;
    return;
  }
  // ---- transpose part ----
  const float* in; u16t* out; int R, C;
  if (t < 4096) {
    R = EMB; C = EMB;
    const int seg = t >> 10; t &= 1023;
    if (seg == 0)      { in = Wq; out = WqkvT; }
    else if (seg == 1) { in = Wk; out = WqkvT + (size_t)EMB * EMB; }
    else if (seg == 2) { in = Wv; out = WqkvT + (size_t)2 * EMB * EMB; }
    else               { in = Wo; out = WoT; }
  } else if (t < 8192) {
    in = W1; out = W1T; R = EMB; C = FFD; t -= 4096;
  } else {
    in = W2; out = W2T; R = FFD; C = EMB; t -= 8192;
  }
  const int bx = t % (C >> 5), by = t / (C >> 5);

  __shared__ float tile[32][33];
  const int tx = threadIdx.x & 31, ty = threadIdx.x >> 5;
  const int c = bx * 32 + tx;
#pragma unroll
  for (int i = 0; i < 4; i++) {
    int r = by * 32 + ty + i * 8;
    tile[ty + i * 8][tx] = in[(size_t)r * C + c];
  }
  __syncthreads();
  const int r2 = by * 32 + tx;
#pragma unroll
  for (int i = 0; i < 4; i++) {
    int c2 = bx * 32 + ty + i * 8;
    out[(size_t)c2 * R + r2] = f2b(tile[tx][ty + i * 8]);
  }
}

// ---------------- V transpose: qkv V part -> vt[b*H+h][64][SEQN] ---------
__global__ __launch_bounds__(256) void vtr_k(const u16t* __restrict__ qkv, u16t* __restrict__ vt) {
  __shared__ u16t tile[32][33];
  const int tx = threadIdx.x & 31, ty = threadIdx.x >> 5;  // 32 x 8
  const int k0 = blockIdx.x * 32;
  const int d0 = blockIdx.y * 32;
  const int bh = blockIdx.z;
  const int b = bh / HEADS, h = bh % HEADS;
  const u16t* src = qkv + (size_t)b * SEQN * (3 * EMB) + 2 * EMB + h * HDIM;
#pragma unroll
  for (int i = 0; i < 4; i++)
    tile[ty + i * 8][tx] = src[(size_t)(k0 + ty + i * 8) * (3 * EMB) + d0 + tx];
  __syncthreads();
  u16t* dst = vt + ((size_t)bh * HDIM + d0) * SEQN + k0;
#pragma unroll
  for (int i = 0; i < 4; i++)
    dst[(size_t)(ty + i * 8) * SEQN + tx] = tile[tx][ty + i * 8];
}

// ------- GEMM 256x256 tile: 4-phase, T2 swizzle, counted vmcnt -----------
// Measured ~1250 TF warm (FF1 27.5us) -- keep for QKV/FF1 (wide-N shapes).
template <bool GELU, bool BIAS, bool OUTF32>
__global__ __launch_bounds__(512, 2) void gemm256_k(const u16t* __restrict__ A, const u16t* __restrict__ Bt,
                                                    const float* __restrict__ bias, void* __restrict__ C_,
                                                    int M, int N, int K) {
  __shared__ u16t As[2][256 * 64];
  __shared__ u16t Bs[2][256 * 64];
  const int tid = threadIdx.x;
  const int lane = tid & 63, wave = tid >> 6;
  const int wr = wave >> 2, wc = wave & 3;  // 2 x 4 waves
  const int nwg = gridDim.x, per = nwg >> 3;
  const int swz = (blockIdx.x & 7) * per + (blockIdx.x >> 3);
  const int nx = N >> 8;
  const int m0 = (swz / nx) * 256, n0 = (swz % nx) * 256;
  f32x4 acc[8][4] = {};
  const int nk = K >> 6;

  // stage one 128-row half (2 loads/thread) of the A or B tile
  auto stageA = [&](int t, int buf, int h) {
    const int k0 = t << 6;
#pragma unroll
    for (int i = 0; i < 2; i++) {
      unsigned P = (h * 2 + i) * 8192 + tid * 16;
      unsigned row = P >> 7, slot = ((P >> 4) & 7) ^ (row & 7);
      gload16(A + (size_t)(m0 + row) * K + k0 + slot * 8, &As[buf][P >> 1]);
    }
  };
  auto stageB = [&](int t, int buf, int h) {
    const int k0 = t << 6;
#pragma unroll
    for (int i = 0; i < 2; i++) {
      unsigned P = (h * 2 + i) * 8192 + tid * 16;
      unsigned row = P >> 7, slot = ((P >> 4) & 7) ^ (row & 7);
      gload16(Bt + (size_t)(n0 + row) * K + k0 + slot * 8, &Bs[buf][P >> 1]);
    }
  };

  // prologue: tile0 A+B, tile1 B (B of buf[1] is only read at tile1 phase 0)
  stageA(0, 0, 0); stageA(0, 0, 1);
  stageB(0, 0, 0); stageB(0, 0, 1);
  if (nk > 1) {
    stageB(1, 1, 0); stageB(1, 1, 1);
    asm volatile("s_waitcnt vmcnt(4)" ::: "memory");  // A(0),B(0) done; B(1) in flight
  } else {
    asm volatile("s_waitcnt vmcnt(0)" ::: "memory");
  }
  __builtin_amdgcn_s_barrier();

  for (int t = 0; t < nk; t++) {
    const int cur = t & 1;
    const u16t* Asc = As[cur];
    const u16t* Bsc = Bs[cur];
    auto rdA = [&](int mi, int kc) -> bf16x8 {
      unsigned row = wr * 128 + mi * 16 + (lane & 15);
      unsigned slot = ((unsigned)(kc * 4 + (lane >> 4))) ^ (row & 7);
      return *(const bf16x8*)&Asc[row * 64 + slot * 8];
    };
    // ---- phase 0 ----
    bf16x8 bfr[4][2];
#pragma unroll
    for (int ni = 0; ni < 4; ni++)
#pragma unroll
      for (int kc = 0; kc < 2; kc++) {
        unsigned row = wc * 64 + ni * 16 + (lane & 15);
        unsigned slot = ((unsigned)(kc * 4 + (lane >> 4))) ^ (row & 7);
        bfr[ni][kc] = *(const bf16x8*)&Bsc[row * 64 + slot * 8];
      }
    bf16x8 aL0 = rdA(0, 0), aL1 = rdA(0, 1), aH0 = rdA(1, 0), aH1 = rdA(1, 1);
    if (t + 1 < nk) stageA(t + 1, cur ^ 1, 0);
    __builtin_amdgcn_s_barrier();
    __builtin_amdgcn_s_setprio(1);
#pragma unroll
    for (int ni = 0; ni < 4; ni++) {
      acc[0][ni] = __builtin_amdgcn_mfma_f32_16x16x32_bf16(aL0, bfr[ni][0], acc[0][ni], 0, 0, 0);
      acc[0][ni] = __builtin_amdgcn_mfma_f32_16x16x32_bf16(aL1, bfr[ni][1], acc[0][ni], 0, 0, 0);
      acc[1][ni] = __builtin_amdgcn_mfma_f32_16x16x32_bf16(aH0, bfr[ni][0], acc[1][ni], 0, 0, 0);
      acc[1][ni] = __builtin_amdgcn_mfma_f32_16x16x32_bf16(aH1, bfr[ni][1], acc[1][ni], 0, 0, 0);
    }
    __builtin_amdgcn_s_setprio(0);
    __builtin_amdgcn_s_barrier();
    // ---- phase 1 ----
    aL0 = rdA(2, 0); aL1 = rdA(2, 1); aH0 = rdA(3, 0); aH1 = rdA(3, 1);
    if (t + 1 < nk) stageA(t + 1, cur ^ 1, 1);
    __builtin_amdgcn_s_barrier();
    __builtin_amdgcn_s_setprio(1);
#pragma unroll
    for (int ni = 0; ni < 4; ni++) {
      acc[2][ni] = __builtin_amdgcn_mfma_f32_16x16x32_bf16(aL0, bfr[ni][0], acc[2][ni], 0, 0, 0);
      acc[2][ni] = __builtin_amdgcn_mfma_f32_16x16x32_bf16(aL1, bfr[ni][1], acc[2][ni], 0, 0, 0);
      acc[3][ni] = __builtin_amdgcn_mfma_f32_16x16x32_bf16(aH0, bfr[ni][0], acc[3][ni], 0, 0, 0);
      acc[3][ni] = __builtin_amdgcn_mfma_f32_16x16x32_bf16(aH1, bfr[ni][1], acc[3][ni], 0, 0, 0);
    }
    __builtin_amdgcn_s_setprio(0);
    __builtin_amdgcn_s_barrier();
    // ---- phase 2 ----
    aL0 = rdA(4, 0); aL1 = rdA(4, 1); aH0 = rdA(5, 0); aH1 = rdA(5, 1);
    if (t + 2 < nk) stageB(t + 2, cur, 0);  // Bs[cur] B-frags already in regs
    __builtin_amdgcn_s_barrier();
    __builtin_amdgcn_s_setprio(1);
#pragma unroll
    for (int ni = 0; ni < 4; ni++) {
      acc[4][ni] = __builtin_amdgcn_mfma_f32_16x16x32_bf16(aL0, bfr[ni][0], acc[4][ni], 0, 0, 0);
      acc[4][ni] = __builtin_amdgcn_mfma_f32_16x16x32_bf16(aL1, bfr[ni][1], acc[4][ni], 0, 0, 0);
      acc[5][ni] = __builtin_amdgcn_mfma_f32_16x16x32_bf16(aH0, bfr[ni][0], acc[5][ni], 0, 0, 0);
      acc[5][ni] = __builtin_amdgcn_mfma_f32_16x16x32_bf16(aH1, bfr[ni][1], acc[5][ni], 0, 0, 0);
    }
    __builtin_amdgcn_s_setprio(0);
    __builtin_amdgcn_s_barrier();
    // ---- phase 3 ----
    aL0 = rdA(6, 0); aL1 = rdA(6, 1); aH0 = rdA(7, 0); aH1 = rdA(7, 1);
    if (t + 2 < nk) stageB(t + 2, cur, 1);
    if (t + 2 < nk)      asm volatile("s_waitcnt vmcnt(4)" ::: "memory");
    else if (t + 1 < nk) asm volatile("s_waitcnt vmcnt(0)" ::: "memory");
    __builtin_amdgcn_s_barrier();
    __builtin_amdgcn_s_setprio(1);
#pragma unroll
    for (int ni = 0; ni < 4; ni++) {
      acc[6][ni] = __builtin_amdgcn_mfma_f32_16x16x32_bf16(aL0, bfr[ni][0], acc[6][ni], 0, 0, 0);
      acc[6][ni] = __builtin_amdgcn_mfma_f32_16x16x32_bf16(aL1, bfr[ni][1], acc[6][ni], 0, 0, 0);
      acc[7][ni] = __builtin_amdgcn_mfma_f32_16x16x32_bf16(aH0, bfr[ni][0], acc[7][ni], 0, 0, 0);
      acc[7][ni] = __builtin_amdgcn_mfma_f32_16x16x32_bf16(aH1, bfr[ni][1], acc[7][ni], 0, 0, 0);
    }
    __builtin_amdgcn_s_setprio(0);
    __builtin_amdgcn_s_barrier();
  }

#pragma unroll
  for (int mi = 0; mi < 8; mi++) {
#pragma unroll
    for (int ni = 0; ni < 4; ni++) {
      int col = n0 + wc * 64 + ni * 16 + (lane & 15);
      int rb = m0 + wr * 128 + mi * 16 + ((lane >> 4) << 2);
      float bv = 0.f;
      if (BIAS) bv = bias[col];
#pragma unroll
      for (int r = 0; r < 4; r++) {
        float v = acc[mi][ni][r] + bv;
        if (GELU) v = gelu_f(v);
        size_t idx = (size_t)(rb + r) * N + col;
        if (OUTF32) ((float*)C_)[idx] = v;
        else ((u16t*)C_)[idx] = f2b(v);
      }
    }
  }
}

// -------- GEMM 128x64 (N=1024 shapes): 3-stage ring, counted vmcnt, T2 ---
// R14: K-loop unrolled by 3 so every ring-buffer index is a compile-time
// constant -> LDS buffer bases fold into ds_read offset: immediates (zero
// per-iter address VALU, no modulo), and the compiler can pipeline across
// the three statically-addressed bodies. Same ops, same order -> bit-same.
template <int BN, bool GELU, bool RESID, bool BIAS, bool RESF32, bool OUTF32>
__global__ __launch_bounds__(256) void gemm_k(const u16t* __restrict__ A, const u16t* __restrict__ Bt,
                                              const float* __restrict__ bias, const void* __restrict__ res_,
                                              void* __restrict__ C_, int M, int N, int K) {
  constexpr int NF = BN / 32;
  static_assert(BN == 64, "vmcnt count assumes 6 loads/stage");
  __shared__ u16t As[3][128 * 64];
  __shared__ u16t Bs[3][BN * 64];
  const int tid = threadIdx.x;
  const int lane = tid & 63;
  const int wave = tid >> 6;
  const int nx = N / BN, pnx = nx >> 3;
  const int bid = blockIdx.x;
  const int xcd = bid & 7, idx = bid >> 3;
  const int n0 = (xcd * pnx + (idx % pnx)) * BN;
  const int m0 = (idx / pnx) * 128;
  const int wm = (wave >> 1) * 64, wn = (wave & 1) * (BN / 2);
  f32x4 acc[4][NF] = {};
  const int nk = K >> 6;

  auto stage = [&](int t, int buf) {
    const int k0 = t << 6;
#pragma unroll
    for (int i = 0; i < 4; i++) {
      unsigned P = i * 4096 + tid * 16;
      unsigned row = P >> 7, slot = ((P >> 4) & 7) ^ (row & 7);
      gload16(A + (size_t)(m0 + row) * K + k0 + slot * 8, &As[buf][P >> 1]);
    }
#pragma unroll
    for (int i = 0; i < BN / 32; i++) {
      unsigned P = i * 4096 + tid * 16;
      unsigned row = P >> 7, slot = ((P >> 4) & 7) ^ (row & 7);
      gload16(Bt + (size_t)(n0 + row) * K + k0 + slot * 8, &Bs[buf][P >> 1]);
    }
  };

  // one K-step against statically-addressed buffers Asc/Bsc; prefetch
  // target sbuf is also a literal at every steady-state call site.
  auto kstep = [&](int t, const u16t* Asc, const u16t* Bsc, int sbuf) __attribute__((always_inline)) {
    if (t + 1 < nk) asm volatile("s_waitcnt vmcnt(6)" ::: "memory");
    else            asm volatile("s_waitcnt vmcnt(0)" ::: "memory");
    __builtin_amdgcn_s_barrier();
#pragma unroll
    for (int kc = 0; kc < 2; kc++) {
      bf16x8 af[4], bf[NF];
#pragma unroll
      for (int mi = 0; mi < 4; mi++) {
        unsigned row = wm + mi * 16 + (lane & 15);
        unsigned slot = ((unsigned)(kc * 4 + (lane >> 4))) ^ (row & 7);
        af[mi] = *(const bf16x8*)&Asc[row * 64 + slot * 8];
      }
#pragma unroll
      for (int ni = 0; ni < NF; ni++) {
        unsigned row = wn + ni * 16 + (lane & 15);
        unsigned slot = ((unsigned)(kc * 4 + (lane >> 4))) ^ (row & 7);
        bf[ni] = *(const bf16x8*)&Bsc[row * 64 + slot * 8];
      }
      __builtin_amdgcn_s_setprio(1);
#pragma unroll
      for (int mi = 0; mi < 4; mi++)
#pragma unroll
        for (int ni = 0; ni < NF; ni++)
          acc[mi][ni] = __builtin_amdgcn_mfma_f32_16x16x32_bf16(af[mi], bf[ni], acc[mi][ni], 0, 0, 0);
      __builtin_amdgcn_s_setprio(0);
    }
    if (t + 2 < nk) stage(t + 2, sbuf);
  };

  stage(0, 0);
  if (nk > 1) stage(1, 1);

  int t = 0;
  for (; t + 3 <= nk; t += 3) {        // steady state: static ring ids
    kstep(t,     As[0], Bs[0], 2);     // prefetch (t+2)%3 == 2
    kstep(t + 1, As[1], Bs[1], 0);
    kstep(t + 2, As[2], Bs[2], 1);
  }
  for (; t < nk; t++)                  // tail (<=2 iters, dynamic ids)
    kstep(t, As[t % 3], Bs[t % 3], (t + 2) % 3);

#pragma unroll
  for (int mi = 0; mi < 4; mi++) {
#pragma unroll
    for (int ni = 0; ni < NF; ni++) {
      int col = n0 + wn + ni * 16 + (lane & 15);
      int rb = m0 + wm + mi * 16 + ((lane >> 4) << 2);
      float bv = 0.f;
      if (BIAS) bv = bias[col];
#pragma unroll
      for (int r = 0; r < 4; r++) {
        float v = acc[mi][ni][r] + bv;
        if (GELU) v = gelu_f(v);
        size_t idx = (size_t)(rb + r) * N + col;
        if (RESID) v += RESF32 ? ((const float*)res_)[idx] : b2f(((const u16t*)res_)[idx]);
        if (OUTF32) ((float*)C_)[idx] = v;
        else ((u16t*)C_)[idx] = f2b(v);
      }
    }
  }
}

// -- Flash attention (causal), KVBLK=64, abs softmax ----------------------
// R13 structure (best known): swapped QK^T (packed b64 P-store), dbuf K/V
// reg-staging, truncating P->bf16, exp2-direct via Q pre-scale.
__global__ __launch_bounds__(256) void attn_k(const u16t* __restrict__ qkv,
                                              const u16t* __restrict__ vt,
                                              u16t* __restrict__ ctx) {
  const int b = blockIdx.z, h = blockIdx.y;
  const int tid = threadIdx.x, lane = tid & 63, wave = tid >> 6;
  const int bx = (b == 1) ? (gridDim.x - 1 - blockIdx.x) : blockIdx.x;  // causal balance
  const int q0 = bx * 128 + wave * 32;
  const int ld = 3 * EMB;
  const u16t* Qp = qkv + (size_t)b * SEQN * ld + h * HDIM;
  const u16t* Kp = Qp + EMB;
  const u16t* VTp = vt + (size_t)(b * HEADS + h) * HDIM * SEQN;  // [64][SEQN]

  __shared__ u16t Ks[2][64 * 64];
  __shared__ u16t Vs[2][64 * 64];
  __shared__ u16t Ps[4][32][72];

  bf16x8 qf[2][2];
#pragma unroll
  for (int mi = 0; mi < 2; mi++)
#pragma unroll
    for (int kc = 0; kc < 2; kc++) {
      u16x8 qraw = *(const u16x8*)(Qp + (size_t)(q0 + mi * 16 + (lane & 15)) * ld + kc * 32 + (lane >> 4) * 8);
      u16x8 qs;
#pragma unroll
      for (int j = 0; j < 8; j++) qs[j] = f2b(b2f(qraw[j]) * 0.18033688011112042f);  // (1/8)*log2(e)
      qf[mi][kc] = __builtin_bit_cast(bf16x8, qs);
    }

  u16x8 onesu;
#pragma unroll
  for (int j = 0; j < 8; j++) onesu[j] = 0x3F80;  // bf16 1.0
  const bf16x8 ones = __builtin_bit_cast(bf16x8, onesu);

  f32x4 o[2][4] = {};
  f32x4 ls[2] = {};

  u16x8 kreg[2], vreg[2];
  auto issue = [&](int kt) {  // global (pre-swizzled source) -> regs
    const int kb = kt * 64;
#pragma unroll
    for (int i = 0; i < 2; i++) {
      unsigned P = i * 4096 + tid * 16;
      unsigned row = P >> 7;
      unsigned slot = ((P >> 4) & 7) ^ (row & 7);
      kreg[i] = *(const u16x8*)(Kp + (size_t)(kb + row) * ld + slot * 8);
      vreg[i] = *(const u16x8*)(VTp + (size_t)row * SEQN + kb + slot * 8);
    }
  };
  auto write = [&](int buf) {  // regs -> linear LDS offsets
#pragma unroll
    for (int i = 0; i < 2; i++) {
      unsigned P = i * 4096 + tid * 16;
      *(u16x8*)&Ks[buf][P >> 1] = kreg[i];
      *(u16x8*)&Vs[buf][P >> 1] = vreg[i];
    }
  };

  const int ntiles = 2 * bx + 2;
  // prologue: tile 0 into LDS buf 0
  issue(0);
  asm volatile("s_waitcnt vmcnt(0)" ::: "memory");
  write(0);
  __syncthreads();

  for (int kt = 0; kt < ntiles; kt++) {
    const int kb = kt * 64;
    const int cur = kt & 1;
    if (kt + 1 < ntiles) issue(kt + 1);  // latency covered by compute below

    if (kb <= q0 + 31) {
      f32x4 st[2][4] = {};   // st[mi][ni]: D[kv][q] (swapped)
      __builtin_amdgcn_s_setprio(1);
#pragma unroll
      for (int ni = 0; ni < 4; ni++) {
#pragma unroll
        for (int kc = 0; kc < 2; kc++) {
          unsigned row = ni * 16 + (lane & 15);
          unsigned slot = ((unsigned)(kc * 4 + (lane >> 4))) ^ (row & 7);
          bf16x8 bfr = *(const bf16x8*)&Ks[cur][row * 64 + slot * 8];
          // swapped operand order: D = K . Q^T  (bit-same products/order)
          st[0][ni] = __builtin_amdgcn_mfma_f32_16x16x32_bf16(bfr, qf[0][kc], st[0][ni], 0, 0, 0);
          st[1][ni] = __builtin_amdgcn_mfma_f32_16x16x32_bf16(bfr, qf[1][kc], st[1][ni], 0, 0, 0);
        }
      }
      __builtin_amdgcn_s_setprio(0);

      if (kb + 63 > q0) {
#pragma unroll
        for (int mi = 0; mi < 2; mi++)
#pragma unroll
          for (int ni = 0; ni < 4; ni++) {
            int qq = q0 + mi * 16 + (lane & 15);  // q is now the column
#pragma unroll
            for (int r = 0; r < 4; r++) {
              int kk = kb + ni * 16 + ((lane >> 4) << 2) + r;  // kv is the row
              if (kk > qq) st[mi][ni][r] = -1e30f;
            }
          }
      }

      // P-store: 4 kv-consecutive values at fixed q -> one packed b64 per
      // (mi,ni). Same [q][kv] layout as before (read side unchanged).
#pragma unroll
      for (int mi = 0; mi < 2; mi++)
#pragma unroll
        for (int ni = 0; ni < 4; ni++) {
          u16x4 pk;
#pragma unroll
          for (int r = 0; r < 4; r++) {
            union { float f; unsigned int u; } pv;
            asm("v_exp_f32 %0, %1" : "=v"(pv.f) : "v"(st[mi][ni][r]));
            pk[r] = (u16t)(pv.u >> 16);  // truncating bf16
          }
          *(u16x4*)&Ps[wave][mi * 16 + (lane & 15)][ni * 16 + ((lane >> 4) << 2)] = pk;
        }

      bf16x8 pa[2][2];
#pragma unroll
      for (int mi = 0; mi < 2; mi++)
#pragma unroll
        for (int kc = 0; kc < 2; kc++)
          pa[mi][kc] = *(const bf16x8*)&Ps[wave][mi * 16 + (lane & 15)][kc * 32 + (lane >> 4) * 8];

      __builtin_amdgcn_s_setprio(1);
#pragma unroll
      for (int di = 0; di < 4; di++) {
#pragma unroll
        for (int kc = 0; kc < 2; kc++) {
          unsigned row = di * 16 + (lane & 15);
          unsigned slot = ((unsigned)(kc * 4 + (lane >> 4))) ^ (row & 7);
          bf16x8 vf = *(const bf16x8*)&Vs[cur][row * 64 + slot * 8];
          o[0][di] = __builtin_amdgcn_mfma_f32_16x16x32_bf16(pa[0][kc], vf, o[0][di], 0, 0, 0);
          o[1][di] = __builtin_amdgcn_mfma_f32_16x16x32_bf16(pa[1][kc], vf, o[1][di], 0, 0, 0);
        }
      }
#pragma unroll
      for (int kc = 0; kc < 2; kc++) {
        ls[0] = __builtin_amdgcn_mfma_f32_16x16x32_bf16(pa[0][kc], ones, ls[0], 0, 0, 0);
        ls[1] = __builtin_amdgcn_mfma_f32_16x16x32_bf16(pa[1][kc], ones, ls[1], 0, 0, 0);
      }
      __builtin_amdgcn_s_setprio(0);
    }

    // Single barrier per tile: write kt+1 into the OTHER buffer (no
    // overwrite hazard with this tile's readers), then publish.
    asm volatile("s_waitcnt vmcnt(0)" ::: "memory");  // issue(kt+1) landed; also compiler fence
    if (kt + 1 < ntiles) write(cur ^ 1);
    __syncthreads();  // lgkm drain + barrier: writes visible before next compute
  }

  u16t* Cp = ctx + (size_t)b * SEQN * EMB + h * HDIM;
#pragma unroll
  for (int mi = 0; mi < 2; mi++)
#pragma unroll
    for (int r = 0; r < 4; r++) {
      float inv = 1.f / ls[mi][r];
      int qq = q0 + mi * 16 + ((lane >> 4) << 2) + r;
#pragma unroll
      for (int di = 0; di < 4; di++)
        Cp[(size_t)qq * EMB + di * 16 + (lane & 15)] = f2b(o[mi][di][r] * inv);
    }
}

// -------------------------------------------------------------------------
extern "C" void kernel_launch(void* const* d_in, const int* in_sizes, int n_in,
                              void* d_out, int out_size, void* d_ws, size_t ws_size,
                              hipStream_t stream) {
  const float* x  = (const float*)d_in[0];
  const float* Wq = (const float*)d_in[1];
  const float* Wk = (const float*)d_in[2];
  const float* Wv = (const float*)d_in[3];
  const float* Wo = (const float*)d_in[4];
  const float* bo = (const float*)d_in[5];
  const float* W1 = (const float*)d_in[6];
  const float* b1 = (const float*)d_in[7];
  const float* W2 = (const float*)d_in[8];
  const float* b2 = (const float*)d_in[9];
  const float* g1 = (const float*)d_in[10];
  const float* s1 = (const float*)d_in[11];
  const float* g2 = (const float*)d_in[12];
  const float* s2 = (const float*)d_in[13];
  float* out = (float*)d_out;  // reference output dtype is float32

  // workspace layout (64 MiB total).
  // ALIAS MAP (liveness!):
  //   ff1 = qkvb..qkvb+32MB => covers qkvb(24MB) AND ctxb(8MB); live to FF2 end.
  //   vtb = hln (dead between QKV-GEMM and LN2); hln dead after FF1 reads it.
  char* p = (char*)d_ws;
  u16t* WqkvT = (u16t*)p; p += (size_t)3 * EMB * EMB * 2;   // [3072][1024]
  u16t* WoT   = (u16t*)p; p += (size_t)EMB * EMB * 2;       // [1024][1024]
  u16t* W1T   = (u16t*)p; p += (size_t)FFD * EMB * 2;       // [4096][1024]
  u16t* W2T   = (u16t*)p; p += (size_t)EMB * FFD * 2;       // [1024][4096]
  u16t* hln   = (u16t*)p; p += (size_t)ROWS * EMB * 2;      // [4096][1024]
  u16t* qkvb  = (u16t*)p; p += (size_t)ROWS * 3 * EMB * 2;  // [4096][3072]
  u16t* ctxb  = (u16t*)p; p += (size_t)ROWS * EMB * 2;      // [4096][1024]
  u16t* ff1   = qkvb;  // [4096][4096] aliases qkv(24MB)+ctx(8MB)
  u16t* vtb   = hln;   // [32][64][2048] aliases hln

  dim3 blk(256);
  // merged transposes + LN1 (blocks >= 12288 run LN rows)
  trln_k<<<dim3(12288 + ROWS), blk, 0, stream>>>(Wq, Wk, Wv, Wo, W1, W2,
                                                 WqkvT, WoT, W1T, W2T, x, g1, s1, hln);
  gemm256_k<false, false, false><<<dim3((3 * EMB / 256) * (ROWS / 256)), dim3(512), 0, stream>>>(
      hln, WqkvT, nullptr, qkvb, ROWS, 3 * EMB, EMB);
  vtr_k<<<dim3(SEQN / 32, HDIM / 32, BATCH * HEADS), blk, 0, stream>>>(qkvb, vtb);
  attn_k<<<dim3(SEQN / 128, HEADS, BATCH), blk, 0, stream>>>(qkvb, vtb, ctxb);
  gemm_k<64, false, true, true, true, true><<<dim3((EMB / 64) * (ROWS / 128)), blk, 0, stream>>>(
      ctxb, WoT, bo, x, out, ROWS, EMB, EMB);
  ln_k<true><<<ROWS, blk, 0, stream>>>(out, g2, s2, hln);
  gemm256_k<true, true, false><<<dim3((FFD / 256) * (ROWS / 256)), dim3(512), 0, stream>>>(
      hln, W1T, b1, ff1, ROWS, FFD, EMB);
  gemm_k<64, false, true, true, true, true><<<dim3((EMB / 64) * (ROWS / 128)), blk, 0, stream>>>(
      ff1, W2T, b2, out, out, ROWS, EMB, FFD);
}

// Round 15
// 210.760 us; speedup vs baseline: 1.0817x; 1.0216x over previous
//
#include <hip/hip_runtime.h>
#include <stdint.h>

#define EMB 1024
#define HEADS 16
#define HDIM 64
#define SEQN 2048
#define BATCH 2
#define FFD 4096
#define ROWS (BATCH * SEQN)

typedef unsigned short u16t;
typedef __attribute__((ext_vector_type(4))) unsigned short u16x4;
typedef __attribute__((ext_vector_type(8))) unsigned short u16x8;
typedef __attribute__((ext_vector_type(8))) __bf16 bf16x8;
typedef __attribute__((ext_vector_type(4))) float f32x4;

__device__ __forceinline__ float b2f(u16t u) {
  union { float f; unsigned int i; } v; v.i = ((unsigned int)u) << 16; return v.f;
}
__device__ __forceinline__ u16t f2b(float f) {
  union { float f; unsigned int i; } v; v.f = f;
  unsigned int r = v.i + 0x7FFFu + ((v.i >> 16) & 1u);
  return (u16t)(r >> 16);
}

// gelu_tanh via sigmoid identity: 0.5v(1+tanh(t)) = v/(1+e^{-2t}).
// Confirmed: warm pipeline gain ~21 us vs libm tanhf (R1 vs R6).
__device__ __forceinline__ float gelu_f(float v) {
  float t2 = 1.5957691216057308f * (v + 0.044715f * v * v * v);  // 2*sqrt(2/pi)*(...)
  return v / (1.f + __expf(-t2));
}

__device__ __forceinline__ void gload16(const u16t* g, u16t* l) {
  __builtin_amdgcn_global_load_lds((const __attribute__((address_space(1))) void*)g,
                                   (__attribute__((address_space(3))) void*)l, 16, 0, 0);
}

// ---------------- LayerNorm: one block per row (1024 cols) ----------------
template <bool INF32>
__global__ __launch_bounds__(256) void ln_k(const void* __restrict__ x_, const float* __restrict__ g,
                                            const float* __restrict__ s, u16t* __restrict__ out) {
  const int row = blockIdx.x;
  const int t = threadIdx.x;
  float f[4];
  if (INF32) {
    const float4* xr = (const float4*)((const float*)x_ + (size_t)row * EMB);
    float4 xv = xr[t];
    f[0] = xv.x; f[1] = xv.y; f[2] = xv.z; f[3] = xv.w;
  } else {
    const u16t* xr = (const u16t*)x_ + (size_t)row * EMB;
    u16x4 xv = *(const u16x4*)(xr + t * 4);
#pragma unroll
    for (int i = 0; i < 4; i++) f[i] = b2f(xv[i]);
  }
  float sum = 0.f, sq = 0.f;
#pragma unroll
  for (int i = 0; i < 4; i++) { sum += f[i]; sq += f[i] * f[i]; }
#pragma unroll
  for (int off = 1; off < 64; off <<= 1) { sum += __shfl_xor(sum, off); sq += __shfl_xor(sq, off); }
  __shared__ float red[8];
  const int lane = t & 63, wave = t >> 6;
  if (lane == 0) { red[wave] = sum; red[4 + wave] = sq; }
  __syncthreads();
  sum = red[0] + red[1] + red[2] + red[3];
  sq = red[4] + red[5] + red[6] + red[7];
  const float mean = sum * (1.f / EMB);
  const float var = sq * (1.f / EMB) - mean * mean;
  const float rstd = rsqrtf(var + 1e-5f);
  float4 gv = ((const float4*)g)[t];
  float4 sv = ((const float4*)s)[t];
  float gg[4] = {gv.x, gv.y, gv.z, gv.w};
  float ss[4] = {sv.x, sv.y, sv.z, sv.w};
  u16x4 ov;
#pragma unroll
  for (int i = 0; i < 4; i++) ov[i] = f2b((f[i] - mean) * rstd * gg[i] + ss[i]);
  *(u16x4*)(out + (size_t)row * EMB + t * 4) = ov;
}

// ------ Merged: ALL 6 weight transposes + LN1 in ONE dispatch ------------
__global__ __launch_bounds__(256) void trln_k(const float* __restrict__ Wq, const float* __restrict__ Wk,
                                              const float* __restrict__ Wv, const float* __restrict__ Wo,
                                              const float* __restrict__ W1, const float* __restrict__ W2,
                                              u16t* __restrict__ WqkvT, u16t* __restrict__ WoT,
                                              u16t* __restrict__ W1T, u16t* __restrict__ W2T,
                                              const float* __restrict__ x, const float* __restrict__ g1,
                                              const float* __restrict__ s1, u16t* __restrict__ hln) {
  int t = blockIdx.x;
  if (t >= 12288) {
    // ---- LN1 part: one block per row ----
    const int row = t - 12288;
    const int tt = threadIdx.x;
    const float4* xr = (const float4*)(x + (size_t)row * EMB);
    float4 xv = xr[tt];
    float f[4] = {xv.x, xv.y, xv.z, xv.w};
    float sum = 0.f, sq = 0.f;
#pragma unroll
    for (int i = 0; i < 4; i++) { sum += f[i]; sq += f[i] * f[i]; }
#pragma unroll
    for (int off = 1; off < 64; off <<= 1) { sum += __shfl_xor(sum, off); sq += __shfl_xor(sq, off); }
    __shared__ float red[8];
    const int lane = tt & 63, wave = tt >> 6;
    if (lane == 0) { red[wave] = sum; red[4 + wave] = sq; }
    __syncthreads();
    sum = red[0] + red[1] + red[2] + red[3];
    sq = red[4] + red[5] + red[6] + red[7];
    const float mean = sum * (1.f / EMB);
    const float var = sq * (1.f / EMB) - mean * mean;
    const float rstd = rsqrtf(var + 1e-5f);
    float4 gv = ((const float4*)g1)[tt];
    float4 sv = ((const float4*)s1)[tt];
    float gg[4] = {gv.x, gv.y, gv.z, gv.w};
    float ss[4] = {sv.x, sv.y, sv.z, sv.w};
    u16x4 ov;
#pragma unroll
    for (int i = 0; i < 4; i++) ov[i] = f2b((f[i] - mean) * rstd * gg[i] + ss[i]);
    *(u16x4*)(hln + (size_t)row * EMB + tt * 4) = ov;
    return;
  }
  // ---- transpose part ----
  const float* in; u16t* out; int R, C;
  if (t < 4096) {
    R = EMB; C = EMB;
    const int seg = t >> 10; t &= 1023;
    if (seg == 0)      { in = Wq; out = WqkvT; }
    else if (seg == 1) { in = Wk; out = WqkvT + (size_t)EMB * EMB; }
    else if (seg == 2) { in = Wv; out = WqkvT + (size_t)2 * EMB * EMB; }
    else               { in = Wo; out = WoT; }
  } else if (t < 8192) {
    in = W1; out = W1T; R = EMB; C = FFD; t -= 4096;
  } else {
    in = W2; out = W2T; R = FFD; C = EMB; t -= 8192;
  }
  const int bx = t % (C >> 5), by = t / (C >> 5);

  __shared__ float tile[32][33];
  const int tx = threadIdx.x & 31, ty = threadIdx.x >> 5;
  const int c = bx * 32 + tx;
#pragma unroll
  for (int i = 0; i < 4; i++) {
    int r = by * 32 + ty + i * 8;
    tile[ty + i * 8][tx] = in[(size_t)r * C + c];
  }
  __syncthreads();
  const int r2 = by * 32 + tx;
#pragma unroll
  for (int i = 0; i < 4; i++) {
    int c2 = bx * 32 + ty + i * 8;
    out[(size_t)c2 * R + r2] = f2b(tile[tx][ty + i * 8]);
  }
}

// ---------------- V transpose: qkv V part -> vt[b*H+h][64][SEQN] ---------
__global__ __launch_bounds__(256) void vtr_k(const u16t* __restrict__ qkv, u16t* __restrict__ vt) {
  __shared__ u16t tile[32][33];
  const int tx = threadIdx.x & 31, ty = threadIdx.x >> 5;  // 32 x 8
  const int k0 = blockIdx.x * 32;
  const int d0 = blockIdx.y * 32;
  const int bh = blockIdx.z;
  const int b = bh / HEADS, h = bh % HEADS;
  const u16t* src = qkv + (size_t)b * SEQN * (3 * EMB) + 2 * EMB + h * HDIM;
#pragma unroll
  for (int i = 0; i < 4; i++)
    tile[ty + i * 8][tx] = src[(size_t)(k0 + ty + i * 8) * (3 * EMB) + d0 + tx];
  __syncthreads();
  u16t* dst = vt + ((size_t)bh * HDIM + d0) * SEQN + k0;
#pragma unroll
  for (int i = 0; i < 4; i++)
    dst[(size_t)(ty + i * 8) * SEQN + tx] = tile[tx][ty + i * 8];
}

// ------- GEMM 256x256 tile: 4-phase, T2 swizzle, counted vmcnt -----------
// Measured ~1250 TF warm (FF1 27.5us) -- keep for QKV/FF1 (wide-N shapes).
template <bool GELU, bool BIAS, bool OUTF32>
__global__ __launch_bounds__(512, 2) void gemm256_k(const u16t* __restrict__ A, const u16t* __restrict__ Bt,
                                                    const float* __restrict__ bias, void* __restrict__ C_,
                                                    int M, int N, int K) {
  __shared__ u16t As[2][256 * 64];
  __shared__ u16t Bs[2][256 * 64];
  const int tid = threadIdx.x;
  const int lane = tid & 63, wave = tid >> 6;
  const int wr = wave >> 2, wc = wave & 3;  // 2 x 4 waves
  const int nwg = gridDim.x, per = nwg >> 3;
  const int swz = (blockIdx.x & 7) * per + (blockIdx.x >> 3);
  const int nx = N >> 8;
  const int m0 = (swz / nx) * 256, n0 = (swz % nx) * 256;
  f32x4 acc[8][4] = {};
  const int nk = K >> 6;

  // stage one 128-row half (2 loads/thread) of the A or B tile
  auto stageA = [&](int t, int buf, int h) {
    const int k0 = t << 6;
#pragma unroll
    for (int i = 0; i < 2; i++) {
      unsigned P = (h * 2 + i) * 8192 + tid * 16;
      unsigned row = P >> 7, slot = ((P >> 4) & 7) ^ (row & 7);
      gload16(A + (size_t)(m0 + row) * K + k0 + slot * 8, &As[buf][P >> 1]);
    }
  };
  auto stageB = [&](int t, int buf, int h) {
    const int k0 = t << 6;
#pragma unroll
    for (int i = 0; i < 2; i++) {
      unsigned P = (h * 2 + i) * 8192 + tid * 16;
      unsigned row = P >> 7, slot = ((P >> 4) & 7) ^ (row & 7);
      gload16(Bt + (size_t)(n0 + row) * K + k0 + slot * 8, &Bs[buf][P >> 1]);
    }
  };

  // prologue: tile0 A+B, tile1 B (B of buf[1] is only read at tile1 phase 0)
  stageA(0, 0, 0); stageA(0, 0, 1);
  stageB(0, 0, 0); stageB(0, 0, 1);
  if (nk > 1) {
    stageB(1, 1, 0); stageB(1, 1, 1);
    asm volatile("s_waitcnt vmcnt(4)" ::: "memory");  // A(0),B(0) done; B(1) in flight
  } else {
    asm volatile("s_waitcnt vmcnt(0)" ::: "memory");
  }
  __builtin_amdgcn_s_barrier();

  for (int t = 0; t < nk; t++) {
    const int cur = t & 1;
    const u16t* Asc = As[cur];
    const u16t* Bsc = Bs[cur];
    auto rdA = [&](int mi, int kc) -> bf16x8 {
      unsigned row = wr * 128 + mi * 16 + (lane & 15);
      unsigned slot = ((unsigned)(kc * 4 + (lane >> 4))) ^ (row & 7);
      return *(const bf16x8*)&Asc[row * 64 + slot * 8];
    };
    // ---- phase 0 ----
    bf16x8 bfr[4][2];
#pragma unroll
    for (int ni = 0; ni < 4; ni++)
#pragma unroll
      for (int kc = 0; kc < 2; kc++) {
        unsigned row = wc * 64 + ni * 16 + (lane & 15);
        unsigned slot = ((unsigned)(kc * 4 + (lane >> 4))) ^ (row & 7);
        bfr[ni][kc] = *(const bf16x8*)&Bsc[row * 64 + slot * 8];
      }
    bf16x8 aL0 = rdA(0, 0), aL1 = rdA(0, 1), aH0 = rdA(1, 0), aH1 = rdA(1, 1);
    if (t + 1 < nk) stageA(t + 1, cur ^ 1, 0);
    __builtin_amdgcn_s_barrier();
    __builtin_amdgcn_s_setprio(1);
#pragma unroll
    for (int ni = 0; ni < 4; ni++) {
      acc[0][ni] = __builtin_amdgcn_mfma_f32_16x16x32_bf16(aL0, bfr[ni][0], acc[0][ni], 0, 0, 0);
      acc[0][ni] = __builtin_amdgcn_mfma_f32_16x16x32_bf16(aL1, bfr[ni][1], acc[0][ni], 0, 0, 0);
      acc[1][ni] = __builtin_amdgcn_mfma_f32_16x16x32_bf16(aH0, bfr[ni][0], acc[1][ni], 0, 0, 0);
      acc[1][ni] = __builtin_amdgcn_mfma_f32_16x16x32_bf16(aH1, bfr[ni][1], acc[1][ni], 0, 0, 0);
    }
    __builtin_amdgcn_s_setprio(0);
    __builtin_amdgcn_s_barrier();
    // ---- phase 1 ----
    aL0 = rdA(2, 0); aL1 = rdA(2, 1); aH0 = rdA(3, 0); aH1 = rdA(3, 1);
    if (t + 1 < nk) stageA(t + 1, cur ^ 1, 1);
    __builtin_amdgcn_s_barrier();
    __builtin_amdgcn_s_setprio(1);
#pragma unroll
    for (int ni = 0; ni < 4; ni++) {
      acc[2][ni] = __builtin_amdgcn_mfma_f32_16x16x32_bf16(aL0, bfr[ni][0], acc[2][ni], 0, 0, 0);
      acc[2][ni] = __builtin_amdgcn_mfma_f32_16x16x32_bf16(aL1, bfr[ni][1], acc[2][ni], 0, 0, 0);
      acc[3][ni] = __builtin_amdgcn_mfma_f32_16x16x32_bf16(aH0, bfr[ni][0], acc[3][ni], 0, 0, 0);
      acc[3][ni] = __builtin_amdgcn_mfma_f32_16x16x32_bf16(aH1, bfr[ni][1], acc[3][ni], 0, 0, 0);
    }
    __builtin_amdgcn_s_setprio(0);
    __builtin_amdgcn_s_barrier();
    // ---- phase 2 ----
    aL0 = rdA(4, 0); aL1 = rdA(4, 1); aH0 = rdA(5, 0); aH1 = rdA(5, 1);
    if (t + 2 < nk) stageB(t + 2, cur, 0);  // Bs[cur] B-frags already in regs
    __builtin_amdgcn_s_barrier();
    __builtin_amdgcn_s_setprio(1);
#pragma unroll
    for (int ni = 0; ni < 4; ni++) {
      acc[4][ni] = __builtin_amdgcn_mfma_f32_16x16x32_bf16(aL0, bfr[ni][0], acc[4][ni], 0, 0, 0);
      acc[4][ni] = __builtin_amdgcn_mfma_f32_16x16x32_bf16(aL1, bfr[ni][1], acc[4][ni], 0, 0, 0);
      acc[5][ni] = __builtin_amdgcn_mfma_f32_16x16x32_bf16(aH0, bfr[ni][0], acc[5][ni], 0, 0, 0);
      acc[5][ni] = __builtin_amdgcn_mfma_f32_16x16x32_bf16(aH1, bfr[ni][1], acc[5][ni], 0, 0, 0);
    }
    __builtin_amdgcn_s_setprio(0);
    __builtin_amdgcn_s_barrier();
    // ---- phase 3 ----
    aL0 = rdA(6, 0); aL1 = rdA(6, 1); aH0 = rdA(7, 0); aH1 = rdA(7, 1);
    if (t + 2 < nk) stageB(t + 2, cur, 1);
    if (t + 2 < nk)      asm volatile("s_waitcnt vmcnt(4)" ::: "memory");
    else if (t + 1 < nk) asm volatile("s_waitcnt vmcnt(0)" ::: "memory");
    __builtin_amdgcn_s_barrier();
    __builtin_amdgcn_s_setprio(1);
#pragma unroll
    for (int ni = 0; ni < 4; ni++) {
      acc[6][ni] = __builtin_amdgcn_mfma_f32_16x16x32_bf16(aL0, bfr[ni][0], acc[6][ni], 0, 0, 0);
      acc[6][ni] = __builtin_amdgcn_mfma_f32_16x16x32_bf16(aL1, bfr[ni][1], acc[6][ni], 0, 0, 0);
      acc[7][ni] = __builtin_amdgcn_mfma_f32_16x16x32_bf16(aH0, bfr[ni][0], acc[7][ni], 0, 0, 0);
      acc[7][ni] = __builtin_amdgcn_mfma_f32_16x16x32_bf16(aH1, bfr[ni][1], acc[7][ni], 0, 0, 0);
    }
    __builtin_amdgcn_s_setprio(0);
    __builtin_amdgcn_s_barrier();
  }

#pragma unroll
  for (int mi = 0; mi < 8; mi++) {
#pragma unroll
    for (int ni = 0; ni < 4; ni++) {
      int col = n0 + wc * 64 + ni * 16 + (lane & 15);
      int rb = m0 + wr * 128 + mi * 16 + ((lane >> 4) << 2);
      float bv = 0.f;
      if (BIAS) bv = bias[col];
#pragma unroll
      for (int r = 0; r < 4; r++) {
        float v = acc[mi][ni][r] + bv;
        if (GELU) v = gelu_f(v);
        size_t idx = (size_t)(rb + r) * N + col;
        if (OUTF32) ((float*)C_)[idx] = v;
        else ((u16t*)C_)[idx] = f2b(v);
      }
    }
  }
}

// -------- GEMM 128x64 (N=1024 shapes): 3-stage ring, counted vmcnt, T2 ---
// R14: K-loop unrolled by 3 -> static ring ids (ds offsets fold to
// immediates). Confirmed -1.2us.
template <int BN, bool GELU, bool RESID, bool BIAS, bool RESF32, bool OUTF32>
__global__ __launch_bounds__(256) void gemm_k(const u16t* __restrict__ A, const u16t* __restrict__ Bt,
                                              const float* __restrict__ bias, const void* __restrict__ res_,
                                              void* __restrict__ C_, int M, int N, int K) {
  constexpr int NF = BN / 32;
  static_assert(BN == 64, "vmcnt count assumes 6 loads/stage");
  __shared__ u16t As[3][128 * 64];
  __shared__ u16t Bs[3][BN * 64];
  const int tid = threadIdx.x;
  const int lane = tid & 63;
  const int wave = tid >> 6;
  const int nx = N / BN, pnx = nx >> 3;
  const int bid = blockIdx.x;
  const int xcd = bid & 7, idx = bid >> 3;
  const int n0 = (xcd * pnx + (idx % pnx)) * BN;
  const int m0 = (idx / pnx) * 128;
  const int wm = (wave >> 1) * 64, wn = (wave & 1) * (BN / 2);
  f32x4 acc[4][NF] = {};
  const int nk = K >> 6;

  auto stage = [&](int t, int buf) {
    const int k0 = t << 6;
#pragma unroll
    for (int i = 0; i < 4; i++) {
      unsigned P = i * 4096 + tid * 16;
      unsigned row = P >> 7, slot = ((P >> 4) & 7) ^ (row & 7);
      gload16(A + (size_t)(m0 + row) * K + k0 + slot * 8, &As[buf][P >> 1]);
    }
#pragma unroll
    for (int i = 0; i < BN / 32; i++) {
      unsigned P = i * 4096 + tid * 16;
      unsigned row = P >> 7, slot = ((P >> 4) & 7) ^ (row & 7);
      gload16(Bt + (size_t)(n0 + row) * K + k0 + slot * 8, &Bs[buf][P >> 1]);
    }
  };

  // one K-step against statically-addressed buffers Asc/Bsc; prefetch
  // target sbuf is also a literal at every steady-state call site.
  auto kstep = [&](int t, const u16t* Asc, const u16t* Bsc, int sbuf) __attribute__((always_inline)) {
    if (t + 1 < nk) asm volatile("s_waitcnt vmcnt(6)" ::: "memory");
    else            asm volatile("s_waitcnt vmcnt(0)" ::: "memory");
    __builtin_amdgcn_s_barrier();
#pragma unroll
    for (int kc = 0; kc < 2; kc++) {
      bf16x8 af[4], bf[NF];
#pragma unroll
      for (int mi = 0; mi < 4; mi++) {
        unsigned row = wm + mi * 16 + (lane & 15);
        unsigned slot = ((unsigned)(kc * 4 + (lane >> 4))) ^ (row & 7);
        af[mi] = *(const bf16x8*)&Asc[row * 64 + slot * 8];
      }
#pragma unroll
      for (int ni = 0; ni < NF; ni++) {
        unsigned row = wn + ni * 16 + (lane & 15);
        unsigned slot = ((unsigned)(kc * 4 + (lane >> 4))) ^ (row & 7);
        bf[ni] = *(const bf16x8*)&Bsc[row * 64 + slot * 8];
      }
      __builtin_amdgcn_s_setprio(1);
#pragma unroll
      for (int mi = 0; mi < 4; mi++)
#pragma unroll
        for (int ni = 0; ni < NF; ni++)
          acc[mi][ni] = __builtin_amdgcn_mfma_f32_16x16x32_bf16(af[mi], bf[ni], acc[mi][ni], 0, 0, 0);
      __builtin_amdgcn_s_setprio(0);
    }
    if (t + 2 < nk) stage(t + 2, sbuf);
  };

  stage(0, 0);
  if (nk > 1) stage(1, 1);

  int t = 0;
  for (; t + 3 <= nk; t += 3) {        // steady state: static ring ids
    kstep(t,     As[0], Bs[0], 2);     // prefetch (t+2)%3 == 2
    kstep(t + 1, As[1], Bs[1], 0);
    kstep(t + 2, As[2], Bs[2], 1);
  }
  for (; t < nk; t++)                  // tail (<=2 iters, dynamic ids)
    kstep(t, As[t % 3], Bs[t % 3], (t + 2) % 3);

#pragma unroll
  for (int mi = 0; mi < 4; mi++) {
#pragma unroll
    for (int ni = 0; ni < NF; ni++) {
      int col = n0 + wn + ni * 16 + (lane & 15);
      int rb = m0 + wm + mi * 16 + ((lane >> 4) << 2);
      float bv = 0.f;
      if (BIAS) bv = bias[col];
#pragma unroll
      for (int r = 0; r < 4; r++) {
        float v = acc[mi][ni][r] + bv;
        if (GELU) v = gelu_f(v);
        size_t idx = (size_t)(rb + r) * N + col;
        if (RESID) v += RESF32 ? ((const float*)res_)[idx] : b2f(((const u16t*)res_)[idx]);
        if (OUTF32) ((float*)C_)[idx] = v;
        else ((u16t*)C_)[idx] = f2b(v);
      }
    }
  }
}

// -- Flash attention (causal), KVBLK=64, abs softmax ----------------------
// R13 structure + R15: tile loop unrolled by 2 (ntiles = 2*bx+2 is always
// even -> no tail). All Ks/Vs buffer bases become compile-time literals
// (fold into ds_read/ds_write offset: immediates), same trick that won
// R14 on gemm_k. Ops and order unchanged -> bit-identical.
__global__ __launch_bounds__(256) void attn_k(const u16t* __restrict__ qkv,
                                              const u16t* __restrict__ vt,
                                              u16t* __restrict__ ctx) {
  const int b = blockIdx.z, h = blockIdx.y;
  const int tid = threadIdx.x, lane = tid & 63, wave = tid >> 6;
  const int bx = (b == 1) ? (gridDim.x - 1 - blockIdx.x) : blockIdx.x;  // causal balance
  const int q0 = bx * 128 + wave * 32;
  const int ld = 3 * EMB;
  const u16t* Qp = qkv + (size_t)b * SEQN * ld + h * HDIM;
  const u16t* Kp = Qp + EMB;
  const u16t* VTp = vt + (size_t)(b * HEADS + h) * HDIM * SEQN;  // [64][SEQN]

  __shared__ u16t Ks[2][64 * 64];
  __shared__ u16t Vs[2][64 * 64];
  __shared__ u16t Ps[4][32][72];

  bf16x8 qf[2][2];
#pragma unroll
  for (int mi = 0; mi < 2; mi++)
#pragma unroll
    for (int kc = 0; kc < 2; kc++) {
      u16x8 qraw = *(const u16x8*)(Qp + (size_t)(q0 + mi * 16 + (lane & 15)) * ld + kc * 32 + (lane >> 4) * 8);
      u16x8 qs;
#pragma unroll
      for (int j = 0; j < 8; j++) qs[j] = f2b(b2f(qraw[j]) * 0.18033688011112042f);  // (1/8)*log2(e)
      qf[mi][kc] = __builtin_bit_cast(bf16x8, qs);
    }

  u16x8 onesu;
#pragma unroll
  for (int j = 0; j < 8; j++) onesu[j] = 0x3F80;  // bf16 1.0
  const bf16x8 ones = __builtin_bit_cast(bf16x8, onesu);

  f32x4 o[2][4] = {};
  f32x4 ls[2] = {};

  u16x8 kreg[2], vreg[2];
  auto issue = [&](int kt) {  // global (pre-swizzled source) -> regs
    const int kb = kt * 64;
#pragma unroll
    for (int i = 0; i < 2; i++) {
      unsigned P = i * 4096 + tid * 16;
      unsigned row = P >> 7;
      unsigned slot = ((P >> 4) & 7) ^ (row & 7);
      kreg[i] = *(const u16x8*)(Kp + (size_t)(kb + row) * ld + slot * 8);
      vreg[i] = *(const u16x8*)(VTp + (size_t)row * SEQN + kb + slot * 8);
    }
  };

  const int ntiles = 2 * bx + 2;  // ALWAYS EVEN -> clean unroll-by-2
  // prologue: tile 0 into LDS buf 0
  issue(0);
  asm volatile("s_waitcnt vmcnt(0)" ::: "memory");
#pragma unroll
  for (int i = 0; i < 2; i++) {
    unsigned P = i * 4096 + tid * 16;
    *(u16x8*)&Ks[0][P >> 1] = kreg[i];
    *(u16x8*)&Vs[0][P >> 1] = vreg[i];
  }
  __syncthreads();

  // one tile step with statically-addressed buffers; wK/wV = write targets
  auto body = [&](int kt, const u16t* Kc, const u16t* Vc,
                  u16t* wK, u16t* wV) __attribute__((always_inline)) {
    const int kb = kt * 64;
    if (kt + 1 < ntiles) issue(kt + 1);  // latency covered by compute below

    if (kb <= q0 + 31) {
      f32x4 st[2][4] = {};   // st[mi][ni]: D[kv][q] (swapped)
      __builtin_amdgcn_s_setprio(1);
#pragma unroll
      for (int ni = 0; ni < 4; ni++) {
#pragma unroll
        for (int kc = 0; kc < 2; kc++) {
          unsigned row = ni * 16 + (lane & 15);
          unsigned slot = ((unsigned)(kc * 4 + (lane >> 4))) ^ (row & 7);
          bf16x8 bfr = *(const bf16x8*)&Kc[row * 64 + slot * 8];
          // swapped operand order: D = K . Q^T  (bit-same products/order)
          st[0][ni] = __builtin_amdgcn_mfma_f32_16x16x32_bf16(bfr, qf[0][kc], st[0][ni], 0, 0, 0);
          st[1][ni] = __builtin_amdgcn_mfma_f32_16x16x32_bf16(bfr, qf[1][kc], st[1][ni], 0, 0, 0);
        }
      }
      __builtin_amdgcn_s_setprio(0);

      if (kb + 63 > q0) {
#pragma unroll
        for (int mi = 0; mi < 2; mi++)
#pragma unroll
          for (int ni = 0; ni < 4; ni++) {
            int qq = q0 + mi * 16 + (lane & 15);  // q is now the column
#pragma unroll
            for (int r = 0; r < 4; r++) {
              int kk = kb + ni * 16 + ((lane >> 4) << 2) + r;  // kv is the row
              if (kk > qq) st[mi][ni][r] = -1e30f;
            }
          }
      }

      // P-store: 4 kv-consecutive values at fixed q -> one packed b64 per
      // (mi,ni). Same [q][kv] layout as before (read side unchanged).
#pragma unroll
      for (int mi = 0; mi < 2; mi++)
#pragma unroll
        for (int ni = 0; ni < 4; ni++) {
          u16x4 pk;
#pragma unroll
          for (int r = 0; r < 4; r++) {
            union { float f; unsigned int u; } pv;
            asm("v_exp_f32 %0, %1" : "=v"(pv.f) : "v"(st[mi][ni][r]));
            pk[r] = (u16t)(pv.u >> 16);  // truncating bf16
          }
          *(u16x4*)&Ps[wave][mi * 16 + (lane & 15)][ni * 16 + ((lane >> 4) << 2)] = pk;
        }

      bf16x8 pa[2][2];
#pragma unroll
      for (int mi = 0; mi < 2; mi++)
#pragma unroll
        for (int kc = 0; kc < 2; kc++)
          pa[mi][kc] = *(const bf16x8*)&Ps[wave][mi * 16 + (lane & 15)][kc * 32 + (lane >> 4) * 8];

      __builtin_amdgcn_s_setprio(1);
#pragma unroll
      for (int di = 0; di < 4; di++) {
#pragma unroll
        for (int kc = 0; kc < 2; kc++) {
          unsigned row = di * 16 + (lane & 15);
          unsigned slot = ((unsigned)(kc * 4 + (lane >> 4))) ^ (row & 7);
          bf16x8 vf = *(const bf16x8*)&Vc[row * 64 + slot * 8];
          o[0][di] = __builtin_amdgcn_mfma_f32_16x16x32_bf16(pa[0][kc], vf, o[0][di], 0, 0, 0);
          o[1][di] = __builtin_amdgcn_mfma_f32_16x16x32_bf16(pa[1][kc], vf, o[1][di], 0, 0, 0);
        }
      }
#pragma unroll
      for (int kc = 0; kc < 2; kc++) {
        ls[0] = __builtin_amdgcn_mfma_f32_16x16x32_bf16(pa[0][kc], ones, ls[0], 0, 0, 0);
        ls[1] = __builtin_amdgcn_mfma_f32_16x16x32_bf16(pa[1][kc], ones, ls[1], 0, 0, 0);
      }
      __builtin_amdgcn_s_setprio(0);
    }

    // Single barrier per tile: write kt+1 into the OTHER buffer (static
    // target), then publish.
    asm volatile("s_waitcnt vmcnt(0)" ::: "memory");  // issue(kt+1) landed; also compiler fence
    if (kt + 1 < ntiles) {
#pragma unroll
      for (int i = 0; i < 2; i++) {
        unsigned P = i * 4096 + tid * 16;
        *(u16x8*)&wK[P >> 1] = kreg[i];
        *(u16x8*)&wV[P >> 1] = vreg[i];
      }
    }
    __syncthreads();  // lgkm drain + barrier: writes visible before next compute
  };

  for (int kt = 0; kt < ntiles; kt += 2) {
    body(kt,     Ks[0], Vs[0], Ks[1], Vs[1]);   // cur=0, write buf 1
    body(kt + 1, Ks[1], Vs[1], Ks[0], Vs[0]);   // cur=1, write buf 0
  }

  u16t* Cp = ctx + (size_t)b * SEQN * EMB + h * HDIM;
#pragma unroll
  for (int mi = 0; mi < 2; mi++)
#pragma unroll
    for (int r = 0; r < 4; r++) {
      float inv = 1.f / ls[mi][r];
      int qq = q0 + mi * 16 + ((lane >> 4) << 2) + r;
#pragma unroll
      for (int di = 0; di < 4; di++)
        Cp[(size_t)qq * EMB + di * 16 + (lane & 15)] = f2b(o[mi][di][r] * inv);
    }
}

// -------------------------------------------------------------------------
extern "C" void kernel_launch(void* const* d_in, const int* in_sizes, int n_in,
                              void* d_out, int out_size, void* d_ws, size_t ws_size,
                              hipStream_t stream) {
  const float* x  = (const float*)d_in[0];
  const float* Wq = (const float*)d_in[1];
  const float* Wk = (const float*)d_in[2];
  const float* Wv = (const float*)d_in[3];
  const float* Wo = (const float*)d_in[4];
  const float* bo = (const float*)d_in[5];
  const float* W1 = (const float*)d_in[6];
  const float* b1 = (const float*)d_in[7];
  const float* W2 = (const float*)d_in[8];
  const float* b2 = (const float*)d_in[9];
  const float* g1 = (const float*)d_in[10];
  const float* s1 = (const float*)d_in[11];
  const float* g2 = (const float*)d_in[12];
  const float* s2 = (const float*)d_in[13];
  float* out = (float*)d_out;  // reference output dtype is float32

  // workspace layout (64 MiB total).
  // ALIAS MAP (liveness!):
  //   ff1 = qkvb..qkvb+32MB => covers qkvb(24MB) AND ctxb(8MB); live to FF2 end.
  //   vtb = hln (dead between QKV-GEMM and LN2); hln dead after FF1 reads it.
  char* p = (char*)d_ws;
  u16t* WqkvT = (u16t*)p; p += (size_t)3 * EMB * EMB * 2;   // [3072][1024]
  u16t* WoT   = (u16t*)p; p += (size_t)EMB * EMB * 2;       // [1024][1024]
  u16t* W1T   = (u16t*)p; p += (size_t)FFD * EMB * 2;       // [4096][1024]
  u16t* W2T   = (u16t*)p; p += (size_t)EMB * FFD * 2;       // [1024][4096]
  u16t* hln   = (u16t*)p; p += (size_t)ROWS * EMB * 2;      // [4096][1024]
  u16t* qkvb  = (u16t*)p; p += (size_t)ROWS * 3 * EMB * 2;  // [4096][3072]
  u16t* ctxb  = (u16t*)p; p += (size_t)ROWS * EMB * 2;      // [4096][1024]
  u16t* ff1   = qkvb;  // [4096][4096] aliases qkv(24MB)+ctx(8MB)
  u16t* vtb   = hln;   // [32][64][2048] aliases hln

  dim3 blk(256);
  // merged transposes + LN1 (blocks >= 12288 run LN rows)
  trln_k<<<dim3(12288 + ROWS), blk, 0, stream>>>(Wq, Wk, Wv, Wo, W1, W2,
                                                 WqkvT, WoT, W1T, W2T, x, g1, s1, hln);
  gemm256_k<false, false, false><<<dim3((3 * EMB / 256) * (ROWS / 256)), dim3(512), 0, stream>>>(
      hln, WqkvT, nullptr, qkvb, ROWS, 3 * EMB, EMB);
  vtr_k<<<dim3(SEQN / 32, HDIM / 32, BATCH * HEADS), blk, 0, stream>>>(qkvb, vtb);
  attn_k<<<dim3(SEQN / 128, HEADS, BATCH), blk, 0, stream>>>(qkvb, vtb, ctxb);
  gemm_k<64, false, true, true, true, true><<<dim3((EMB / 64) * (ROWS / 128)), blk, 0, stream>>>(
      ctxb, WoT, bo, x, out, ROWS, EMB, EMB);
  ln_k<true><<<ROWS, blk, 0, stream>>>(out, g2, s2, hln);
  gemm256_k<true, true, false><<<dim3((FFD / 256) * (ROWS / 256)), dim3(512), 0, stream>>>(
      hln, W1T, b1, ff1, ROWS, FFD, EMB);
  gemm_k<64, false, true, true, true, true><<<dim3((EMB / 64) * (ROWS / 128)), blk, 0, stream>>>(
      ff1, W2T, b2, out, out, ROWS, EMB, FFD);
}

// Round 16
// 208.182 us; speedup vs baseline: 1.0951x; 1.0124x over previous
//
#include <hip/hip_runtime.h>
#include <stdint.h>

#define EMB 1024
#define HEADS 16
#define HDIM 64
#define SEQN 2048
#define BATCH 2
#define FFD 4096
#define ROWS (BATCH * SEQN)

typedef unsigned short u16t;
typedef __attribute__((ext_vector_type(4))) unsigned short u16x4;
typedef __attribute__((ext_vector_type(8))) unsigned short u16x8;
typedef __attribute__((ext_vector_type(8))) __bf16 bf16x8;
typedef __attribute__((ext_vector_type(4))) float f32x4;

__device__ __forceinline__ float b2f(u16t u) {
  union { float f; unsigned int i; } v; v.i = ((unsigned int)u) << 16; return v.f;
}
__device__ __forceinline__ u16t f2b(float f) {
  union { float f; unsigned int i; } v; v.f = f;
  unsigned int r = v.i + 0x7FFFu + ((v.i >> 16) & 1u);
  return (u16t)(r >> 16);
}

// gelu_tanh via sigmoid identity: 0.5v(1+tanh(t)) = v/(1+e^{-2t}).
// Confirmed: warm pipeline gain ~21 us vs libm tanhf (R1 vs R6).
__device__ __forceinline__ float gelu_f(float v) {
  float t2 = 1.5957691216057308f * (v + 0.044715f * v * v * v);  // 2*sqrt(2/pi)*(...)
  return v / (1.f + __expf(-t2));
}

__device__ __forceinline__ void gload16(const u16t* g, u16t* l) {
  __builtin_amdgcn_global_load_lds((const __attribute__((address_space(1))) void*)g,
                                   (__attribute__((address_space(3))) void*)l, 16, 0, 0);
}

// ---------------- LayerNorm: one block per row (1024 cols) ----------------
template <bool INF32>
__global__ __launch_bounds__(256) void ln_k(const void* __restrict__ x_, const float* __restrict__ g,
                                            const float* __restrict__ s, u16t* __restrict__ out) {
  const int row = blockIdx.x;
  const int t = threadIdx.x;
  float f[4];
  if (INF32) {
    const float4* xr = (const float4*)((const float*)x_ + (size_t)row * EMB);
    float4 xv = xr[t];
    f[0] = xv.x; f[1] = xv.y; f[2] = xv.z; f[3] = xv.w;
  } else {
    const u16t* xr = (const u16t*)x_ + (size_t)row * EMB;
    u16x4 xv = *(const u16x4*)(xr + t * 4);
#pragma unroll
    for (int i = 0; i < 4; i++) f[i] = b2f(xv[i]);
  }
  float sum = 0.f, sq = 0.f;
#pragma unroll
  for (int i = 0; i < 4; i++) { sum += f[i]; sq += f[i] * f[i]; }
#pragma unroll
  for (int off = 1; off < 64; off <<= 1) { sum += __shfl_xor(sum, off); sq += __shfl_xor(sq, off); }
  __shared__ float red[8];
  const int lane = t & 63, wave = t >> 6;
  if (lane == 0) { red[wave] = sum; red[4 + wave] = sq; }
  __syncthreads();
  sum = red[0] + red[1] + red[2] + red[3];
  sq = red[4] + red[5] + red[6] + red[7];
  const float mean = sum * (1.f / EMB);
  const float var = sq * (1.f / EMB) - mean * mean;
  const float rstd = rsqrtf(var + 1e-5f);
  float4 gv = ((const float4*)g)[t];
  float4 sv = ((const float4*)s)[t];
  float gg[4] = {gv.x, gv.y, gv.z, gv.w};
  float ss[4] = {sv.x, sv.y, sv.z, sv.w};
  u16x4 ov;
#pragma unroll
  for (int i = 0; i < 4; i++) ov[i] = f2b((f[i] - mean) * rstd * gg[i] + ss[i]);
  *(u16x4*)(out + (size_t)row * EMB + t * 4) = ov;
}

// ------ Merged: ALL 6 weight transposes + LN1 in ONE dispatch ------------
__global__ __launch_bounds__(256) void trln_k(const float* __restrict__ Wq, const float* __restrict__ Wk,
                                              const float* __restrict__ Wv, const float* __restrict__ Wo,
                                              const float* __restrict__ W1, const float* __restrict__ W2,
                                              u16t* __restrict__ WqkvT, u16t* __restrict__ WoT,
                                              u16t* __restrict__ W1T, u16t* __restrict__ W2T,
                                              const float* __restrict__ x, const float* __restrict__ g1,
                                              const float* __restrict__ s1, u16t* __restrict__ hln) {
  int t = blockIdx.x;
  if (t >= 12288) {
    // ---- LN1 part: one block per row ----
    const int row = t - 12288;
    const int tt = threadIdx.x;
    const float4* xr = (const float4*)(x + (size_t)row * EMB);
    float4 xv = xr[tt];
    float f[4] = {xv.x, xv.y, xv.z, xv.w};
    float sum = 0.f, sq = 0.f;
#pragma unroll
    for (int i = 0; i < 4; i++) { sum += f[i]; sq += f[i] * f[i]; }
#pragma unroll
    for (int off = 1; off < 64; off <<= 1) { sum += __shfl_xor(sum, off); sq += __shfl_xor(sq, off); }
    __shared__ float red[8];
    const int lane = tt & 63, wave = tt >> 6;
    if (lane == 0) { red[wave] = sum; red[4 + wave] = sq; }
    __syncthreads();
    sum = red[0] + red[1] + red[2] + red[3];
    sq = red[4] + red[5] + red[6] + red[7];
    const float mean = sum * (1.f / EMB);
    const float var = sq * (1.f / EMB) - mean * mean;
    const float rstd = rsqrtf(var + 1e-5f);
    float4 gv = ((const float4*)g1)[tt];
    float4 sv = ((const float4*)s1)[tt];
    float gg[4] = {gv.x, gv.y, gv.z, gv.w};
    float ss[4] = {sv.x, sv.y, sv.z, sv.w};
    u16x4 ov;
#pragma unroll
    for (int i = 0; i < 4; i++) ov[i] = f2b((f[i] - mean) * rstd * gg[i] + ss[i]);
    *(u16x4*)(hln + (size_t)row * EMB + tt * 4) = ov;
    return;
  }
  // ---- transpose part ----
  const float* in; u16t* out; int R, C;
  if (t < 4096) {
    R = EMB; C = EMB;
    const int seg = t >> 10; t &= 1023;
    if (seg == 0)      { in = Wq; out = WqkvT; }
    else if (seg == 1) { in = Wk; out = WqkvT + (size_t)EMB * EMB; }
    else if (seg == 2) { in = Wv; out = WqkvT + (size_t)2 * EMB * EMB; }
    else               { in = Wo; out = WoT; }
  } else if (t < 8192) {
    in = W1; out = W1T; R = EMB; C = FFD; t -= 4096;
  } else {
    in = W2; out = W2T; R = FFD; C = EMB; t -= 8192;
  }
  const int bx = t % (C >> 5), by = t / (C >> 5);

  __shared__ float tile[32][33];
  const int tx = threadIdx.x & 31, ty = threadIdx.x >> 5;
  const int c = bx * 32 + tx;
#pragma unroll
  for (int i = 0; i < 4; i++) {
    int r = by * 32 + ty + i * 8;
    tile[ty + i * 8][tx] = in[(size_t)r * C + c];
  }
  __syncthreads();
  const int r2 = by * 32 + tx;
#pragma unroll
  for (int i = 0; i < 4; i++) {
    int c2 = bx * 32 + ty + i * 8;
    out[(size_t)c2 * R + r2] = f2b(tile[tx][ty + i * 8]);
  }
}

// ---------------- V transpose: qkv V part -> vt[b*H+h][64][SEQN] ---------
__global__ __launch_bounds__(256) void vtr_k(const u16t* __restrict__ qkv, u16t* __restrict__ vt) {
  __shared__ u16t tile[32][33];
  const int tx = threadIdx.x & 31, ty = threadIdx.x >> 5;  // 32 x 8
  const int k0 = blockIdx.x * 32;
  const int d0 = blockIdx.y * 32;
  const int bh = blockIdx.z;
  const int b = bh / HEADS, h = bh % HEADS;
  const u16t* src = qkv + (size_t)b * SEQN * (3 * EMB) + 2 * EMB + h * HDIM;
#pragma unroll
  for (int i = 0; i < 4; i++)
    tile[ty + i * 8][tx] = src[(size_t)(k0 + ty + i * 8) * (3 * EMB) + d0 + tx];
  __syncthreads();
  u16t* dst = vt + ((size_t)bh * HDIM + d0) * SEQN + k0;
#pragma unroll
  for (int i = 0; i < 4; i++)
    dst[(size_t)(ty + i * 8) * SEQN + tx] = tile[tx][ty + i * 8];
}

// ------- GEMM 256x256 tile: 4-phase, T2 swizzle, counted vmcnt -----------
// R16: K-loop unrolled by 2 (nk = K/64 = 16 at both call sites -> even, no
// tail executes). All As/Bs buffer bases + staging targets become
// compile-time literals (same static-addressing transform that won R14 on
// gemm_k and R15 on attn). Ops and order unchanged -> bit-identical.
template <bool GELU, bool BIAS, bool OUTF32>
__global__ __launch_bounds__(512, 2) void gemm256_k(const u16t* __restrict__ A, const u16t* __restrict__ Bt,
                                                    const float* __restrict__ bias, void* __restrict__ C_,
                                                    int M, int N, int K) {
  __shared__ u16t As[2][256 * 64];
  __shared__ u16t Bs[2][256 * 64];
  const int tid = threadIdx.x;
  const int lane = tid & 63, wave = tid >> 6;
  const int wr = wave >> 2, wc = wave & 3;  // 2 x 4 waves
  const int nwg = gridDim.x, per = nwg >> 3;
  const int swz = (blockIdx.x & 7) * per + (blockIdx.x >> 3);
  const int nx = N >> 8;
  const int m0 = (swz / nx) * 256, n0 = (swz % nx) * 256;
  f32x4 acc[8][4] = {};
  const int nk = K >> 6;

  // stage one 128-row half (2 loads/thread) of the A or B tile
  auto stageA = [&](int t, u16t* buf, int h) {
    const int k0 = t << 6;
#pragma unroll
    for (int i = 0; i < 2; i++) {
      unsigned P = (h * 2 + i) * 8192 + tid * 16;
      unsigned row = P >> 7, slot = ((P >> 4) & 7) ^ (row & 7);
      gload16(A + (size_t)(m0 + row) * K + k0 + slot * 8, &buf[P >> 1]);
    }
  };
  auto stageB = [&](int t, u16t* buf, int h) {
    const int k0 = t << 6;
#pragma unroll
    for (int i = 0; i < 2; i++) {
      unsigned P = (h * 2 + i) * 8192 + tid * 16;
      unsigned row = P >> 7, slot = ((P >> 4) & 7) ^ (row & 7);
      gload16(Bt + (size_t)(n0 + row) * K + k0 + slot * 8, &buf[P >> 1]);
    }
  };

  // prologue: tile0 A+B, tile1 B (B of buf[1] is only read at tile1 phase 0)
  stageA(0, As[0], 0); stageA(0, As[0], 1);
  stageB(0, Bs[0], 0); stageB(0, Bs[0], 1);
  if (nk > 1) {
    stageB(1, Bs[1], 0); stageB(1, Bs[1], 1);
    asm volatile("s_waitcnt vmcnt(4)" ::: "memory");  // A(0),B(0) done; B(1) in flight
  } else {
    asm volatile("s_waitcnt vmcnt(0)" ::: "memory");
  }
  __builtin_amdgcn_s_barrier();

  // one K-tile (4 phases) against statically-addressed buffers.
  // Anx = stageA target (other buffer), Bcu = stageB target (current).
  auto tstep = [&](int t, const u16t* Asc, const u16t* Bsc,
                   u16t* Anx, u16t* Bcu) __attribute__((always_inline)) {
    auto rdA = [&](int mi, int kc) -> bf16x8 {
      unsigned row = wr * 128 + mi * 16 + (lane & 15);
      unsigned slot = ((unsigned)(kc * 4 + (lane >> 4))) ^ (row & 7);
      return *(const bf16x8*)&Asc[row * 64 + slot * 8];
    };
    // ---- phase 0 ----
    bf16x8 bfr[4][2];
#pragma unroll
    for (int ni = 0; ni < 4; ni++)
#pragma unroll
      for (int kc = 0; kc < 2; kc++) {
        unsigned row = wc * 64 + ni * 16 + (lane & 15);
        unsigned slot = ((unsigned)(kc * 4 + (lane >> 4))) ^ (row & 7);
        bfr[ni][kc] = *(const bf16x8*)&Bsc[row * 64 + slot * 8];
      }
    bf16x8 aL0 = rdA(0, 0), aL1 = rdA(0, 1), aH0 = rdA(1, 0), aH1 = rdA(1, 1);
    if (t + 1 < nk) stageA(t + 1, Anx, 0);
    __builtin_amdgcn_s_barrier();
    __builtin_amdgcn_s_setprio(1);
#pragma unroll
    for (int ni = 0; ni < 4; ni++) {
      acc[0][ni] = __builtin_amdgcn_mfma_f32_16x16x32_bf16(aL0, bfr[ni][0], acc[0][ni], 0, 0, 0);
      acc[0][ni] = __builtin_amdgcn_mfma_f32_16x16x32_bf16(aL1, bfr[ni][1], acc[0][ni], 0, 0, 0);
      acc[1][ni] = __builtin_amdgcn_mfma_f32_16x16x32_bf16(aH0, bfr[ni][0], acc[1][ni], 0, 0, 0);
      acc[1][ni] = __builtin_amdgcn_mfma_f32_16x16x32_bf16(aH1, bfr[ni][1], acc[1][ni], 0, 0, 0);
    }
    __builtin_amdgcn_s_setprio(0);
    __builtin_amdgcn_s_barrier();
    // ---- phase 1 ----
    aL0 = rdA(2, 0); aL1 = rdA(2, 1); aH0 = rdA(3, 0); aH1 = rdA(3, 1);
    if (t + 1 < nk) stageA(t + 1, Anx, 1);
    __builtin_amdgcn_s_barrier();
    __builtin_amdgcn_s_setprio(1);
#pragma unroll
    for (int ni = 0; ni < 4; ni++) {
      acc[2][ni] = __builtin_amdgcn_mfma_f32_16x16x32_bf16(aL0, bfr[ni][0], acc[2][ni], 0, 0, 0);
      acc[2][ni] = __builtin_amdgcn_mfma_f32_16x16x32_bf16(aL1, bfr[ni][1], acc[2][ni], 0, 0, 0);
      acc[3][ni] = __builtin_amdgcn_mfma_f32_16x16x32_bf16(aH0, bfr[ni][0], acc[3][ni], 0, 0, 0);
      acc[3][ni] = __builtin_amdgcn_mfma_f32_16x16x32_bf16(aH1, bfr[ni][1], acc[3][ni], 0, 0, 0);
    }
    __builtin_amdgcn_s_setprio(0);
    __builtin_amdgcn_s_barrier();
    // ---- phase 2 ----
    aL0 = rdA(4, 0); aL1 = rdA(4, 1); aH0 = rdA(5, 0); aH1 = rdA(5, 1);
    if (t + 2 < nk) stageB(t + 2, Bcu, 0);  // Bsc B-frags already in regs
    __builtin_amdgcn_s_barrier();
    __builtin_amdgcn_s_setprio(1);
#pragma unroll
    for (int ni = 0; ni < 4; ni++) {
      acc[4][ni] = __builtin_amdgcn_mfma_f32_16x16x32_bf16(aL0, bfr[ni][0], acc[4][ni], 0, 0, 0);
      acc[4][ni] = __builtin_amdgcn_mfma_f32_16x16x32_bf16(aL1, bfr[ni][1], acc[4][ni], 0, 0, 0);
      acc[5][ni] = __builtin_amdgcn_mfma_f32_16x16x32_bf16(aH0, bfr[ni][0], acc[5][ni], 0, 0, 0);
      acc[5][ni] = __builtin_amdgcn_mfma_f32_16x16x32_bf16(aH1, bfr[ni][1], acc[5][ni], 0, 0, 0);
    }
    __builtin_amdgcn_s_setprio(0);
    __builtin_amdgcn_s_barrier();
    // ---- phase 3 ----
    aL0 = rdA(6, 0); aL1 = rdA(6, 1); aH0 = rdA(7, 0); aH1 = rdA(7, 1);
    if (t + 2 < nk) stageB(t + 2, Bcu, 1);
    if (t + 2 < nk)      asm volatile("s_waitcnt vmcnt(4)" ::: "memory");
    else if (t + 1 < nk) asm volatile("s_waitcnt vmcnt(0)" ::: "memory");
    __builtin_amdgcn_s_barrier();
    __builtin_amdgcn_s_setprio(1);
#pragma unroll
    for (int ni = 0; ni < 4; ni++) {
      acc[6][ni] = __builtin_amdgcn_mfma_f32_16x16x32_bf16(aL0, bfr[ni][0], acc[6][ni], 0, 0, 0);
      acc[6][ni] = __builtin_amdgcn_mfma_f32_16x16x32_bf16(aL1, bfr[ni][1], acc[6][ni], 0, 0, 0);
      acc[7][ni] = __builtin_amdgcn_mfma_f32_16x16x32_bf16(aH0, bfr[ni][0], acc[7][ni], 0, 0, 0);
      acc[7][ni] = __builtin_amdgcn_mfma_f32_16x16x32_bf16(aH1, bfr[ni][1], acc[7][ni], 0, 0, 0);
    }
    __builtin_amdgcn_s_setprio(0);
    __builtin_amdgcn_s_barrier();
  };

  int t = 0;
  for (; t + 2 <= nk; t += 2) {   // steady state: static buffer ids
    tstep(t,     As[0], Bs[0], As[1], Bs[0]);  // cur=0: A->buf1, B(t+2)->buf0
    tstep(t + 1, As[1], Bs[1], As[0], Bs[1]);  // cur=1: A->buf0, B(t+2)->buf1
  }
  for (; t < nk; t++)             // tail (never executes for K=1024)
    tstep(t, As[t & 1], Bs[t & 1], As[(t & 1) ^ 1], Bs[t & 1]);

#pragma unroll
  for (int mi = 0; mi < 8; mi++) {
#pragma unroll
    for (int ni = 0; ni < 4; ni++) {
      int col = n0 + wc * 64 + ni * 16 + (lane & 15);
      int rb = m0 + wr * 128 + mi * 16 + ((lane >> 4) << 2);
      float bv = 0.f;
      if (BIAS) bv = bias[col];
#pragma unroll
      for (int r = 0; r < 4; r++) {
        float v = acc[mi][ni][r] + bv;
        if (GELU) v = gelu_f(v);
        size_t idx = (size_t)(rb + r) * N + col;
        if (OUTF32) ((float*)C_)[idx] = v;
        else ((u16t*)C_)[idx] = f2b(v);
      }
    }
  }
}

// -------- GEMM 128x64 (N=1024 shapes): 3-stage ring, counted vmcnt, T2 ---
// R14: K-loop unrolled by 3 -> static ring ids (ds offsets fold to
// immediates). Confirmed -1.2us.
template <int BN, bool GELU, bool RESID, bool BIAS, bool RESF32, bool OUTF32>
__global__ __launch_bounds__(256) void gemm_k(const u16t* __restrict__ A, const u16t* __restrict__ Bt,
                                              const float* __restrict__ bias, const void* __restrict__ res_,
                                              void* __restrict__ C_, int M, int N, int K) {
  constexpr int NF = BN / 32;
  static_assert(BN == 64, "vmcnt count assumes 6 loads/stage");
  __shared__ u16t As[3][128 * 64];
  __shared__ u16t Bs[3][BN * 64];
  const int tid = threadIdx.x;
  const int lane = tid & 63;
  const int wave = tid >> 6;
  const int nx = N / BN, pnx = nx >> 3;
  const int bid = blockIdx.x;
  const int xcd = bid & 7, idx = bid >> 3;
  const int n0 = (xcd * pnx + (idx % pnx)) * BN;
  const int m0 = (idx / pnx) * 128;
  const int wm = (wave >> 1) * 64, wn = (wave & 1) * (BN / 2);
  f32x4 acc[4][NF] = {};
  const int nk = K >> 6;

  auto stage = [&](int t, int buf) {
    const int k0 = t << 6;
#pragma unroll
    for (int i = 0; i < 4; i++) {
      unsigned P = i * 4096 + tid * 16;
      unsigned row = P >> 7, slot = ((P >> 4) & 7) ^ (row & 7);
      gload16(A + (size_t)(m0 + row) * K + k0 + slot * 8, &As[buf][P >> 1]);
    }
#pragma unroll
    for (int i = 0; i < BN / 32; i++) {
      unsigned P = i * 4096 + tid * 16;
      unsigned row = P >> 7, slot = ((P >> 4) & 7) ^ (row & 7);
      gload16(Bt + (size_t)(n0 + row) * K + k0 + slot * 8, &Bs[buf][P >> 1]);
    }
  };

  // one K-step against statically-addressed buffers Asc/Bsc; prefetch
  // target sbuf is also a literal at every steady-state call site.
  auto kstep = [&](int t, const u16t* Asc, const u16t* Bsc, int sbuf) __attribute__((always_inline)) {
    if (t + 1 < nk) asm volatile("s_waitcnt vmcnt(6)" ::: "memory");
    else            asm volatile("s_waitcnt vmcnt(0)" ::: "memory");
    __builtin_amdgcn_s_barrier();
#pragma unroll
    for (int kc = 0; kc < 2; kc++) {
      bf16x8 af[4], bf[NF];
#pragma unroll
      for (int mi = 0; mi < 4; mi++) {
        unsigned row = wm + mi * 16 + (lane & 15);
        unsigned slot = ((unsigned)(kc * 4 + (lane >> 4))) ^ (row & 7);
        af[mi] = *(const bf16x8*)&Asc[row * 64 + slot * 8];
      }
#pragma unroll
      for (int ni = 0; ni < NF; ni++) {
        unsigned row = wn + ni * 16 + (lane & 15);
        unsigned slot = ((unsigned)(kc * 4 + (lane >> 4))) ^ (row & 7);
        bf[ni] = *(const bf16x8*)&Bsc[row * 64 + slot * 8];
      }
      __builtin_amdgcn_s_setprio(1);
#pragma unroll
      for (int mi = 0; mi < 4; mi++)
#pragma unroll
        for (int ni = 0; ni < NF; ni++)
          acc[mi][ni] = __builtin_amdgcn_mfma_f32_16x16x32_bf16(af[mi], bf[ni], acc[mi][ni], 0, 0, 0);
      __builtin_amdgcn_s_setprio(0);
    }
    if (t + 2 < nk) stage(t + 2, sbuf);
  };

  stage(0, 0);
  if (nk > 1) stage(1, 1);

  int t = 0;
  for (; t + 3 <= nk; t += 3) {        // steady state: static ring ids
    kstep(t,     As[0], Bs[0], 2);     // prefetch (t+2)%3 == 2
    kstep(t + 1, As[1], Bs[1], 0);
    kstep(t + 2, As[2], Bs[2], 1);
  }
  for (; t < nk; t++)                  // tail (<=2 iters, dynamic ids)
    kstep(t, As[t % 3], Bs[t % 3], (t + 2) % 3);

#pragma unroll
  for (int mi = 0; mi < 4; mi++) {
#pragma unroll
    for (int ni = 0; ni < NF; ni++) {
      int col = n0 + wn + ni * 16 + (lane & 15);
      int rb = m0 + wm + mi * 16 + ((lane >> 4) << 2);
      float bv = 0.f;
      if (BIAS) bv = bias[col];
#pragma unroll
      for (int r = 0; r < 4; r++) {
        float v = acc[mi][ni][r] + bv;
        if (GELU) v = gelu_f(v);
        size_t idx = (size_t)(rb + r) * N + col;
        if (RESID) v += RESF32 ? ((const float*)res_)[idx] : b2f(((const u16t*)res_)[idx]);
        if (OUTF32) ((float*)C_)[idx] = v;
        else ((u16t*)C_)[idx] = f2b(v);
      }
    }
  }
}

// -- Flash attention (causal), KVBLK=64, abs softmax ----------------------
// R15 structure (best known): swapped QK^T (packed b64 P-store), dbuf K/V
// reg-staging with unroll-by-2 static LDS addressing, truncating P->bf16,
// exp2-direct via Q pre-scale.
__global__ __launch_bounds__(256) void attn_k(const u16t* __restrict__ qkv,
                                              const u16t* __restrict__ vt,
                                              u16t* __restrict__ ctx) {
  const int b = blockIdx.z, h = blockIdx.y;
  const int tid = threadIdx.x, lane = tid & 63, wave = tid >> 6;
  const int bx = (b == 1) ? (gridDim.x - 1 - blockIdx.x) : blockIdx.x;  // causal balance
  const int q0 = bx * 128 + wave * 32;
  const int ld = 3 * EMB;
  const u16t* Qp = qkv + (size_t)b * SEQN * ld + h * HDIM;
  const u16t* Kp = Qp + EMB;
  const u16t* VTp = vt + (size_t)(b * HEADS + h) * HDIM * SEQN;  // [64][SEQN]

  __shared__ u16t Ks[2][64 * 64];
  __shared__ u16t Vs[2][64 * 64];
  __shared__ u16t Ps[4][32][72];

  bf16x8 qf[2][2];
#pragma unroll
  for (int mi = 0; mi < 2; mi++)
#pragma unroll
    for (int kc = 0; kc < 2; kc++) {
      u16x8 qraw = *(const u16x8*)(Qp + (size_t)(q0 + mi * 16 + (lane & 15)) * ld + kc * 32 + (lane >> 4) * 8);
      u16x8 qs;
#pragma unroll
      for (int j = 0; j < 8; j++) qs[j] = f2b(b2f(qraw[j]) * 0.18033688011112042f);  // (1/8)*log2(e)
      qf[mi][kc] = __builtin_bit_cast(bf16x8, qs);
    }

  u16x8 onesu;
#pragma unroll
  for (int j = 0; j < 8; j++) onesu[j] = 0x3F80;  // bf16 1.0
  const bf16x8 ones = __builtin_bit_cast(bf16x8, onesu);

  f32x4 o[2][4] = {};
  f32x4 ls[2] = {};

  u16x8 kreg[2], vreg[2];
  auto issue = [&](int kt) {  // global (pre-swizzled source) -> regs
    const int kb = kt * 64;
#pragma unroll
    for (int i = 0; i < 2; i++) {
      unsigned P = i * 4096 + tid * 16;
      unsigned row = P >> 7;
      unsigned slot = ((P >> 4) & 7) ^ (row & 7);
      kreg[i] = *(const u16x8*)(Kp + (size_t)(kb + row) * ld + slot * 8);
      vreg[i] = *(const u16x8*)(VTp + (size_t)row * SEQN + kb + slot * 8);
    }
  };

  const int ntiles = 2 * bx + 2;  // ALWAYS EVEN -> clean unroll-by-2
  // prologue: tile 0 into LDS buf 0
  issue(0);
  asm volatile("s_waitcnt vmcnt(0)" ::: "memory");
#pragma unroll
  for (int i = 0; i < 2; i++) {
    unsigned P = i * 4096 + tid * 16;
    *(u16x8*)&Ks[0][P >> 1] = kreg[i];
    *(u16x8*)&Vs[0][P >> 1] = vreg[i];
  }
  __syncthreads();

  // one tile step with statically-addressed buffers; wK/wV = write targets
  auto body = [&](int kt, const u16t* Kc, const u16t* Vc,
                  u16t* wK, u16t* wV) __attribute__((always_inline)) {
    const int kb = kt * 64;
    if (kt + 1 < ntiles) issue(kt + 1);  // latency covered by compute below

    if (kb <= q0 + 31) {
      f32x4 st[2][4] = {};   // st[mi][ni]: D[kv][q] (swapped)
      __builtin_amdgcn_s_setprio(1);
#pragma unroll
      for (int ni = 0; ni < 4; ni++) {
#pragma unroll
        for (int kc = 0; kc < 2; kc++) {
          unsigned row = ni * 16 + (lane & 15);
          unsigned slot = ((unsigned)(kc * 4 + (lane >> 4))) ^ (row & 7);
          bf16x8 bfr = *(const bf16x8*)&Kc[row * 64 + slot * 8];
          // swapped operand order: D = K . Q^T  (bit-same products/order)
          st[0][ni] = __builtin_amdgcn_mfma_f32_16x16x32_bf16(bfr, qf[0][kc], st[0][ni], 0, 0, 0);
          st[1][ni] = __builtin_amdgcn_mfma_f32_16x16x32_bf16(bfr, qf[1][kc], st[1][ni], 0, 0, 0);
        }
      }
      __builtin_amdgcn_s_setprio(0);

      if (kb + 63 > q0) {
#pragma unroll
        for (int mi = 0; mi < 2; mi++)
#pragma unroll
          for (int ni = 0; ni < 4; ni++) {
            int qq = q0 + mi * 16 + (lane & 15);  // q is now the column
#pragma unroll
            for (int r = 0; r < 4; r++) {
              int kk = kb + ni * 16 + ((lane >> 4) << 2) + r;  // kv is the row
              if (kk > qq) st[mi][ni][r] = -1e30f;
            }
          }
      }

      // P-store: 4 kv-consecutive values at fixed q -> one packed b64 per
      // (mi,ni). Same [q][kv] layout as before (read side unchanged).
#pragma unroll
      for (int mi = 0; mi < 2; mi++)
#pragma unroll
        for (int ni = 0; ni < 4; ni++) {
          u16x4 pk;
#pragma unroll
          for (int r = 0; r < 4; r++) {
            union { float f; unsigned int u; } pv;
            asm("v_exp_f32 %0, %1" : "=v"(pv.f) : "v"(st[mi][ni][r]));
            pk[r] = (u16t)(pv.u >> 16);  // truncating bf16
          }
          *(u16x4*)&Ps[wave][mi * 16 + (lane & 15)][ni * 16 + ((lane >> 4) << 2)] = pk;
        }

      bf16x8 pa[2][2];
#pragma unroll
      for (int mi = 0; mi < 2; mi++)
#pragma unroll
        for (int kc = 0; kc < 2; kc++)
          pa[mi][kc] = *(const bf16x8*)&Ps[wave][mi * 16 + (lane & 15)][kc * 32 + (lane >> 4) * 8];

      __builtin_amdgcn_s_setprio(1);
#pragma unroll
      for (int di = 0; di < 4; di++) {
#pragma unroll
        for (int kc = 0; kc < 2; kc++) {
          unsigned row = di * 16 + (lane & 15);
          unsigned slot = ((unsigned)(kc * 4 + (lane >> 4))) ^ (row & 7);
          bf16x8 vf = *(const bf16x8*)&Vc[row * 64 + slot * 8];
          o[0][di] = __builtin_amdgcn_mfma_f32_16x16x32_bf16(pa[0][kc], vf, o[0][di], 0, 0, 0);
          o[1][di] = __builtin_amdgcn_mfma_f32_16x16x32_bf16(pa[1][kc], vf, o[1][di], 0, 0, 0);
        }
      }
#pragma unroll
      for (int kc = 0; kc < 2; kc++) {
        ls[0] = __builtin_amdgcn_mfma_f32_16x16x32_bf16(pa[0][kc], ones, ls[0], 0, 0, 0);
        ls[1] = __builtin_amdgcn_mfma_f32_16x16x32_bf16(pa[1][kc], ones, ls[1], 0, 0, 0);
      }
      __builtin_amdgcn_s_setprio(0);
    }

    // Single barrier per tile: write kt+1 into the OTHER buffer (static
    // target), then publish.
    asm volatile("s_waitcnt vmcnt(0)" ::: "memory");  // issue(kt+1) landed; also compiler fence
    if (kt + 1 < ntiles) {
#pragma unroll
      for (int i = 0; i < 2; i++) {
        unsigned P = i * 4096 + tid * 16;
        *(u16x8*)&wK[P >> 1] = kreg[i];
        *(u16x8*)&wV[P >> 1] = vreg[i];
      }
    }
    __syncthreads();  // lgkm drain + barrier: writes visible before next compute
  };

  for (int kt = 0; kt < ntiles; kt += 2) {
    body(kt,     Ks[0], Vs[0], Ks[1], Vs[1]);   // cur=0, write buf 1
    body(kt + 1, Ks[1], Vs[1], Ks[0], Vs[0]);   // cur=1, write buf 0
  }

  u16t* Cp = ctx + (size_t)b * SEQN * EMB + h * HDIM;
#pragma unroll
  for (int mi = 0; mi < 2; mi++)
#pragma unroll
    for (int r = 0; r < 4; r++) {
      float inv = 1.f / ls[mi][r];
      int qq = q0 + mi * 16 + ((lane >> 4) << 2) + r;
#pragma unroll
      for (int di = 0; di < 4; di++)
        Cp[(size_t)qq * EMB + di * 16 + (lane & 15)] = f2b(o[mi][di][r] * inv);
    }
}

// -------------------------------------------------------------------------
extern "C" void kernel_launch(void* const* d_in, const int* in_sizes, int n_in,
                              void* d_out, int out_size, void* d_ws, size_t ws_size,
                              hipStream_t stream) {
  const float* x  = (const float*)d_in[0];
  const float* Wq = (const float*)d_in[1];
  const float* Wk = (const float*)d_in[2];
  const float* Wv = (const float*)d_in[3];
  const float* Wo = (const float*)d_in[4];
  const float* bo = (const float*)d_in[5];
  const float* W1 = (const float*)d_in[6];
  const float* b1 = (const float*)d_in[7];
  const float* W2 = (const float*)d_in[8];
  const float* b2 = (const float*)d_in[9];
  const float* g1 = (const float*)d_in[10];
  const float* s1 = (const float*)d_in[11];
  const float* g2 = (const float*)d_in[12];
  const float* s2 = (const float*)d_in[13];
  float* out = (float*)d_out;  // reference output dtype is float32

  // workspace layout (64 MiB total).
  // ALIAS MAP (liveness!):
  //   ff1 = qkvb..qkvb+32MB => covers qkvb(24MB) AND ctxb(8MB); live to FF2 end.
  //   vtb = hln (dead between QKV-GEMM and LN2); hln dead after FF1 reads it.
  char* p = (char*)d_ws;
  u16t* WqkvT = (u16t*)p; p += (size_t)3 * EMB * EMB * 2;   // [3072][1024]
  u16t* WoT   = (u16t*)p; p += (size_t)EMB * EMB * 2;       // [1024][1024]
  u16t* W1T   = (u16t*)p; p += (size_t)FFD * EMB * 2;       // [4096][1024]
  u16t* W2T   = (u16t*)p; p += (size_t)EMB * FFD * 2;       // [1024][4096]
  u16t* hln   = (u16t*)p; p += (size_t)ROWS * EMB * 2;      // [4096][1024]
  u16t* qkvb  = (u16t*)p; p += (size_t)ROWS * 3 * EMB * 2;  // [4096][3072]
  u16t* ctxb  = (u16t*)p; p += (size_t)ROWS * EMB * 2;      // [4096][1024]
  u16t* ff1   = qkvb;  // [4096][4096] aliases qkv(24MB)+ctx(8MB)
  u16t* vtb   = hln;   // [32][64][2048] aliases hln

  dim3 blk(256);
  // merged transposes + LN1 (blocks >= 12288 run LN rows)
  trln_k<<<dim3(12288 + ROWS), blk, 0, stream>>>(Wq, Wk, Wv, Wo, W1, W2,
                                                 WqkvT, WoT, W1T, W2T, x, g1, s1, hln);
  gemm256_k<false, false, false><<<dim3((3 * EMB / 256) * (ROWS / 256)), dim3(512), 0, stream>>>(
      hln, WqkvT, nullptr, qkvb, ROWS, 3 * EMB, EMB);
  vtr_k<<<dim3(SEQN / 32, HDIM / 32, BATCH * HEADS), blk, 0, stream>>>(qkvb, vtb);
  attn_k<<<dim3(SEQN / 128, HEADS, BATCH), blk, 0, stream>>>(qkvb, vtb, ctxb);
  gemm_k<64, false, true, true, true, true><<<dim3((EMB / 64) * (ROWS / 128)), blk, 0, stream>>>(
      ctxb, WoT, bo, x, out, ROWS, EMB, EMB);
  ln_k<true><<<ROWS, blk, 0, stream>>>(out, g2, s2, hln);
  gemm256_k<true, true, false><<<dim3((FFD / 256) * (ROWS / 256)), dim3(512), 0, stream>>>(
      hln, W1T, b1, ff1, ROWS, FFD, EMB);
  gemm_k<64, false, true, true, true, true><<<dim3((EMB / 64) * (ROWS / 128)), blk, 0, stream>>>(
      ff1, W2T, b2, out, out, ROWS, EMB, FFD);
}

// Round 17
// 207.456 us; speedup vs baseline: 1.0989x; 1.0035x over previous
//
#include <hip/hip_runtime.h>
#include <stdint.h>

#define EMB 1024
#define HEADS 16
#define HDIM 64
#define SEQN 2048
#define BATCH 2
#define FFD 4096
#define ROWS (BATCH * SEQN)

typedef unsigned short u16t;
typedef __attribute__((ext_vector_type(4))) unsigned short u16x4;
typedef __attribute__((ext_vector_type(8))) unsigned short u16x8;
typedef __attribute__((ext_vector_type(8))) __bf16 bf16x8;
typedef __attribute__((ext_vector_type(4))) float f32x4;

__device__ __forceinline__ float b2f(u16t u) {
  union { float f; unsigned int i; } v; v.i = ((unsigned int)u) << 16; return v.f;
}
__device__ __forceinline__ u16t f2b(float f) {
  union { float f; unsigned int i; } v; v.f = f;
  unsigned int r = v.i + 0x7FFFu + ((v.i >> 16) & 1u);
  return (u16t)(r >> 16);
}

// gelu_tanh via sigmoid identity: 0.5v(1+tanh(t)) = v/(1+e^{-2t}).
// R17: log2(e) folded into the constant -> v_exp_f32 (exp2) directly,
// deleting __expf's hidden v_mul per element (R10's attn trick).
// 2*sqrt(2/pi)*log2(e) = 2.3022082665776377
__device__ __forceinline__ float gelu_f(float v) {
  float t2 = 2.3022082665776377f * (v + 0.044715f * v * v * v);
  float e;
  asm("v_exp_f32 %0, %1" : "=v"(e) : "v"(-t2));  // e = 2^(-t2) = exp(-2t)
  return v / (1.f + e);
}

__device__ __forceinline__ void gload16(const u16t* g, u16t* l) {
  __builtin_amdgcn_global_load_lds((const __attribute__((address_space(1))) void*)g,
                                   (__attribute__((address_space(3))) void*)l, 16, 0, 0);
}

// ---------------- LayerNorm: one block per row (1024 cols) ----------------
template <bool INF32>
__global__ __launch_bounds__(256) void ln_k(const void* __restrict__ x_, const float* __restrict__ g,
                                            const float* __restrict__ s, u16t* __restrict__ out) {
  const int row = blockIdx.x;
  const int t = threadIdx.x;
  float f[4];
  if (INF32) {
    const float4* xr = (const float4*)((const float*)x_ + (size_t)row * EMB);
    float4 xv = xr[t];
    f[0] = xv.x; f[1] = xv.y; f[2] = xv.z; f[3] = xv.w;
  } else {
    const u16t* xr = (const u16t*)x_ + (size_t)row * EMB;
    u16x4 xv = *(const u16x4*)(xr + t * 4);
#pragma unroll
    for (int i = 0; i < 4; i++) f[i] = b2f(xv[i]);
  }
  float sum = 0.f, sq = 0.f;
#pragma unroll
  for (int i = 0; i < 4; i++) { sum += f[i]; sq += f[i] * f[i]; }
#pragma unroll
  for (int off = 1; off < 64; off <<= 1) { sum += __shfl_xor(sum, off); sq += __shfl_xor(sq, off); }
  __shared__ float red[8];
  const int lane = t & 63, wave = t >> 6;
  if (lane == 0) { red[wave] = sum; red[4 + wave] = sq; }
  __syncthreads();
  sum = red[0] + red[1] + red[2] + red[3];
  sq = red[4] + red[5] + red[6] + red[7];
  const float mean = sum * (1.f / EMB);
  const float var = sq * (1.f / EMB) - mean * mean;
  const float rstd = rsqrtf(var + 1e-5f);
  float4 gv = ((const float4*)g)[t];
  float4 sv = ((const float4*)s)[t];
  float gg[4] = {gv.x, gv.y, gv.z, gv.w};
  float ss[4] = {sv.x, sv.y, sv.z, sv.w};
  u16x4 ov;
#pragma unroll
  for (int i = 0; i < 4; i++) ov[i] = f2b((f[i] - mean) * rstd * gg[i] + ss[i]);
  *(u16x4*)(out + (size_t)row * EMB + t * 4) = ov;
}

// ------ Merged: ALL 6 weight transposes + LN1 in ONE dispatch ------------
// R17: transpose write vectorized -- thread->quad remap (qid>>3, qid&7)
// writes one u16x4 (8B) instead of 4 scalar 2B stores. Same transpose
// semantics: out[(bx*32+a)*R + by*32+b] = tile[b][a] in both mappings.
__global__ __launch_bounds__(256) void trln_k(const float* __restrict__ Wq, const float* __restrict__ Wk,
                                              const float* __restrict__ Wv, const float* __restrict__ Wo,
                                              const float* __restrict__ W1, const float* __restrict__ W2,
                                              u16t* __restrict__ WqkvT, u16t* __restrict__ WoT,
                                              u16t* __restrict__ W1T, u16t* __restrict__ W2T,
                                              const float* __restrict__ x, const float* __restrict__ g1,
                                              const float* __restrict__ s1, u16t* __restrict__ hln) {
  int t = blockIdx.x;
  if (t >= 12288) {
    // ---- LN1 part: one block per row ----
    const int row = t - 12288;
    const int tt = threadIdx.x;
    const float4* xr = (const float4*)(x + (size_t)row * EMB);
    float4 xv = xr[tt];
    float f[4] = {xv.x, xv.y, xv.z, xv.w};
    float sum = 0.f, sq = 0.f;
#pragma unroll
    for (int i = 0; i < 4; i++) { sum += f[i]; sq += f[i] * f[i]; }
#pragma unroll
    for (int off = 1; off < 64; off <<= 1) { sum += __shfl_xor(sum, off); sq += __shfl_xor(sq, off); }
    __shared__ float red[8];
    const int lane = tt & 63, wave = tt >> 6;
    if (lane == 0) { red[wave] = sum; red[4 + wave] = sq; }
    __syncthreads();
    sum = red[0] + red[1] + red[2] + red[3];
    sq = red[4] + red[5] + red[6] + red[7];
    const float mean = sum * (1.f / EMB);
    const float var = sq * (1.f / EMB) - mean * mean;
    const float rstd = rsqrtf(var + 1e-5f);
    float4 gv = ((const float4*)g1)[tt];
    float4 sv = ((const float4*)s1)[tt];
    float gg[4] = {gv.x, gv.y, gv.z, gv.w};
    float ss[4] = {sv.x, sv.y, sv.z, sv.w};
    u16x4 ov;
#pragma unroll
    for (int i = 0; i < 4; i++) ov[i] = f2b((f[i] - mean) * rstd * gg[i] + ss[i]);
    *(u16x4*)(hln + (size_t)row * EMB + tt * 4) = ov;
    return;
  }
  // ---- transpose part ----
  const float* in; u16t* out; int R, C;
  if (t < 4096) {
    R = EMB; C = EMB;
    const int seg = t >> 10; t &= 1023;
    if (seg == 0)      { in = Wq; out = WqkvT; }
    else if (seg == 1) { in = Wk; out = WqkvT + (size_t)EMB * EMB; }
    else if (seg == 2) { in = Wv; out = WqkvT + (size_t)2 * EMB * EMB; }
    else               { in = Wo; out = WoT; }
  } else if (t < 8192) {
    in = W1; out = W1T; R = EMB; C = FFD; t -= 4096;
  } else {
    in = W2; out = W2T; R = FFD; C = EMB; t -= 8192;
  }
  const int bx = t % (C >> 5), by = t / (C >> 5);

  __shared__ float tile[32][33];
  const int tx = threadIdx.x & 31, ty = threadIdx.x >> 5;
  const int c = bx * 32 + tx;
#pragma unroll
  for (int i = 0; i < 4; i++) {
    int r = by * 32 + ty + i * 8;
    tile[ty + i * 8][tx] = in[(size_t)r * C + c];
  }
  __syncthreads();
  const int qid = threadIdx.x;     // 0..255
  const int c2i = qid >> 3;        // 0..31 (output row within tile)
  const int r2q = qid & 7;         // 0..7  (quad of output cols)
  u16x4 ov;
#pragma unroll
  for (int j = 0; j < 4; j++) ov[j] = f2b(tile[r2q * 4 + j][c2i]);
  *(u16x4*)&out[(size_t)(bx * 32 + c2i) * R + by * 32 + r2q * 4] = ov;
}

// ---------------- V transpose: qkv V part -> vt[b*H+h][64][SEQN] ---------
__global__ __launch_bounds__(256) void vtr_k(const u16t* __restrict__ qkv, u16t* __restrict__ vt) {
  __shared__ u16t tile[32][33];
  const int tx = threadIdx.x & 31, ty = threadIdx.x >> 5;  // 32 x 8
  const int k0 = blockIdx.x * 32;
  const int d0 = blockIdx.y * 32;
  const int bh = blockIdx.z;
  const int b = bh / HEADS, h = bh % HEADS;
  const u16t* src = qkv + (size_t)b * SEQN * (3 * EMB) + 2 * EMB + h * HDIM;
#pragma unroll
  for (int i = 0; i < 4; i++)
    tile[ty + i * 8][tx] = src[(size_t)(k0 + ty + i * 8) * (3 * EMB) + d0 + tx];
  __syncthreads();
  u16t* dst = vt + ((size_t)bh * HDIM + d0) * SEQN + k0;
#pragma unroll
  for (int i = 0; i < 4; i++)
    dst[(size_t)(ty + i * 8) * SEQN + tx] = tile[tx][ty + i * 8];
}

// ------- GEMM 256x256 tile: 4-phase, T2 swizzle, counted vmcnt -----------
// R16: unroll-by-2 static buffer addressing. ~1250 TF warm.
template <bool GELU, bool BIAS, bool OUTF32>
__global__ __launch_bounds__(512, 2) void gemm256_k(const u16t* __restrict__ A, const u16t* __restrict__ Bt,
                                                    const float* __restrict__ bias, void* __restrict__ C_,
                                                    int M, int N, int K) {
  __shared__ u16t As[2][256 * 64];
  __shared__ u16t Bs[2][256 * 64];
  const int tid = threadIdx.x;
  const int lane = tid & 63, wave = tid >> 6;
  const int wr = wave >> 2, wc = wave & 3;  // 2 x 4 waves
  const int nwg = gridDim.x, per = nwg >> 3;
  const int swz = (blockIdx.x & 7) * per + (blockIdx.x >> 3);
  const int nx = N >> 8;
  const int m0 = (swz / nx) * 256, n0 = (swz % nx) * 256;
  f32x4 acc[8][4] = {};
  const int nk = K >> 6;

  // stage one 128-row half (2 loads/thread) of the A or B tile
  auto stageA = [&](int t, u16t* buf, int h) {
    const int k0 = t << 6;
#pragma unroll
    for (int i = 0; i < 2; i++) {
      unsigned P = (h * 2 + i) * 8192 + tid * 16;
      unsigned row = P >> 7, slot = ((P >> 4) & 7) ^ (row & 7);
      gload16(A + (size_t)(m0 + row) * K + k0 + slot * 8, &buf[P >> 1]);
    }
  };
  auto stageB = [&](int t, u16t* buf, int h) {
    const int k0 = t << 6;
#pragma unroll
    for (int i = 0; i < 2; i++) {
      unsigned P = (h * 2 + i) * 8192 + tid * 16;
      unsigned row = P >> 7, slot = ((P >> 4) & 7) ^ (row & 7);
      gload16(Bt + (size_t)(n0 + row) * K + k0 + slot * 8, &buf[P >> 1]);
    }
  };

  // prologue: tile0 A+B, tile1 B (B of buf[1] is only read at tile1 phase 0)
  stageA(0, As[0], 0); stageA(0, As[0], 1);
  stageB(0, Bs[0], 0); stageB(0, Bs[0], 1);
  if (nk > 1) {
    stageB(1, Bs[1], 0); stageB(1, Bs[1], 1);
    asm volatile("s_waitcnt vmcnt(4)" ::: "memory");  // A(0),B(0) done; B(1) in flight
  } else {
    asm volatile("s_waitcnt vmcnt(0)" ::: "memory");
  }
  __builtin_amdgcn_s_barrier();

  // one K-tile (4 phases) against statically-addressed buffers.
  // Anx = stageA target (other buffer), Bcu = stageB target (current).
  auto tstep = [&](int t, const u16t* Asc, const u16t* Bsc,
                   u16t* Anx, u16t* Bcu) __attribute__((always_inline)) {
    auto rdA = [&](int mi, int kc) -> bf16x8 {
      unsigned row = wr * 128 + mi * 16 + (lane & 15);
      unsigned slot = ((unsigned)(kc * 4 + (lane >> 4))) ^ (row & 7);
      return *(const bf16x8*)&Asc[row * 64 + slot * 8];
    };
    // ---- phase 0 ----
    bf16x8 bfr[4][2];
#pragma unroll
    for (int ni = 0; ni < 4; ni++)
#pragma unroll
      for (int kc = 0; kc < 2; kc++) {
        unsigned row = wc * 64 + ni * 16 + (lane & 15);
        unsigned slot = ((unsigned)(kc * 4 + (lane >> 4))) ^ (row & 7);
        bfr[ni][kc] = *(const bf16x8*)&Bsc[row * 64 + slot * 8];
      }
    bf16x8 aL0 = rdA(0, 0), aL1 = rdA(0, 1), aH0 = rdA(1, 0), aH1 = rdA(1, 1);
    if (t + 1 < nk) stageA(t + 1, Anx, 0);
    __builtin_amdgcn_s_barrier();
    __builtin_amdgcn_s_setprio(1);
#pragma unroll
    for (int ni = 0; ni < 4; ni++) {
      acc[0][ni] = __builtin_amdgcn_mfma_f32_16x16x32_bf16(aL0, bfr[ni][0], acc[0][ni], 0, 0, 0);
      acc[0][ni] = __builtin_amdgcn_mfma_f32_16x16x32_bf16(aL1, bfr[ni][1], acc[0][ni], 0, 0, 0);
      acc[1][ni] = __builtin_amdgcn_mfma_f32_16x16x32_bf16(aH0, bfr[ni][0], acc[1][ni], 0, 0, 0);
      acc[1][ni] = __builtin_amdgcn_mfma_f32_16x16x32_bf16(aH1, bfr[ni][1], acc[1][ni], 0, 0, 0);
    }
    __builtin_amdgcn_s_setprio(0);
    __builtin_amdgcn_s_barrier();
    // ---- phase 1 ----
    aL0 = rdA(2, 0); aL1 = rdA(2, 1); aH0 = rdA(3, 0); aH1 = rdA(3, 1);
    if (t + 1 < nk) stageA(t + 1, Anx, 1);
    __builtin_amdgcn_s_barrier();
    __builtin_amdgcn_s_setprio(1);
#pragma unroll
    for (int ni = 0; ni < 4; ni++) {
      acc[2][ni] = __builtin_amdgcn_mfma_f32_16x16x32_bf16(aL0, bfr[ni][0], acc[2][ni], 0, 0, 0);
      acc[2][ni] = __builtin_amdgcn_mfma_f32_16x16x32_bf16(aL1, bfr[ni][1], acc[2][ni], 0, 0, 0);
      acc[3][ni] = __builtin_amdgcn_mfma_f32_16x16x32_bf16(aH0, bfr[ni][0], acc[3][ni], 0, 0, 0);
      acc[3][ni] = __builtin_amdgcn_mfma_f32_16x16x32_bf16(aH1, bfr[ni][1], acc[3][ni], 0, 0, 0);
    }
    __builtin_amdgcn_s_setprio(0);
    __builtin_amdgcn_s_barrier();
    // ---- phase 2 ----
    aL0 = rdA(4, 0); aL1 = rdA(4, 1); aH0 = rdA(5, 0); aH1 = rdA(5, 1);
    if (t + 2 < nk) stageB(t + 2, Bcu, 0);  // Bsc B-frags already in regs
    __builtin_amdgcn_s_barrier();
    __builtin_amdgcn_s_setprio(1);
#pragma unroll
    for (int ni = 0; ni < 4; ni++) {
      acc[4][ni] = __builtin_amdgcn_mfma_f32_16x16x32_bf16(aL0, bfr[ni][0], acc[4][ni], 0, 0, 0);
      acc[4][ni] = __builtin_amdgcn_mfma_f32_16x16x32_bf16(aL1, bfr[ni][1], acc[4][ni], 0, 0, 0);
      acc[5][ni] = __builtin_amdgcn_mfma_f32_16x16x32_bf16(aH0, bfr[ni][0], acc[5][ni], 0, 0, 0);
      acc[5][ni] = __builtin_amdgcn_mfma_f32_16x16x32_bf16(aH1, bfr[ni][1], acc[5][ni], 0, 0, 0);
    }
    __builtin_amdgcn_s_setprio(0);
    __builtin_amdgcn_s_barrier();
    // ---- phase 3 ----
    aL0 = rdA(6, 0); aL1 = rdA(6, 1); aH0 = rdA(7, 0); aH1 = rdA(7, 1);
    if (t + 2 < nk) stageB(t + 2, Bcu, 1);
    if (t + 2 < nk)      asm volatile("s_waitcnt vmcnt(4)" ::: "memory");
    else if (t + 1 < nk) asm volatile("s_waitcnt vmcnt(0)" ::: "memory");
    __builtin_amdgcn_s_barrier();
    __builtin_amdgcn_s_setprio(1);
#pragma unroll
    for (int ni = 0; ni < 4; ni++) {
      acc[6][ni] = __builtin_amdgcn_mfma_f32_16x16x32_bf16(aL0, bfr[ni][0], acc[6][ni], 0, 0, 0);
      acc[6][ni] = __builtin_amdgcn_mfma_f32_16x16x32_bf16(aL1, bfr[ni][1], acc[6][ni], 0, 0, 0);
      acc[7][ni] = __builtin_amdgcn_mfma_f32_16x16x32_bf16(aH0, bfr[ni][0], acc[7][ni], 0, 0, 0);
      acc[7][ni] = __builtin_amdgcn_mfma_f32_16x16x32_bf16(aH1, bfr[ni][1], acc[7][ni], 0, 0, 0);
    }
    __builtin_amdgcn_s_setprio(0);
    __builtin_amdgcn_s_barrier();
  };

  int t = 0;
  for (; t + 2 <= nk; t += 2) {   // steady state: static buffer ids
    tstep(t,     As[0], Bs[0], As[1], Bs[0]);  // cur=0: A->buf1, B(t+2)->buf0
    tstep(t + 1, As[1], Bs[1], As[0], Bs[1]);  // cur=1: A->buf0, B(t+2)->buf1
  }
  for (; t < nk; t++)             // tail (never executes for K=1024)
    tstep(t, As[t & 1], Bs[t & 1], As[(t & 1) ^ 1], Bs[t & 1]);

#pragma unroll
  for (int mi = 0; mi < 8; mi++) {
#pragma unroll
    for (int ni = 0; ni < 4; ni++) {
      int col = n0 + wc * 64 + ni * 16 + (lane & 15);
      int rb = m0 + wr * 128 + mi * 16 + ((lane >> 4) << 2);
      float bv = 0.f;
      if (BIAS) bv = bias[col];
#pragma unroll
      for (int r = 0; r < 4; r++) {
        float v = acc[mi][ni][r] + bv;
        if (GELU) v = gelu_f(v);
        size_t idx = (size_t)(rb + r) * N + col;
        if (OUTF32) ((float*)C_)[idx] = v;
        else ((u16t*)C_)[idx] = f2b(v);
      }
    }
  }
}

// -------- GEMM 128x64 (N=1024 shapes): 3-stage ring, counted vmcnt, T2 ---
// R14: K-loop unrolled by 3 -> static ring ids.
template <int BN, bool GELU, bool RESID, bool BIAS, bool RESF32, bool OUTF32>
__global__ __launch_bounds__(256) void gemm_k(const u16t* __restrict__ A, const u16t* __restrict__ Bt,
                                              const float* __restrict__ bias, const void* __restrict__ res_,
                                              void* __restrict__ C_, int M, int N, int K) {
  constexpr int NF = BN / 32;
  static_assert(BN == 64, "vmcnt count assumes 6 loads/stage");
  __shared__ u16t As[3][128 * 64];
  __shared__ u16t Bs[3][BN * 64];
  const int tid = threadIdx.x;
  const int lane = tid & 63;
  const int wave = tid >> 6;
  const int nx = N / BN, pnx = nx >> 3;
  const int bid = blockIdx.x;
  const int xcd = bid & 7, idx = bid >> 3;
  const int n0 = (xcd * pnx + (idx % pnx)) * BN;
  const int m0 = (idx / pnx) * 128;
  const int wm = (wave >> 1) * 64, wn = (wave & 1) * (BN / 2);
  f32x4 acc[4][NF] = {};
  const int nk = K >> 6;

  auto stage = [&](int t, int buf) {
    const int k0 = t << 6;
#pragma unroll
    for (int i = 0; i < 4; i++) {
      unsigned P = i * 4096 + tid * 16;
      unsigned row = P >> 7, slot = ((P >> 4) & 7) ^ (row & 7);
      gload16(A + (size_t)(m0 + row) * K + k0 + slot * 8, &As[buf][P >> 1]);
    }
#pragma unroll
    for (int i = 0; i < BN / 32; i++) {
      unsigned P = i * 4096 + tid * 16;
      unsigned row = P >> 7, slot = ((P >> 4) & 7) ^ (row & 7);
      gload16(Bt + (size_t)(n0 + row) * K + k0 + slot * 8, &Bs[buf][P >> 1]);
    }
  };

  // one K-step against statically-addressed buffers Asc/Bsc; prefetch
  // target sbuf is also a literal at every steady-state call site.
  auto kstep = [&](int t, const u16t* Asc, const u16t* Bsc, int sbuf) __attribute__((always_inline)) {
    if (t + 1 < nk) asm volatile("s_waitcnt vmcnt(6)" ::: "memory");
    else            asm volatile("s_waitcnt vmcnt(0)" ::: "memory");
    __builtin_amdgcn_s_barrier();
#pragma unroll
    for (int kc = 0; kc < 2; kc++) {
      bf16x8 af[4], bf[NF];
#pragma unroll
      for (int mi = 0; mi < 4; mi++) {
        unsigned row = wm + mi * 16 + (lane & 15);
        unsigned slot = ((unsigned)(kc * 4 + (lane >> 4))) ^ (row & 7);
        af[mi] = *(const bf16x8*)&Asc[row * 64 + slot * 8];
      }
#pragma unroll
      for (int ni = 0; ni < NF; ni++) {
        unsigned row = wn + ni * 16 + (lane & 15);
        unsigned slot = ((unsigned)(kc * 4 + (lane >> 4))) ^ (row & 7);
        bf[ni] = *(const bf16x8*)&Bsc[row * 64 + slot * 8];
      }
      __builtin_amdgcn_s_setprio(1);
#pragma unroll
      for (int mi = 0; mi < 4; mi++)
#pragma unroll
        for (int ni = 0; ni < NF; ni++)
          acc[mi][ni] = __builtin_amdgcn_mfma_f32_16x16x32_bf16(af[mi], bf[ni], acc[mi][ni], 0, 0, 0);
      __builtin_amdgcn_s_setprio(0);
    }
    if (t + 2 < nk) stage(t + 2, sbuf);
  };

  stage(0, 0);
  if (nk > 1) stage(1, 1);

  int t = 0;
  for (; t + 3 <= nk; t += 3) {        // steady state: static ring ids
    kstep(t,     As[0], Bs[0], 2);     // prefetch (t+2)%3 == 2
    kstep(t + 1, As[1], Bs[1], 0);
    kstep(t + 2, As[2], Bs[2], 1);
  }
  for (; t < nk; t++)                  // tail (<=2 iters, dynamic ids)
    kstep(t, As[t % 3], Bs[t % 3], (t + 2) % 3);

#pragma unroll
  for (int mi = 0; mi < 4; mi++) {
#pragma unroll
    for (int ni = 0; ni < NF; ni++) {
      int col = n0 + wn + ni * 16 + (lane & 15);
      int rb = m0 + wm + mi * 16 + ((lane >> 4) << 2);
      float bv = 0.f;
      if (BIAS) bv = bias[col];
#pragma unroll
      for (int r = 0; r < 4; r++) {
        float v = acc[mi][ni][r] + bv;
        if (GELU) v = gelu_f(v);
        size_t idx = (size_t)(rb + r) * N + col;
        if (RESID) v += RESF32 ? ((const float*)res_)[idx] : b2f(((const u16t*)res_)[idx]);
        if (OUTF32) ((float*)C_)[idx] = v;
        else ((u16t*)C_)[idx] = f2b(v);
      }
    }
  }
}

// -- Flash attention (causal), KVBLK=64, abs softmax ----------------------
// R15 structure (best known): swapped QK^T (packed b64 P-store), dbuf K/V
// reg-staging with unroll-by-2 static LDS addressing, truncating P->bf16,
// exp2-direct via Q pre-scale.
__global__ __launch_bounds__(256) void attn_k(const u16t* __restrict__ qkv,
                                              const u16t* __restrict__ vt,
                                              u16t* __restrict__ ctx) {
  const int b = blockIdx.z, h = blockIdx.y;
  const int tid = threadIdx.x, lane = tid & 63, wave = tid >> 6;
  const int bx = (b == 1) ? (gridDim.x - 1 - blockIdx.x) : blockIdx.x;  // causal balance
  const int q0 = bx * 128 + wave * 32;
  const int ld = 3 * EMB;
  const u16t* Qp = qkv + (size_t)b * SEQN * ld + h * HDIM;
  const u16t* Kp = Qp + EMB;
  const u16t* VTp = vt + (size_t)(b * HEADS + h) * HDIM * SEQN;  // [64][SEQN]

  __shared__ u16t Ks[2][64 * 64];
  __shared__ u16t Vs[2][64 * 64];
  __shared__ u16t Ps[4][32][72];

  bf16x8 qf[2][2];
#pragma unroll
  for (int mi = 0; mi < 2; mi++)
#pragma unroll
    for (int kc = 0; kc < 2; kc++) {
      u16x8 qraw = *(const u16x8*)(Qp + (size_t)(q0 + mi * 16 + (lane & 15)) * ld + kc * 32 + (lane >> 4) * 8);
      u16x8 qs;
#pragma unroll
      for (int j = 0; j < 8; j++) qs[j] = f2b(b2f(qraw[j]) * 0.18033688011112042f);  // (1/8)*log2(e)
      qf[mi][kc] = __builtin_bit_cast(bf16x8, qs);
    }

  u16x8 onesu;
#pragma unroll
  for (int j = 0; j < 8; j++) onesu[j] = 0x3F80;  // bf16 1.0
  const bf16x8 ones = __builtin_bit_cast(bf16x8, onesu);

  f32x4 o[2][4] = {};
  f32x4 ls[2] = {};

  u16x8 kreg[2], vreg[2];
  auto issue = [&](int kt) {  // global (pre-swizzled source) -> regs
    const int kb = kt * 64;
#pragma unroll
    for (int i = 0; i < 2; i++) {
      unsigned P = i * 4096 + tid * 16;
      unsigned row = P >> 7;
      unsigned slot = ((P >> 4) & 7) ^ (row & 7);
      kreg[i] = *(const u16x8*)(Kp + (size_t)(kb + row) * ld + slot * 8);
      vreg[i] = *(const u16x8*)(VTp + (size_t)row * SEQN + kb + slot * 8);
    }
  };

  const int ntiles = 2 * bx + 2;  // ALWAYS EVEN -> clean unroll-by-2
  // prologue: tile 0 into LDS buf 0
  issue(0);
  asm volatile("s_waitcnt vmcnt(0)" ::: "memory");
#pragma unroll
  for (int i = 0; i < 2; i++) {
    unsigned P = i * 4096 + tid * 16;
    *(u16x8*)&Ks[0][P >> 1] = kreg[i];
    *(u16x8*)&Vs[0][P >> 1] = vreg[i];
  }
  __syncthreads();

  // one tile step with statically-addressed buffers; wK/wV = write targets
  auto body = [&](int kt, const u16t* Kc, const u16t* Vc,
                  u16t* wK, u16t* wV) __attribute__((always_inline)) {
    const int kb = kt * 64;
    if (kt + 1 < ntiles) issue(kt + 1);  // latency covered by compute below

    if (kb <= q0 + 31) {
      f32x4 st[2][4] = {};   // st[mi][ni]: D[kv][q] (swapped)
      __builtin_amdgcn_s_setprio(1);
#pragma unroll
      for (int ni = 0; ni < 4; ni++) {
#pragma unroll
        for (int kc = 0; kc < 2; kc++) {
          unsigned row = ni * 16 + (lane & 15);
          unsigned slot = ((unsigned)(kc * 4 + (lane >> 4))) ^ (row & 7);
          bf16x8 bfr = *(const bf16x8*)&Kc[row * 64 + slot * 8];
          // swapped operand order: D = K . Q^T  (bit-same products/order)
          st[0][ni] = __builtin_amdgcn_mfma_f32_16x16x32_bf16(bfr, qf[0][kc], st[0][ni], 0, 0, 0);
          st[1][ni] = __builtin_amdgcn_mfma_f32_16x16x32_bf16(bfr, qf[1][kc], st[1][ni], 0, 0, 0);
        }
      }
      __builtin_amdgcn_s_setprio(0);

      if (kb + 63 > q0) {
#pragma unroll
        for (int mi = 0; mi < 2; mi++)
#pragma unroll
          for (int ni = 0; ni < 4; ni++) {
            int qq = q0 + mi * 16 + (lane & 15);  // q is now the column
#pragma unroll
            for (int r = 0; r < 4; r++) {
              int kk = kb + ni * 16 + ((lane >> 4) << 2) + r;  // kv is the row
              if (kk > qq) st[mi][ni][r] = -1e30f;
            }
          }
      }

      // P-store: 4 kv-consecutive values at fixed q -> one packed b64 per
      // (mi,ni). Same [q][kv] layout as before (read side unchanged).
#pragma unroll
      for (int mi = 0; mi < 2; mi++)
#pragma unroll
        for (int ni = 0; ni < 4; ni++) {
          u16x4 pk;
#pragma unroll
          for (int r = 0; r < 4; r++) {
            union { float f; unsigned int u; } pv;
            asm("v_exp_f32 %0, %1" : "=v"(pv.f) : "v"(st[mi][ni][r]));
            pk[r] = (u16t)(pv.u >> 16);  // truncating bf16
          }
          *(u16x4*)&Ps[wave][mi * 16 + (lane & 15)][ni * 16 + ((lane >> 4) << 2)] = pk;
        }

      bf16x8 pa[2][2];
#pragma unroll
      for (int mi = 0; mi < 2; mi++)
#pragma unroll
        for (int kc = 0; kc < 2; kc++)
          pa[mi][kc] = *(const bf16x8*)&Ps[wave][mi * 16 + (lane & 15)][kc * 32 + (lane >> 4) * 8];

      __builtin_amdgcn_s_setprio(1);
#pragma unroll
      for (int di = 0; di < 4; di++) {
#pragma unroll
        for (int kc = 0; kc < 2; kc++) {
          unsigned row = di * 16 + (lane & 15);
          unsigned slot = ((unsigned)(kc * 4 + (lane >> 4))) ^ (row & 7);
          bf16x8 vf = *(const bf16x8*)&Vc[row * 64 + slot * 8];
          o[0][di] = __builtin_amdgcn_mfma_f32_16x16x32_bf16(pa[0][kc], vf, o[0][di], 0, 0, 0);
          o[1][di] = __builtin_amdgcn_mfma_f32_16x16x32_bf16(pa[1][kc], vf, o[1][di], 0, 0, 0);
        }
      }
#pragma unroll
      for (int kc = 0; kc < 2; kc++) {
        ls[0] = __builtin_amdgcn_mfma_f32_16x16x32_bf16(pa[0][kc], ones, ls[0], 0, 0, 0);
        ls[1] = __builtin_amdgcn_mfma_f32_16x16x32_bf16(pa[1][kc], ones, ls[1], 0, 0, 0);
      }
      __builtin_amdgcn_s_setprio(0);
    }

    // Single barrier per tile: write kt+1 into the OTHER buffer (static
    // target), then publish.
    asm volatile("s_waitcnt vmcnt(0)" ::: "memory");  // issue(kt+1) landed; also compiler fence
    if (kt + 1 < ntiles) {
#pragma unroll
      for (int i = 0; i < 2; i++) {
        unsigned P = i * 4096 + tid * 16;
        *(u16x8*)&wK[P >> 1] = kreg[i];
        *(u16x8*)&wV[P >> 1] = vreg[i];
      }
    }
    __syncthreads();  // lgkm drain + barrier: writes visible before next compute
  };

  for (int kt = 0; kt < ntiles; kt += 2) {
    body(kt,     Ks[0], Vs[0], Ks[1], Vs[1]);   // cur=0, write buf 1
    body(kt + 1, Ks[1], Vs[1], Ks[0], Vs[0]);   // cur=1, write buf 0
  }

  u16t* Cp = ctx + (size_t)b * SEQN * EMB + h * HDIM;
#pragma unroll
  for (int mi = 0; mi < 2; mi++)
#pragma unroll
    for (int r = 0; r < 4; r++) {
      float inv = 1.f / ls[mi][r];
      int qq = q0 + mi * 16 + ((lane >> 4) << 2) + r;
#pragma unroll
      for (int di = 0; di < 4; di++)
        Cp[(size_t)qq * EMB + di * 16 + (lane & 15)] = f2b(o[mi][di][r] * inv);
    }
}

// -------------------------------------------------------------------------
extern "C" void kernel_launch(void* const* d_in, const int* in_sizes, int n_in,
                              void* d_out, int out_size, void* d_ws, size_t ws_size,
                              hipStream_t stream) {
  const float* x  = (const float*)d_in[0];
  const float* Wq = (const float*)d_in[1];
  const float* Wk = (const float*)d_in[2];
  const float* Wv = (const float*)d_in[3];
  const float* Wo = (const float*)d_in[4];
  const float* bo = (const float*)d_in[5];
  const float* W1 = (const float*)d_in[6];
  const float* b1 = (const float*)d_in[7];
  const float* W2 = (const float*)d_in[8];
  const float* b2 = (const float*)d_in[9];
  const float* g1 = (const float*)d_in[10];
  const float* s1 = (const float*)d_in[11];
  const float* g2 = (const float*)d_in[12];
  const float* s2 = (const float*)d_in[13];
  float* out = (float*)d_out;  // reference output dtype is float32

  // workspace layout (64 MiB total).
  // ALIAS MAP (liveness!):
  //   ff1 = qkvb..qkvb+32MB => covers qkvb(24MB) AND ctxb(8MB); live to FF2 end.
  //   vtb = hln (dead between QKV-GEMM and LN2); hln dead after FF1 reads it.
  char* p = (char*)d_ws;
  u16t* WqkvT = (u16t*)p; p += (size_t)3 * EMB * EMB * 2;   // [3072][1024]
  u16t* WoT   = (u16t*)p; p += (size_t)EMB * EMB * 2;       // [1024][1024]
  u16t* W1T   = (u16t*)p; p += (size_t)FFD * EMB * 2;       // [4096][1024]
  u16t* W2T   = (u16t*)p; p += (size_t)EMB * FFD * 2;       // [1024][4096]
  u16t* hln   = (u16t*)p; p += (size_t)ROWS * EMB * 2;      // [4096][1024]
  u16t* qkvb  = (u16t*)p; p += (size_t)ROWS * 3 * EMB * 2;  // [4096][3072]
  u16t* ctxb  = (u16t*)p; p += (size_t)ROWS * EMB * 2;      // [4096][1024]
  u16t* ff1   = qkvb;  // [4096][4096] aliases qkv(24MB)+ctx(8MB)
  u16t* vtb   = hln;   // [32][64][2048] aliases hln

  dim3 blk(256);
  // merged transposes + LN1 (blocks >= 12288 run LN rows)
  trln_k<<<dim3(12288 + ROWS), blk, 0, stream>>>(Wq, Wk, Wv, Wo, W1, W2,
                                                 WqkvT, WoT, W1T, W2T, x, g1, s1, hln);
  gemm256_k<false, false, false><<<dim3((3 * EMB / 256) * (ROWS / 256)), dim3(512), 0, stream>>>(
      hln, WqkvT, nullptr, qkvb, ROWS, 3 * EMB, EMB);
  vtr_k<<<dim3(SEQN / 32, HDIM / 32, BATCH * HEADS), blk, 0, stream>>>(qkvb, vtb);
  attn_k<<<dim3(SEQN / 128, HEADS, BATCH), blk, 0, stream>>>(qkvb, vtb, ctxb);
  gemm_k<64, false, true, true, true, true><<<dim3((EMB / 64) * (ROWS / 128)), blk, 0, stream>>>(
      ctxb, WoT, bo, x, out, ROWS, EMB, EMB);
  ln_k<true><<<ROWS, blk, 0, stream>>>(out, g2, s2, hln);
  gemm256_k<true, true, false><<<dim3((FFD / 256) * (ROWS / 256)), dim3(512), 0, stream>>>(
      hln, W1T, b1, ff1, ROWS, FFD, EMB);
  gemm_k<64, false, true, true, true, true><<<dim3((EMB / 64) * (ROWS / 128)), blk, 0, stream>>>(
      ff1, W2T, b2, out, out, ROWS, EMB, FFD);
}